// Round 3
// baseline (881.875 us; speedup 1.0000x reference)
//
#include <hip/hip_runtime.h>
#include <hip/hip_bf16.h>

typedef _Float16 f16;
typedef __attribute__((ext_vector_type(8))) _Float16 half8;
typedef __attribute__((ext_vector_type(4))) _Float16 half4;
typedef __attribute__((ext_vector_type(4))) float f32x4;

static const int BN = 16, SEQN = 4000;

// ---------------------------------------------------------------------------
__device__ __forceinline__ void gload_lds(f16* lds, const f16* g) {
  __builtin_amdgcn_global_load_lds((const __attribute__((address_space(1))) unsigned int*)g,
                                   (__attribute__((address_space(3))) unsigned int*)lds, 16, 0, 0);
}

// bijective XCD swizzle (m204)
__device__ __forceinline__ int xcd_swz(int orig, int nwg) {
  int q = nwg >> 3, r = nwg & 7, x = orig & 7, o = orig >> 3;
  return (x < r ? x * (q + 1) : r * (q + 1) + (x - r) * q) + o;
}

// ---------------------------------------------------------------------------
// conv weights (lsp) -> wp[g_o][tap*800 + g_i], tap = dh*3+dw
__global__ void k_pack_wconv(const float* __restrict__ in, f16* __restrict__ out) {
  int i = blockIdx.x * blockDim.x + threadIdx.x;
  int stride = gridDim.x * blockDim.x;
  const int n = 800 * 7200;
  for (; i < n; i += stride) {
    int o = i / 7200, k = i % 7200;
    int tap = k / 800, gi = k % 800;
    out[i] = (f16)in[(long)o * 7200 + gi * 9 + tap];
  }
}

// out[s][f*800+g] = w_local[s][g*5+f]
__global__ void k_pack_wlocal(const float* __restrict__ in, f16* __restrict__ out) {
  int i = blockIdx.x * blockDim.x + threadIdx.x;
  int stride = gridDim.x * blockDim.x;
  const int n = 4000 * 4000;
  for (; i < n; i += stride) {
    int s = i / 4000, k = i % 4000;
    int f = k / 800, g = k % 800;
    out[i] = (f16)in[s * 4000 + g * 5 + f];
  }
}

// out[c*ldo + r] = in[r*C + c] * scale
__global__ void k_transpose_cast(const float* __restrict__ in, f16* __restrict__ out,
                                 int R, int C, int ldo, float scale) {
  __shared__ float tile[32][33];
  int c0 = blockIdx.x * 32, r0 = blockIdx.y * 32;
  for (int i = threadIdx.y; i < 32; i += 8) {
    int r = r0 + i, c = c0 + threadIdx.x;
    tile[i][threadIdx.x] = (r < R && c < C) ? in[(long)r * C + c] : 0.f;
  }
  __syncthreads();
  for (int i = threadIdx.y; i < 32; i += 8) {
    int c = c0 + i, r = r0 + threadIdx.x;
    if (c < C && r < R) out[(long)c * ldo + r] = (f16)(tile[threadIdx.x][i] * scale);
  }
}

// woT[z][gi][g] = w_dwc_other[g*7200 + gi*9 + z]
__global__ void k_pack_woT(const float* __restrict__ in, f16* __restrict__ out) {
  int id = blockIdx.x * blockDim.x + threadIdx.x;
  if (id >= 640000) return;
  int g = id / 800, gi = id % 800;
  const float* src = in + (long)g * 7200 + gi * 9;
#pragma unroll
  for (int z = 0; z < 9; z++)
    out[(long)z * 640000 + gi * 800 + g] = (f16)src[z];
}

// vtT[(f*120+e)][g] = Vt[(g*5+f)*120+e]; rows >=600 zero
__global__ void k_pack_vt(const float* __restrict__ Vt, f16* __restrict__ out) {
  int id = blockIdx.x * blockDim.x + threadIdx.x;
  if (id >= 640 * 800) return;
  int fe = id / 800, g = id % 800;
  f16 v = (f16)0.f;
  if (fe < 600) {
    int f = fe / 120, e = fe % 120;
    v = (f16)Vt[(long)(g * 5 + f) * 120 + e];
  }
  out[id] = v;
}

// ---------------------------------------------------------------------------
// gather: P[fp][b][ep][g] layout (g innermost)
__global__ void k_gather(const int* __restrict__ X, const float* __restrict__ emb,
                         f16* __restrict__ P_lsp, f16* __restrict__ P_pit,
                         f16* __restrict__ P_cod, f16* __restrict__ P_gai,
                         float* __restrict__ lsp32) {
  const float scale[15] = {1.f,1.f,1.f,1.f,0.8f,0.512f,0.8f,0.64f,0.512f,0.64f,0.512f,0.8f,0.64f,0.512f,0.512f};
  const int br[15] = {0,0,0,0,1,1,2,2,3,3,1,2,2,3,3};
  const int po[15] = {0,1,2,3,0,1,0,1,0,2,2,2,3,1,3};
  int id = blockIdx.x * blockDim.x + threadIdx.x;
  if (id >= 15 * 16 * 5 * 800) return;
  int g = id % 800; int tmp = id / 800;
  int f = tmp % 5; tmp /= 5;
  int b = tmp % 16; int c = tmp / 16;
  int s = g * 5 + f;
  int idx = X[((long)b * SEQN + s) * 15 + c];
  const float* er = emb + (long)idx * 10;
  int t = br[c], p = po[c];
  f16* P = (t == 0) ? P_lsp : (t == 1) ? P_pit : (t == 2) ? P_cod : P_gai;
  int Wp = (t == 1) ? 32 : 42;
  f16* base = P + ((long)((f + 1) * 16 + b) * Wp + (1 + p * 10)) * 800 + g;
  float sc = scale[c];
#pragma unroll
  for (int j = 0; j < 10; j++) {
    float v = er[j] * sc;
    base[(long)j * 800] = (f16)v;
    if (t == 0) lsp32[((long)b * SEQN + s) * 40 + p * 10 + j] = v;
  }
}

// ---------------------------------------------------------------------------
// lsp conv GEMM, split-K over df(=blockIdx.y). M=3200=(f,b,e), N=800(pad896),
// K-slice = 2400 (de,gi). Partials fp32 -> Cp[z][3200][800].
__global__ __launch_bounds__(256) void k_gemm_conv(
    const f16* __restrict__ P, const f16* __restrict__ wp, float* __restrict__ Cp) {
  __shared__ __align__(16) f16 As[4096];
  __shared__ __align__(16) f16 Bs[4096];
  int lin = xcd_swz(blockIdx.x, 175);
  int nx = lin % 7, my = lin / 7;
  int m0 = my * 128, n0 = nx * 128;
  int z = blockIdx.y;
  P += (long)z * 16 * 42 * 800;
  Cp += (long)z * 3200 * 800;
  int t = threadIdx.x;
  const f16 *aptr[2], *bptr[2];
#pragma unroll
  for (int q = 0; q < 2; q++) {
    int row = (q * 256 + t) >> 2;
    int m = m0 + row;
    int f = m / 640, r = m % 640, b = r / 40, e = r % 40;
    aptr[q] = P + ((long)(f * 16 + b) * 42 + e) * 800 + (t & 3) * 8;
    bptr[q] = wp + (long)(n0 + row) * 7200 + z * 2400 + (t & 3) * 8;
  }
  int lane = t & 63, wv = t >> 6;
  int wm = (wv >> 1) * 64, wn = (wv & 1) * 64;
  int l15 = lane & 15, kg = lane >> 4;
  f32x4 acc[4][4] = {};
  for (int kt = 0; kt < 75; kt++) {
    __syncthreads();
    gload_lds(&As[t * 8],        aptr[0] + kt * 32);
    gload_lds(&As[2048 + t * 8], aptr[1] + kt * 32);
    gload_lds(&Bs[t * 8],        bptr[0] + kt * 32);
    gload_lds(&Bs[2048 + t * 8], bptr[1] + kt * 32);
    __syncthreads();
    half8 av[4], bv[4];
#pragma unroll
    for (int i = 0; i < 4; i++) {
      av[i] = *(const half8*)(&As[(wm + i * 16 + l15) * 32 + kg * 8]);
      bv[i] = *(const half8*)(&Bs[(wn + i * 16 + l15) * 32 + kg * 8]);
    }
#pragma unroll
    for (int i = 0; i < 4; i++)
#pragma unroll
      for (int j = 0; j < 4; j++)
        acc[i][j] = __builtin_amdgcn_mfma_f32_16x16x32_f16(av[i], bv[j], acc[i][j], 0, 0, 0);
  }
#pragma unroll
  for (int i = 0; i < 4; i++) {
    int mb = m0 + wm + i * 16 + kg * 4;
#pragma unroll
    for (int j = 0; j < 4; j++) {
      int n = n0 + wn + j * 16 + l15;
      if (n >= 800) continue;
      f32x4 d = acc[i][j];
#pragma unroll
      for (int r = 0; r < 4; r++)
        Cp[(long)(mb + r) * 800 + n] = d[r];
    }
  }
}

// co[(b*40+e)][f*800+n] = f16( sum_z Cp[z][m][n] + bias[n] )
__global__ void k_co_reduce(const float* __restrict__ Cp, const float* __restrict__ bias,
                            f16* __restrict__ co) {
  int id = blockIdx.x * blockDim.x + threadIdx.x;
  if (id >= 640000) return;
  int m = id / 200, n4 = (id % 200) * 4;
  long o = (long)m * 800 + n4;
  f32x4 s = *(const f32x4*)&Cp[o];
  s += *(const f32x4*)&Cp[2560000 + o];
  s += *(const f32x4*)&Cp[5120000 + o];
  s += *(const f32x4*)&bias[n4];
  int f = m / 640, r2 = m % 640;
  half4 h = {(f16)s[0], (f16)s[1], (f16)s[2], (f16)s[3]};
  *(half4*)&co[(long)r2 * 4000 + f * 800 + n4] = h;
}

// ---------------------------------------------------------------------------
// generic NT GEMM with split-K (y) and z-slices. BIASM: 0 none, 1 bias[m].
template <int BIASM>
__global__ __launch_bounds__(256) void k_gemm_nt(
    const f16* __restrict__ A, int lda, const f16* __restrict__ Bm, int ldb,
    float* __restrict__ C, int ldc, const float* __restrict__ bias,
    int gx, int nwg, int nkt, int KTtot, long cslice, long az, long bz, long cz,
    int Mreal, int Nreal, int Aclamp) {
  __shared__ __align__(16) f16 As[4096];
  __shared__ __align__(16) f16 Bs[4096];
  A += (long)blockIdx.z * az;
  Bm += (long)blockIdx.z * bz;
  C += (long)blockIdx.z * cz + (long)blockIdx.y * cslice;
  int lin = xcd_swz(blockIdx.x, nwg);
  int nx = lin % gx, my = lin / gx;
  int m0 = my * 128, n0 = nx * 128;
  int kt0 = blockIdx.y * nkt;
  int ktn = nkt; if (kt0 + ktn > KTtot) ktn = KTtot - kt0;
  int t = threadIdx.x;
  const f16* aptr[2]; const f16* bptr[2];
#pragma unroll
  for (int q = 0; q < 2; q++) {
    int row = (q * 256 + t) >> 2;
    int ra = m0 + row; if (ra >= Aclamp) ra = Aclamp - 1;
    aptr[q] = A + (long)ra * lda + (long)kt0 * 32 + (t & 3) * 8;
    bptr[q] = Bm + (long)(n0 + row) * ldb + (long)kt0 * 32 + (t & 3) * 8;
  }
  int lane = t & 63, wv = t >> 6;
  int wm = (wv >> 1) * 64, wn = (wv & 1) * 64;
  int l15 = lane & 15, kg = lane >> 4;
  f32x4 acc[4][4] = {};
  for (int kt = 0; kt < ktn; kt++) {
    __syncthreads();
    gload_lds(&As[t * 8],        aptr[0] + kt * 32);
    gload_lds(&As[2048 + t * 8], aptr[1] + kt * 32);
    gload_lds(&Bs[t * 8],        bptr[0] + kt * 32);
    gload_lds(&Bs[2048 + t * 8], bptr[1] + kt * 32);
    __syncthreads();
    half8 av[4], bv[4];
#pragma unroll
    for (int i = 0; i < 4; i++) {
      av[i] = *(const half8*)(&As[(wm + i * 16 + l15) * 32 + kg * 8]);
      bv[i] = *(const half8*)(&Bs[(wn + i * 16 + l15) * 32 + kg * 8]);
    }
#pragma unroll
    for (int i = 0; i < 4; i++)
#pragma unroll
      for (int j = 0; j < 4; j++)
        acc[i][j] = __builtin_amdgcn_mfma_f32_16x16x32_f16(av[i], bv[j], acc[i][j], 0, 0, 0);
  }
#pragma unroll
  for (int i = 0; i < 4; i++) {
    int mb = m0 + wm + i * 16 + kg * 4;
#pragma unroll
    for (int j = 0; j < 4; j++) {
      int n = n0 + wn + j * 16 + l15;
      if (n >= Nreal) continue;
      f32x4 d = acc[i][j];
#pragma unroll
      for (int r = 0; r < 4; r++) {
        int m = mb + r;
        if (m >= Mreal) continue;
        float val = d[r];
        if (BIASM == 1) val += bias[m];
        C[(long)m * ldc + n] = val;
      }
    }
  }
}

__global__ void k_vred(const float* __restrict__ vp, float* __restrict__ v) {
  int i = blockIdx.x * blockDim.x + threadIdx.x;
  if (i >= 480000) return;
  float s = 0.f;
  for (int z = 0; z < 5; z++) s += vp[(long)z * 480000 + i];
  v[i] = s;
}

// ---------------------------------------------------------------------------
// Bp[fp][eg][dw*800+gi] = f16( sum_dh A9[(dh*3+dw)][ (fp-dh)*120+eg ][gi] )
__global__ void k_fold_bp(const float* __restrict__ A9, f16* __restrict__ Bp) {
  int id = blockIdx.x * blockDim.x + threadIdx.x;
  if (id >= 7 * 120 * 2400) return;
  int fp = id / 288000;
  int r = id % 288000;
  int eg = r / 2400, k = r % 2400;
  int dw = k / 800, gi = k % 800;
  float s = 0.f;
#pragma unroll
  for (int dh = 0; dh < 3; dh++) {
    int f = fp - dh;
    if (f >= 0 && f < 5)
      s += A9[((long)(dh * 3 + dw) * 640 + f * 120 + eg) * 800 + gi];
  }
  Bp[id] = (f16)s;
}

// ---------------------------------------------------------------------------
// U GEMM: Upart[fp][m][e] = sum_{dw,gi} P_seg[fp][b][j+dw][gi]*Bp[fp][e0+e][dw*800+gi]
// m-segments: [0,640) gain, [640,1152) pitch(480 real), [1152,1792) code
__global__ __launch_bounds__(256) void k_gemm_u(
    const f16* __restrict__ Pg, const f16* __restrict__ Pp, const f16* __restrict__ Pc,
    const f16* __restrict__ Bp, float* __restrict__ Upart) {
  __shared__ __align__(16) f16 As[4096];
  __shared__ __align__(16) f16 Bs[4096];
  int m0 = blockIdx.x * 128, fp = blockIdx.y;
  const f16* P; int seg0, jw, Wp, e0;
  if (m0 < 640)       { seg0 = 0;    jw = 40; Wp = 42; e0 = 0;  P = Pg; }
  else if (m0 < 1152) { seg0 = 640;  jw = 30; Wp = 32; e0 = 40; P = Pp; }
  else                { seg0 = 1152; jw = 40; Wp = 42; e0 = 80; P = Pc; }
  P += (long)fp * 16 * Wp * 800;
  int t = threadIdx.x;
  const f16 *aptr[2], *bptr[2];
#pragma unroll
  for (int q = 0; q < 2; q++) {
    int row = (q * 256 + t) >> 2;
    int local = m0 + row - seg0;
    if (local >= 16 * jw) local = 0;
    int b = local / jw, j = local % jw;
    aptr[q] = P + ((long)b * Wp + j) * 800 + (t & 3) * 8;
    int rn = row < 40 ? row : 39;
    bptr[q] = Bp + ((long)fp * 120 + e0 + rn) * 2400 + (t & 3) * 8;
  }
  int lane = t & 63, wv = t >> 6;
  int wm = (wv >> 1) * 64, wn = (wv & 1) * 64;
  int l15 = lane & 15, kg = lane >> 4;
  f32x4 acc[4][4] = {};
  for (int kt = 0; kt < 75; kt++) {
    __syncthreads();
    gload_lds(&As[t * 8],        aptr[0] + kt * 32);
    gload_lds(&As[2048 + t * 8], aptr[1] + kt * 32);
    gload_lds(&Bs[t * 8],        bptr[0] + kt * 32);
    gload_lds(&Bs[2048 + t * 8], bptr[1] + kt * 32);
    __syncthreads();
    half8 av[4], bv[4];
#pragma unroll
    for (int i = 0; i < 4; i++) {
      av[i] = *(const half8*)(&As[(wm + i * 16 + l15) * 32 + kg * 8]);
      bv[i] = *(const half8*)(&Bs[(wn + i * 16 + l15) * 32 + kg * 8]);
    }
#pragma unroll
    for (int i = 0; i < 4; i++)
#pragma unroll
      for (int j = 0; j < 4; j++)
        acc[i][j] = __builtin_amdgcn_mfma_f32_16x16x32_f16(av[i], bv[j], acc[i][j], 0, 0, 0);
  }
#pragma unroll
  for (int i = 0; i < 4; i++) {
    int mb = m0 + wm + i * 16 + kg * 4;
#pragma unroll
    for (int j = 0; j < 4; j++) {
      int n = wn + j * 16 + l15;
      if (n >= 40) continue;
      f32x4 d = acc[i][j];
#pragma unroll
      for (int r = 0; r < 4; r++) {
        int m = mb + r;
        if (m - seg0 >= 16 * jw) continue;
        Upart[((long)fp * 1792 + m) * 40 + n] = d[r];
      }
    }
  }
}

// Ufin[m][e] = sum_fp Upart + cbblv[e0(m)+e]
__global__ void k_ured(const float* __restrict__ Upart, const float* __restrict__ cbblv,
                       float* __restrict__ Ufin) {
  int id = blockIdx.x * blockDim.x + threadIdx.x;
  if (id >= 1792 * 40) return;
  int m = id / 40, e = id % 40;
  int e0 = m < 640 ? 0 : (m < 1152 ? 40 : 80);
  float s = cbblv[e0 + e];
  for (int fp = 0; fp < 7; fp++) s += Upart[(long)fp * 71680 + id];
  Ufin[id] = s;
}

// cbblv[e] = sum_s bconv_o[s/5]*Vt[s,e] + sum_s b_local[s]*v[s,e]; svv[e]=sum_s v[s,e]
__global__ __launch_bounds__(256) void k_consts(
    const float* __restrict__ Vt, const float* __restrict__ vmat,
    const float* __restrict__ bconv, const float* __restrict__ blocal,
    float* __restrict__ cbblv, float* __restrict__ svv) {
  __shared__ float r1[256], r2[256];
  int e = blockIdx.x, t = threadIdx.x;
  float a = 0.f, b = 0.f;
  for (int s = t; s < 4000; s += 256) {
    a += bconv[s / 5] * Vt[(long)s * 120 + e] + blocal[s] * vmat[(long)s * 120 + e];
    b += vmat[(long)s * 120 + e];
  }
  r1[t] = a; r2[t] = b; __syncthreads();
  for (int o = 128; o > 0; o >>= 1) {
    if (t < o) { r1[t] += r1[t + o]; r2[t] += r2[t + o]; }
    __syncthreads();
  }
  if (t == 0) { cbblv[e] = r1[0]; svv[e] = r2[0]; }
}

// ---------------------------------------------------------------------------
// kv[b,d,e] = sum_s K[s,d]*V[s,e] ; cl ld = 640
__global__ __launch_bounds__(256) void k_kv_partial(
    const float* __restrict__ cl, const float* __restrict__ wlk, const float* __restrict__ blk,
    const float* __restrict__ wlv, const float* __restrict__ blv, float* __restrict__ kvp) {
  __shared__ float s_wk[1600], s_wv[1600];
  __shared__ float s_cl[8][40], s_k[8][40], s_v[8][40];
  int t = threadIdx.x, chunk = blockIdx.x, b = blockIdx.y;
  for (int p = t; p < 1600; p += 256) { s_wk[p] = wlk[p]; s_wv[p] = wlv[p]; }
  float acc[7] = {0.f, 0.f, 0.f, 0.f, 0.f, 0.f, 0.f};
  for (int c8 = 0; c8 < 20; c8++) {
    int sb = chunk * 160 + c8 * 8;
    __syncthreads();
    for (int p = t; p < 320; p += 256) {
      int sl = p / 40, e = p % 40;
      s_cl[sl][e] = cl[(long)(sb + sl) * 640 + b * 40 + e];
    }
    __syncthreads();
    for (int p = t; p < 640; p += 256) {
      int half = p / 320, q = p % 320, sl = q / 40, d = q % 40;
      const float* w = half ? s_wv : s_wk;
      float r = half ? blv[d] : blk[d];
      for (int e = 0; e < 40; e++) r += w[d * 40 + e] * s_cl[sl][e];
      if (half) s_v[sl][d] = r; else s_k[sl][d] = r;
    }
    __syncthreads();
    int ai = 0;
    for (int p = t; p < 1600; p += 256, ai++) {
      int d = p / 40, e = p % 40;
      float a = acc[ai];
      for (int sl = 0; sl < 8; sl++) a += s_k[sl][d] * s_v[sl][e];
      acc[ai] = a;
    }
  }
  int ai = 0;
  for (int p = t; p < 1600; p += 256, ai++)
    kvp[((long)(b * 25 + chunk)) * 1600 + p] = acc[ai];
}

__global__ void k_kv_reduce(const float* __restrict__ kvp, float* __restrict__ kv) {
  int i = blockIdx.x * blockDim.x + threadIdx.x;
  if (i >= 16 * 1600) return;
  int b = i / 1600, p = i % 1600;
  float s = 0.f;
  for (int c = 0; c < 25; c++) s += kvp[((long)(b * 25 + c)) * 1600 + p];
  kv[i] = s;
}

__global__ __launch_bounds__(256) void k_c1(const float* __restrict__ wcls,
                                            const float* __restrict__ bg, float* __restrict__ c1p) {
  __shared__ float red[256];
  int t = threadIdx.x;
  float s = 0.f;
  for (long i = (long)blockIdx.x * 256 + t; i < 480000; i += (long)gridDim.x * 256)
    s += wcls[i] * bg[i / 120];
  red[t] = s; __syncthreads();
  for (int o = 128; o > 0; o >>= 1) { if (t < o) red[t] += red[t + o]; __syncthreads(); }
  if (t == 0) c1p[blockIdx.x] = red[0];
}

// ---------------------------------------------------------------------------
// final combine per batch: y = [ sum_{tt,d,e} kv*(w_q U + b_q sv) + lsp residual ]/1024
__global__ __launch_bounds__(256) void k_combine(
    const float* __restrict__ Ufin, const float* __restrict__ kvb,
    const float* __restrict__ vmat, const float* __restrict__ lsp32,
    const float* __restrict__ wgq, const float* __restrict__ wpq, const float* __restrict__ wcq,
    const float* __restrict__ bgq, const float* __restrict__ bpq, const float* __restrict__ bcq,
    const float* __restrict__ svv, const float* __restrict__ c1p,
    const float* __restrict__ bcls, const float* __restrict__ bnw,
    const float* __restrict__ bnb, float* __restrict__ out) {
  __shared__ float s_kv[1600], s_U[4800], s_w[4400], s_bq[120], s_sv[120], s_red[256];
  int b = blockIdx.x, t = threadIdx.x;
  for (int p = t; p < 1600; p += 256) {
    s_kv[p] = kvb[b * 1600 + p];
    s_w[p] = wgq[p];
    s_w[2800 + p] = wcq[p];
  }
  for (int p = t; p < 1200; p += 256) s_w[1600 + p] = wpq[p];
  for (int p = t; p < 4800; p += 256) {
    int tt = p / 1600, r = p % 1600, j = r / 40, e = r % 40;
    float uv = 0.f;
    if (tt == 0) uv = Ufin[(b * 40 + j) * 40 + e];
    else if (tt == 1) { if (j < 30) uv = Ufin[(640 + b * 30 + j) * 40 + e]; }
    else uv = Ufin[(1152 + b * 40 + j) * 40 + e];
    s_U[p] = uv;
  }
  if (t < 40) { s_bq[t] = bgq[t]; s_bq[40 + t] = bpq[t]; s_bq[80 + t] = bcq[t]; }
  for (int p = t; p < 120; p += 256) s_sv[p] = svv[p];
  __syncthreads();
  float y = 0.f;
  for (int p = t; p < 4800; p += 256) {
    int tt = p / 1600, q = p % 1600, d = q / 40, e = q % 40;
    float T = 0.f;
    if (tt == 0) {
      for (int j = 0; j < 40; j++) T += s_w[d * 40 + j] * s_U[j * 40 + e];
    } else if (tt == 1) {
      for (int j = 0; j < 30; j++) T += s_w[1600 + d * 30 + j] * s_U[1600 + j * 40 + e];
    } else {
      for (int j = 0; j < 40; j++) T += s_w[2800 + d * 40 + j] * s_U[3200 + j * 40 + e];
    }
    y += s_kv[d * 40 + e] * (T + s_bq[tt * 40 + d] * s_sv[tt * 40 + e]);
  }
  // lsp residual
  for (int s = t; s < 4000; s += 256) {
    const f32x4* lp = (const f32x4*)(lsp32 + ((long)b * SEQN + s) * 40);
    const f32x4* vp = (const f32x4*)(vmat + (long)s * 120);
#pragma unroll
    for (int d4 = 0; d4 < 10; d4++) {
      f32x4 l = lp[d4];
      f32x4 vs = vp[d4] + vp[10 + d4] + vp[20 + d4];
      y += l[0] * vs[0] + l[1] * vs[1] + l[2] * vs[2] + l[3] * vs[3];
    }
  }
  s_red[t] = y; __syncthreads();
  for (int o = 128; o > 0; o >>= 1) { if (t < o) s_red[t] += s_red[t + o]; __syncthreads(); }
  if (t == 0) {
    float c1 = bcls[0];
    for (int i = 0; i < 120; i++) c1 += c1p[i];
    float yy = s_red[0] * (1.f / 1024.f) + c1;
    yy = yy * (bnw[0] * rsqrtf(1.f + 1e-5f)) + bnb[0];
    out[b] = 1.f / (1.f + expf(-yy));
  }
}

// ---------------------------------------------------------------------------
extern "C" void kernel_launch(void* const* d_in, const int* in_sizes, int n_in,
                              void* d_out, int out_size, void* d_ws, size_t ws_size,
                              hipStream_t stream) {
  const int*   X        = (const int*)d_in[0];
  const float* emb      = (const float*)d_in[1];
  const float* w_dwc_l  = (const float*)d_in[2];
  const float* b_dwc_l  = (const float*)d_in[3];
  const float* w_dwc_o  = (const float*)d_in[4];
  const float* b_dwc_o  = (const float*)d_in[5];
  const float* w_local  = (const float*)d_in[6];
  const float* b_local  = (const float*)d_in[7];
  const float* w_global = (const float*)d_in[8];
  const float* b_global = (const float*)d_in[9];
  const float* w_gq = (const float*)d_in[10];
  const float* b_gq = (const float*)d_in[11];
  const float* w_cq = (const float*)d_in[12];
  const float* b_cq = (const float*)d_in[13];
  const float* w_pq = (const float*)d_in[14];
  const float* b_pq = (const float*)d_in[15];
  const float* w_lk = (const float*)d_in[16];
  const float* b_lk = (const float*)d_in[17];
  const float* w_lv = (const float*)d_in[18];
  const float* b_lv = (const float*)d_in[19];
  const float* w_cls = (const float*)d_in[20];
  const float* b_cls = (const float*)d_in[21];
  const float* bn_w = (const float*)d_in[22];
  const float* bn_b = (const float*)d_in[23];
  float* out = (float*)d_out;

  char* ws = (char*)d_ws;
  size_t off = 0;
  auto alloc = [&](size_t bytes) -> void* {
    off = (off + 255) & ~(size_t)255;
    void* p = ws + off; off += bytes; return p;
  };

  const size_t sz_p40 = (size_t)7 * 16 * 42 * 800 * 2;
  const size_t sz_p30 = (size_t)7 * 16 * 32 * 800 * 2;
  f16* P_lsp = (f16*)alloc(sz_p40);
  f16* P_pit = (f16*)alloc(sz_p30);
  f16* P_cod = (f16*)alloc(sz_p40);
  f16* P_gai = (f16*)alloc(sz_p40);
  float* lsp32 = (float*)alloc((size_t)16 * 4000 * 40 * 4);
  f16* wp_lsp = (f16*)alloc((size_t)896 * 7200 * 2);
  f16* wlp    = (f16*)alloc((size_t)4000 * 4000 * 2);
  f16* wlT    = (f16*)alloc((size_t)4000 * 4000 * 2);     // reused as Cp later
  f16* wgT    = (f16*)alloc((size_t)4000 * 4000 * 2);
  f16* wcT    = (f16*)alloc((size_t)128 * 4000 * 2);
  f16* vT     = (f16*)alloc((size_t)128 * 4000 * 2);
  f16* co     = (f16*)alloc((size_t)640 * 4000 * 2);
  float* cl   = (float*)alloc((size_t)4000 * 640 * 4);
  float* vpart = (float*)alloc((size_t)5 * 480000 * 4);
  float* vmat  = (float*)alloc((size_t)480000 * 4);
  float* Vt    = (float*)alloc((size_t)480000 * 4);
  f16* vtT   = (f16*)alloc((size_t)640 * 800 * 2);
  f16* woT   = (f16*)alloc(((size_t)9 * 800 + 96) * 800 * 2);
  float* A9  = (float*)alloc((size_t)9 * 640 * 800 * 4);
  f16* Bp    = (f16*)alloc((size_t)7 * 120 * 2400 * 2);
  float* Upart = (float*)alloc((size_t)7 * 1792 * 40 * 4);
  float* Ufin  = (float*)alloc((size_t)1792 * 40 * 4);
  float* cbblv = (float*)alloc(120 * 4);
  float* svv   = (float*)alloc(120 * 4);
  float* kvp  = (float*)alloc((size_t)400 * 1600 * 4);
  float* kvb  = (float*)alloc((size_t)16 * 1600 * 4);
  float* c1p  = (float*)alloc(120 * 4);
  float* Cp = (float*)wlT;  // 3*3200*800*4 = 30.7MB <= 32MB, lifetime disjoint
  (void)ws_size; (void)in_sizes; (void)n_in; (void)out_size;

  // zero pad borders / tails
  hipMemsetAsync(P_lsp, 0, sz_p40, stream);
  hipMemsetAsync(P_pit, 0, sz_p30, stream);
  hipMemsetAsync(P_cod, 0, sz_p40, stream);
  hipMemsetAsync(P_gai, 0, sz_p40, stream);
  hipMemsetAsync(wcT + (size_t)120 * 4000, 0, (size_t)8 * 4000 * 2, stream);
  hipMemsetAsync(vT + (size_t)120 * 4000, 0, (size_t)8 * 4000 * 2, stream);

  // weight packs
  k_pack_wconv<<<2048, 256, 0, stream>>>(w_dwc_l, wp_lsp);
  k_pack_wlocal<<<8192, 256, 0, stream>>>(w_local, wlp);
  {
    dim3 g(125, 125), blk(32, 8);
    k_transpose_cast<<<g, blk, 0, stream>>>(w_local, wlT, 4000, 4000, 4000, 1.f);
    k_transpose_cast<<<g, blk, 0, stream>>>(w_global, wgT, 4000, 4000, 4000, 1.f);
  }
  {
    dim3 g(4, 125), blk(32, 8);
    k_transpose_cast<<<g, blk, 0, stream>>>(w_cls, wcT, 4000, 120, 4000, 1024.f);
  }
  k_pack_woT<<<2500, 256, 0, stream>>>(w_dwc_o, woT);

  // gather
  k_gather<<<(15 * 16 * 5 * 800 + 255) / 256, 256, 0, stream>>>(
      X, emb, P_lsp, P_pit, P_cod, P_gai, lsp32);

  // v = w_global^T @ (wc*1024), split-K 5
  {
    dim3 g(32, 5);
    k_gemm_nt<0><<<g, 256, 0, stream>>>(wgT, 4000, wcT, 4000, vpart, 120, nullptr,
                                        1, 32, 25, 125, 480000, 0, 0, 0, 4000, 120, 4000);
  }
  k_vred<<<1875, 256, 0, stream>>>(vpart, vmat);

  // Vt = w_local^T @ v, split-K 5
  {
    dim3 g(4, 125), blk(32, 8);
    k_transpose_cast<<<g, blk, 0, stream>>>(vmat, vT, 4000, 120, 4000, 1.f);
  }
  {
    dim3 g(32, 5);
    k_gemm_nt<0><<<g, 256, 0, stream>>>(wlT, 4000, vT, 4000, vpart, 120, nullptr,
                                        1, 32, 25, 125, 480000, 0, 0, 0, 4000, 120, 4000);
  }
  k_vred<<<1875, 256, 0, stream>>>(vpart, Vt);

  k_pack_vt<<<2000, 256, 0, stream>>>(Vt, vtT);
  k_consts<<<120, 256, 0, stream>>>(Vt, vmat, b_dwc_o, b_local, cbblv, svv);

  // A9[z][fe][gi] = sum_g vtT[fe][g]*woT[z][gi][g]
  {
    dim3 g(35, 1, 9);
    k_gemm_nt<0><<<g, 256, 0, stream>>>(vtT, 800, woT, 800, A9, 800, nullptr,
                                        7, 35, 25, 25, 0, 0, 640000, 512000, 640, 800, 640);
  }
  k_fold_bp<<<7875, 256, 0, stream>>>(A9, Bp);

  // lsp conv GEMM (split-K 3 over df) + reduce w/ bias
  {
    dim3 g(175, 3);
    k_gemm_conv<<<g, 256, 0, stream>>>(P_lsp, wp_lsp, Cp);
  }
  k_co_reduce<<<2500, 256, 0, stream>>>(Cp, b_dwc_l, co);

  // cl = w_local(permuted) @ co^T + b_local : [4000][640]
  k_gemm_nt<1><<<160, 256, 0, stream>>>(wlp, 4000, co, 4000, cl, 640, b_local,
                                        5, 160, 125, 125, 0, 0, 0, 0, 4000, 640, 4000);

  // kv
  {
    dim3 g(25, 16);
    k_kv_partial<<<g, 256, 0, stream>>>(cl, w_lk, b_lk, w_lv, b_lv, kvp);
  }
  k_kv_reduce<<<100, 256, 0, stream>>>(kvp, kvb);

  // U path
  {
    dim3 g(14, 7);
    k_gemm_u<<<g, 256, 0, stream>>>(P_gai, P_pit, P_cod, Bp, Upart);
  }
  k_ured<<<280, 256, 0, stream>>>(Upart, cbblv, Ufin);

  // c1
  k_c1<<<120, 256, 0, stream>>>(w_cls, b_global, c1p);

  // final combine (writes sigmoid output)
  k_combine<<<16, 256, 0, stream>>>(Ufin, kvb, vmat, lsp32,
                                    w_gq, w_pq, w_cq, b_gq, b_pq, b_cq,
                                    svv, c1p, b_cls, bn_w, bn_b, out);
}

// Round 4
// 695.802 us; speedup vs baseline: 1.2674x; 1.2674x over previous
//
#include <hip/hip_runtime.h>
#include <hip/hip_bf16.h>

typedef _Float16 f16;
typedef __attribute__((ext_vector_type(8))) _Float16 half8;
typedef __attribute__((ext_vector_type(4))) _Float16 half4;
typedef __attribute__((ext_vector_type(4))) float f32x4;

static const int BN = 16, SEQN = 4000;

// ---------------------------------------------------------------------------
__device__ __forceinline__ void gload_lds(f16* lds, const f16* g) {
  __builtin_amdgcn_global_load_lds((const __attribute__((address_space(1))) unsigned int*)g,
                                   (__attribute__((address_space(3))) unsigned int*)lds, 16, 0, 0);
}

// bijective XCD swizzle (m204)
__device__ __forceinline__ int xcd_swz(int orig, int nwg) {
  int q = nwg >> 3, r = nwg & 7, x = orig & 7, o = orig >> 3;
  return (x < r ? x * (q + 1) : r * (q + 1) + (x - r) * q) + o;
}

// ---------------------------------------------------------------------------
// packs (LDS row-permute: coalesced read + coalesced write)
// wp[o][tap*800+gi] = w[o][gi*9+tap]
__global__ __launch_bounds__(256) void k_pack_wconv(const float* __restrict__ in, f16* __restrict__ out) {
  __shared__ float r[7200];
  int o = blockIdx.x, t = threadIdx.x;
  for (int p = t; p < 7200; p += 256) r[p] = in[(long)o * 7200 + p];
  __syncthreads();
  for (int p = t; p < 7200; p += 256) {
    int tap = p / 800, gi = p % 800;
    out[(long)o * 7200 + p] = (f16)r[gi * 9 + tap];
  }
}

// wlp[s][f*800+g] = w_local[s][g*5+f]
__global__ __launch_bounds__(256) void k_pack_wlocal(const float* __restrict__ in, f16* __restrict__ out) {
  __shared__ float r[4000];
  int s = blockIdx.x, t = threadIdx.x;
  for (int p = t; p < 4000; p += 256) r[p] = in[(long)s * 4000 + p];
  __syncthreads();
  for (int p = t; p < 4000; p += 256) {
    int f = p / 800, g = p % 800;
    out[(long)s * 4000 + p] = (f16)r[g * 5 + f];
  }
}

// out[c*ldo + r] = in[r*C + c] * scale
__global__ void k_transpose_cast(const float* __restrict__ in, f16* __restrict__ out,
                                 int R, int C, int ldo, float scale) {
  __shared__ float tile[32][33];
  int c0 = blockIdx.x * 32, r0 = blockIdx.y * 32;
  for (int i = threadIdx.y; i < 32; i += 8) {
    int r = r0 + i, c = c0 + threadIdx.x;
    tile[i][threadIdx.x] = (r < R && c < C) ? in[(long)r * C + c] : 0.f;
  }
  __syncthreads();
  for (int i = threadIdx.y; i < 32; i += 8) {
    int c = c0 + i, r = r0 + threadIdx.x;
    if (c < C && r < R) out[(long)c * ldo + r] = (f16)(tile[threadIdx.x][i] * scale);
  }
}

// woT[z][gi][g] = w_dwc_other[g*7200 + gi*9 + z]
__global__ void k_pack_woT(const float* __restrict__ in, f16* __restrict__ out) {
  int id = blockIdx.x * blockDim.x + threadIdx.x;
  if (id >= 640000) return;
  int g = id / 800, gi = id % 800;
  const float* src = in + (long)g * 7200 + gi * 9;
#pragma unroll
  for (int z = 0; z < 9; z++)
    out[(long)z * 640000 + gi * 800 + g] = (f16)src[z];
}

// vtT[(f*120+e)][g] = Vt[(g*5+f)*120+e]; rows >=600 zero
__global__ void k_pack_vt(const float* __restrict__ Vt, f16* __restrict__ out) {
  int id = blockIdx.x * blockDim.x + threadIdx.x;
  if (id >= 640 * 800) return;
  int fe = id / 800, g = id % 800;
  f16 v = (f16)0.f;
  if (fe < 600) {
    int f = fe / 120, e = fe % 120;
    v = (f16)Vt[(long)(g * 5 + f) * 120 + e];
  }
  out[id] = v;
}

// ---------------------------------------------------------------------------
// gather: P[fp][b][ep][g] layout (g innermost)
__global__ void k_gather(const int* __restrict__ X, const float* __restrict__ emb,
                         f16* __restrict__ P_lsp, f16* __restrict__ P_pit,
                         f16* __restrict__ P_cod, f16* __restrict__ P_gai,
                         float* __restrict__ lsp32) {
  const float scale[15] = {1.f,1.f,1.f,1.f,0.8f,0.512f,0.8f,0.64f,0.512f,0.64f,0.512f,0.8f,0.64f,0.512f,0.512f};
  const int br[15] = {0,0,0,0,1,1,2,2,3,3,1,2,2,3,3};
  const int po[15] = {0,1,2,3,0,1,0,1,0,2,2,2,3,1,3};
  int id = blockIdx.x * blockDim.x + threadIdx.x;
  if (id >= 15 * 16 * 5 * 800) return;
  int g = id % 800; int tmp = id / 800;
  int f = tmp % 5; tmp /= 5;
  int b = tmp % 16; int c = tmp / 16;
  int s = g * 5 + f;
  int idx = X[((long)b * SEQN + s) * 15 + c];
  const float* er = emb + (long)idx * 10;
  int t = br[c], p = po[c];
  f16* P = (t == 0) ? P_lsp : (t == 1) ? P_pit : (t == 2) ? P_cod : P_gai;
  int Wp = (t == 1) ? 32 : 42;
  f16* base = P + ((long)((f + 1) * 16 + b) * Wp + (1 + p * 10)) * 800 + g;
  float sc = scale[c];
#pragma unroll
  for (int j = 0; j < 10; j++) {
    float v = er[j] * sc;
    base[(long)j * 800] = (f16)v;
    if (t == 0) lsp32[((long)b * SEQN + s) * 40 + p * 10 + j] = v;
  }
}

// ---------------------------------------------------------------------------
// lsp conv GEMM, split-K 9 (one tap per z). M=3200=(f,b,e), N=800(pad896),
// dbuf single-barrier loop. Partials -> Cp[z][3200][800] fp32.
__global__ __launch_bounds__(256) void k_gemm_conv(
    const f16* __restrict__ P, const f16* __restrict__ wp, float* __restrict__ Cp) {
  __shared__ __align__(16) f16 As[2][4096];
  __shared__ __align__(16) f16 Bs[2][4096];
  int lin = xcd_swz(blockIdx.x, 175);
  int nx = lin % 7, my = lin / 7;
  int m0 = my * 128, n0 = nx * 128;
  int z = blockIdx.y;
  int df = z / 3, de = z % 3;
  Cp += (long)z * 3200 * 800;
  int t = threadIdx.x;
  const f16 *ap0, *ap1, *bp0, *bp1;
  {
    int r0 = t >> 2, r1 = 64 + (t >> 2);
    int m = m0 + r0;
    int f = m / 640, r = m % 640, b = r / 40, e = r % 40;
    ap0 = P + ((long)((f + df) * 16 + b) * 42 + (e + de)) * 800 + (t & 3) * 8;
    m = m0 + r1;
    f = m / 640; r = m % 640; b = r / 40; e = r % 40;
    ap1 = P + ((long)((f + df) * 16 + b) * 42 + (e + de)) * 800 + (t & 3) * 8;
    bp0 = wp + (long)(n0 + r0) * 7200 + z * 800 + (t & 3) * 8;
    bp1 = wp + (long)(n0 + r1) * 7200 + z * 800 + (t & 3) * 8;
  }
  int lane = t & 63, wv = t >> 6;
  int wm = (wv >> 1) * 64, wn = (wv & 1) * 64;
  int l15 = lane & 15, kg = lane >> 4;
  f32x4 acc[4][4] = {};
  gload_lds(&As[0][t * 8], ap0); gload_lds(&As[0][2048 + t * 8], ap1);
  gload_lds(&Bs[0][t * 8], bp0); gload_lds(&Bs[0][2048 + t * 8], bp1);
  __syncthreads();
  int cur = 0;
  for (int kt = 0; kt < 25; kt++) {
    if (kt + 1 < 25) {
      int o = (kt + 1) * 32, nb = cur ^ 1;
      gload_lds(&As[nb][t * 8], ap0 + o); gload_lds(&As[nb][2048 + t * 8], ap1 + o);
      gload_lds(&Bs[nb][t * 8], bp0 + o); gload_lds(&Bs[nb][2048 + t * 8], bp1 + o);
    }
    half8 av[4], bv[4];
#pragma unroll
    for (int i = 0; i < 4; i++) {
      av[i] = *(const half8*)(&As[cur][(wm + i * 16 + l15) * 32 + kg * 8]);
      bv[i] = *(const half8*)(&Bs[cur][(wn + i * 16 + l15) * 32 + kg * 8]);
    }
#pragma unroll
    for (int i = 0; i < 4; i++)
#pragma unroll
      for (int j = 0; j < 4; j++)
        acc[i][j] = __builtin_amdgcn_mfma_f32_16x16x32_f16(av[i], bv[j], acc[i][j], 0, 0, 0);
    __syncthreads();
    cur ^= 1;
  }
#pragma unroll
  for (int i = 0; i < 4; i++) {
    int mb = m0 + wm + i * 16 + kg * 4;
#pragma unroll
    for (int j = 0; j < 4; j++) {
      int n = n0 + wn + j * 16 + l15;
      if (n >= 800) continue;
      f32x4 d = acc[i][j];
#pragma unroll
      for (int r = 0; r < 4; r++)
        Cp[(long)(mb + r) * 800 + n] = d[r];
    }
  }
}

// co[(b*40+e)][f*800+n] = f16( sum_z Cp[z][m][n] + bias[n] )
__global__ void k_co_reduce(const float* __restrict__ Cp, const float* __restrict__ bias,
                            f16* __restrict__ co) {
  int id = blockIdx.x * blockDim.x + threadIdx.x;
  if (id >= 640000) return;
  int m = id / 200, n4 = (id % 200) * 4;
  long o = (long)m * 800 + n4;
  f32x4 s = *(const f32x4*)&bias[n4];
#pragma unroll
  for (int z = 0; z < 9; z++) s += *(const f32x4*)&Cp[(long)z * 2560000 + o];
  int f = m / 640, r2 = m % 640;
  half4 h = {(f16)s[0], (f16)s[1], (f16)s[2], (f16)s[3]};
  *(half4*)&co[(long)r2 * 4000 + f * 800 + n4] = h;
}

// ---------------------------------------------------------------------------
// generic NT GEMM (f16 in, fp32 out), dbuf single-barrier, split-K + z-slices.
__global__ __launch_bounds__(256) void k_gemm_nt(
    const f16* __restrict__ A, int lda, const f16* __restrict__ Bm, int ldb,
    float* __restrict__ C, int ldc,
    int gx, int nwg, int nkt, int KTtot, long cslice, long az, long bz, long cz,
    int Mreal, int Nreal, int Aclamp) {
  __shared__ __align__(16) f16 As[2][4096];
  __shared__ __align__(16) f16 Bs[2][4096];
  A += (long)blockIdx.z * az;
  Bm += (long)blockIdx.z * bz;
  C += (long)blockIdx.z * cz + (long)blockIdx.y * cslice;
  int lin = xcd_swz(blockIdx.x, nwg);
  int nx = lin % gx, my = lin / gx;
  int m0 = my * 128, n0 = nx * 128;
  int kt0 = blockIdx.y * nkt;
  int ktn = nkt; if (kt0 + ktn > KTtot) ktn = KTtot - kt0;
  int t = threadIdx.x;
  const f16 *ap0, *ap1, *bp0, *bp1;
  {
    int r0 = t >> 2, r1 = 64 + (t >> 2);
    int ra0 = m0 + r0; if (ra0 >= Aclamp) ra0 = Aclamp - 1;
    int ra1 = m0 + r1; if (ra1 >= Aclamp) ra1 = Aclamp - 1;
    ap0 = A + (long)ra0 * lda + (long)kt0 * 32 + (t & 3) * 8;
    ap1 = A + (long)ra1 * lda + (long)kt0 * 32 + (t & 3) * 8;
    bp0 = Bm + (long)(n0 + r0) * ldb + (long)kt0 * 32 + (t & 3) * 8;
    bp1 = Bm + (long)(n0 + r1) * ldb + (long)kt0 * 32 + (t & 3) * 8;
  }
  int lane = t & 63, wv = t >> 6;
  int wm = (wv >> 1) * 64, wn = (wv & 1) * 64;
  int l15 = lane & 15, kg = lane >> 4;
  f32x4 acc[4][4] = {};
  gload_lds(&As[0][t * 8], ap0); gload_lds(&As[0][2048 + t * 8], ap1);
  gload_lds(&Bs[0][t * 8], bp0); gload_lds(&Bs[0][2048 + t * 8], bp1);
  __syncthreads();
  int cur = 0;
  for (int kt = 0; kt < ktn; kt++) {
    if (kt + 1 < ktn) {
      int o = (kt + 1) * 32, nb = cur ^ 1;
      gload_lds(&As[nb][t * 8], ap0 + o); gload_lds(&As[nb][2048 + t * 8], ap1 + o);
      gload_lds(&Bs[nb][t * 8], bp0 + o); gload_lds(&Bs[nb][2048 + t * 8], bp1 + o);
    }
    half8 av[4], bv[4];
#pragma unroll
    for (int i = 0; i < 4; i++) {
      av[i] = *(const half8*)(&As[cur][(wm + i * 16 + l15) * 32 + kg * 8]);
      bv[i] = *(const half8*)(&Bs[cur][(wn + i * 16 + l15) * 32 + kg * 8]);
    }
#pragma unroll
    for (int i = 0; i < 4; i++)
#pragma unroll
      for (int j = 0; j < 4; j++)
        acc[i][j] = __builtin_amdgcn_mfma_f32_16x16x32_f16(av[i], bv[j], acc[i][j], 0, 0, 0);
    __syncthreads();
    cur ^= 1;
  }
#pragma unroll
  for (int i = 0; i < 4; i++) {
    int mb = m0 + wm + i * 16 + kg * 4;
#pragma unroll
    for (int j = 0; j < 4; j++) {
      int n = n0 + wn + j * 16 + l15;
      if (n >= Nreal) continue;
      f32x4 d = acc[i][j];
#pragma unroll
      for (int r = 0; r < 4; r++) {
        int m = mb + r;
        if (m >= Mreal) continue;
        C[(long)m * ldc + n] = d[r];
      }
    }
  }
}

// ---------------------------------------------------------------------------
// TN GEMM: C[m][n] = sum_k A[m*lda+k](f16) * B[k*ldb+n](f32). Single M-tile.
// B staged transposed through LDS (pad-36 rows). splitK via blockIdx.y.
__global__ __launch_bounds__(256) void k_gemm_tn(
    const f16* __restrict__ A, int lda, const float* __restrict__ B, int ldb,
    float* __restrict__ C, int ldc, int nkt, int KTtot, long cslice,
    int Mreal, int Nreal) {
  __shared__ __align__(16) f16 As[4096];
  __shared__ __align__(16) f16 Bs[128 * 36];
  int n0 = blockIdx.x * 128;
  int kt0 = blockIdx.y * nkt;
  int ktn = nkt; if (kt0 + ktn > KTtot) ktn = KTtot - kt0;
  C += (long)blockIdx.y * cslice;
  int t = threadIdx.x;
  const f16 *ap0, *ap1;
  {
    int r0 = t >> 2, r1 = 64 + (t >> 2);
    if (r0 >= Mreal) r0 = Mreal - 1;
    if (r1 >= Mreal) r1 = Mreal - 1;
    ap0 = A + (long)r0 * lda + (long)kt0 * 32 + (t & 3) * 8;
    ap1 = A + (long)r1 * lda + (long)kt0 * 32 + (t & 3) * 8;
  }
  int lane = t & 63, wv = t >> 6;
  int wm = (wv >> 1) * 64, wn = (wv & 1) * 64;
  int l15 = lane & 15, kg = lane >> 4;
  f32x4 acc[4][4] = {};
  for (int kt = 0; kt < ktn; kt++) {
    float rb[4][4];
    int nli[4], kqi[4];
#pragma unroll
    for (int i = 0; i < 4; i++) {
      int id = i * 256 + t;
      nli[i] = id & 127; kqi[i] = id >> 7;
      int gn = n0 + nli[i]; if (gn >= Nreal) gn = Nreal - 1;
      long kb = ((long)(kt0 + kt) * 32 + kqi[i] * 4);
#pragma unroll
      for (int j = 0; j < 4; j++) rb[i][j] = B[(kb + j) * ldb + gn];
    }
    __syncthreads();
    gload_lds(&As[t * 8], ap0 + kt * 32);
    gload_lds(&As[2048 + t * 8], ap1 + kt * 32);
#pragma unroll
    for (int i = 0; i < 4; i++) {
      half4 h = {(f16)rb[i][0], (f16)rb[i][1], (f16)rb[i][2], (f16)rb[i][3]};
      *(half4*)&Bs[nli[i] * 36 + kqi[i] * 4] = h;
    }
    __syncthreads();
    half8 av[4], bv[4];
#pragma unroll
    for (int i = 0; i < 4; i++) {
      av[i] = *(const half8*)(&As[(wm + i * 16 + l15) * 32 + kg * 8]);
      bv[i] = *(const half8*)(&Bs[(wn + i * 16 + l15) * 36 + kg * 8]);
    }
#pragma unroll
    for (int i = 0; i < 4; i++)
#pragma unroll
      for (int j = 0; j < 4; j++)
        acc[i][j] = __builtin_amdgcn_mfma_f32_16x16x32_f16(av[i], bv[j], acc[i][j], 0, 0, 0);
  }
#pragma unroll
  for (int i = 0; i < 4; i++) {
    int mb = wm + i * 16 + kg * 4;
#pragma unroll
    for (int j = 0; j < 4; j++) {
      int n = n0 + wn + j * 16 + l15;
      if (n >= Nreal) continue;
      f32x4 d = acc[i][j];
#pragma unroll
      for (int r = 0; r < 4; r++) {
        int m = mb + r;
        if (m >= Mreal) continue;
        C[(long)m * ldc + n] = d[r];
      }
    }
  }
}

// out[s*120+e] = sum_z vp[z][e][s]   (transposing reduce)
__global__ void k_vredT(const float* __restrict__ vp, float* __restrict__ v, int nz) {
  int i = blockIdx.x * blockDim.x + threadIdx.x;
  if (i >= 480000) return;
  int s = i / 120, e = i % 120;
  float sum = 0.f;
  for (int z = 0; z < nz; z++) sum += vp[(long)z * 480000 + (long)e * 4000 + s];
  v[i] = sum;
}

// cl[m][n] = sum_z Clp[z][m][n] + b_local[m]
__global__ void k_cl_reduce(const float* __restrict__ Clp, const float* __restrict__ bl,
                            float* __restrict__ cl) {
  int id = blockIdx.x * blockDim.x + threadIdx.x;
  if (id >= 640000) return;
  int m = id / 160, n4 = (id % 160) * 4;
  long o = (long)m * 640 + n4;
  f32x4 s = {0.f, 0.f, 0.f, 0.f};
#pragma unroll
  for (int z = 0; z < 8; z++) s += *(const f32x4*)&Clp[(long)z * 2560000 + o];
  float b = bl[m];
  s += (f32x4){b, b, b, b};
  *(f32x4*)&cl[o] = s;
}

// ---------------------------------------------------------------------------
// Bp[fp][eg][dw*800+gi] = f16( sum_dh A9[(dh*3+dw)][ (fp-dh)*120+eg ][gi] )
__global__ void k_fold_bp(const float* __restrict__ A9, f16* __restrict__ Bp) {
  int id = blockIdx.x * blockDim.x + threadIdx.x;
  if (id >= 7 * 120 * 2400) return;
  int fp = id / 288000;
  int r = id % 288000;
  int eg = r / 2400, k = r % 2400;
  int dw = k / 800, gi = k % 800;
  float s = 0.f;
#pragma unroll
  for (int dh = 0; dh < 3; dh++) {
    int f = fp - dh;
    if (f >= 0 && f < 5)
      s += A9[((long)(dh * 3 + dw) * 640 + f * 120 + eg) * 800 + gi];
  }
  Bp[id] = (f16)s;
}

// ---------------------------------------------------------------------------
// U GEMM: Upart[y=(fp,zk)][m][e], dbuf, split-K 3 (zk over dw)
__global__ __launch_bounds__(256) void k_gemm_u(
    const f16* __restrict__ Pg, const f16* __restrict__ Pp, const f16* __restrict__ Pc,
    const f16* __restrict__ Bp, float* __restrict__ Upart) {
  __shared__ __align__(16) f16 As[2][4096];
  __shared__ __align__(16) f16 Bs[2][4096];
  int m0 = blockIdx.x * 128;
  int y = blockIdx.y, fp = y / 3, zk = y % 3;
  int kt0 = zk * 25;
  const f16* P; int seg0, jw, Wp, e0;
  if (m0 < 640)       { seg0 = 0;    jw = 40; Wp = 42; e0 = 0;  P = Pg; }
  else if (m0 < 1152) { seg0 = 640;  jw = 30; Wp = 32; e0 = 40; P = Pp; }
  else                { seg0 = 1152; jw = 40; Wp = 42; e0 = 80; P = Pc; }
  P += (long)fp * 16 * Wp * 800;
  int t = threadIdx.x;
  const f16 *ap0, *ap1, *bp0, *bp1;
  {
    int r0 = t >> 2, r1 = 64 + (t >> 2);
    int l0 = m0 + r0 - seg0; if (l0 >= 16 * jw) l0 = 0;
    int l1 = m0 + r1 - seg0; if (l1 >= 16 * jw) l1 = 0;
    ap0 = P + ((long)(l0 / jw) * Wp + (l0 % jw)) * 800 + (long)kt0 * 32 + (t & 3) * 8;
    ap1 = P + ((long)(l1 / jw) * Wp + (l1 % jw)) * 800 + (long)kt0 * 32 + (t & 3) * 8;
    int rn0 = r0 < 40 ? r0 : 39, rn1 = r1 < 40 ? r1 : 39;
    bp0 = Bp + ((long)fp * 120 + e0 + rn0) * 2400 + (long)kt0 * 32 + (t & 3) * 8;
    bp1 = Bp + ((long)fp * 120 + e0 + rn1) * 2400 + (long)kt0 * 32 + (t & 3) * 8;
  }
  int lane = t & 63, wv = t >> 6;
  int wm = (wv >> 1) * 64, wn = (wv & 1) * 64;
  int l15 = lane & 15, kg = lane >> 4;
  f32x4 acc[4][4] = {};
  gload_lds(&As[0][t * 8], ap0); gload_lds(&As[0][2048 + t * 8], ap1);
  gload_lds(&Bs[0][t * 8], bp0); gload_lds(&Bs[0][2048 + t * 8], bp1);
  __syncthreads();
  int cur = 0;
  for (int kt = 0; kt < 25; kt++) {
    if (kt + 1 < 25) {
      int o = (kt + 1) * 32, nb = cur ^ 1;
      gload_lds(&As[nb][t * 8], ap0 + o); gload_lds(&As[nb][2048 + t * 8], ap1 + o);
      gload_lds(&Bs[nb][t * 8], bp0 + o); gload_lds(&Bs[nb][2048 + t * 8], bp1 + o);
    }
    half8 av[4], bv[4];
#pragma unroll
    for (int i = 0; i < 4; i++) {
      av[i] = *(const half8*)(&As[cur][(wm + i * 16 + l15) * 32 + kg * 8]);
      bv[i] = *(const half8*)(&Bs[cur][(wn + i * 16 + l15) * 32 + kg * 8]);
    }
#pragma unroll
    for (int i = 0; i < 4; i++)
#pragma unroll
      for (int j = 0; j < 4; j++)
        acc[i][j] = __builtin_amdgcn_mfma_f32_16x16x32_f16(av[i], bv[j], acc[i][j], 0, 0, 0);
    __syncthreads();
    cur ^= 1;
  }
#pragma unroll
  for (int i = 0; i < 4; i++) {
    int mb = m0 + wm + i * 16 + kg * 4;
#pragma unroll
    for (int j = 0; j < 4; j++) {
      int n = wn + j * 16 + l15;
      if (n >= 40) continue;
      f32x4 d = acc[i][j];
#pragma unroll
      for (int r = 0; r < 4; r++) {
        int m = mb + r;
        if (m - seg0 >= 16 * jw) continue;
        Upart[((long)y * 1792 + m) * 40 + n] = d[r];
      }
    }
  }
}

// Ufin[m][e] = sum_y Upart + cbblv[e0(m)+e]
__global__ void k_ured(const float* __restrict__ Upart, const float* __restrict__ cbblv,
                       float* __restrict__ Ufin) {
  int id = blockIdx.x * blockDim.x + threadIdx.x;
  if (id >= 1792 * 40) return;
  int m = id / 40, e = id % 40;
  int e0 = m < 640 ? 0 : (m < 1152 ? 40 : 80);
  float s = cbblv[e0 + e];
  for (int y = 0; y < 21; y++) s += Upart[(long)y * 71680 + id];
  Ufin[id] = s;
}

// cbblv[e] = sum_s bconv_o[s/5]*Vt[s,e] + b_local[s]*v[s,e]; svv[e]=sum_s v[s,e]
__global__ __launch_bounds__(256) void k_consts(
    const float* __restrict__ Vt, const float* __restrict__ vmat,
    const float* __restrict__ bconv, const float* __restrict__ blocal,
    float* __restrict__ cbblv, float* __restrict__ svv) {
  __shared__ float r1[256], r2[256];
  int e = blockIdx.x, t = threadIdx.x;
  float a = 0.f, b = 0.f;
  for (int s = t; s < 4000; s += 256) {
    a += bconv[s / 5] * Vt[(long)s * 120 + e] + blocal[s] * vmat[(long)s * 120 + e];
    b += vmat[(long)s * 120 + e];
  }
  r1[t] = a; r2[t] = b; __syncthreads();
  for (int o = 128; o > 0; o >>= 1) {
    if (t < o) { r1[t] += r1[t + o]; r2[t] += r2[t + o]; }
    __syncthreads();
  }
  if (t == 0) { cbblv[e] = r1[0]; svv[e] = r2[0]; }
}

// ---------------------------------------------------------------------------
__global__ __launch_bounds__(256) void k_kv_partial(
    const float* __restrict__ cl, const float* __restrict__ wlk, const float* __restrict__ blk,
    const float* __restrict__ wlv, const float* __restrict__ blv, float* __restrict__ kvp) {
  __shared__ float s_wk[1600], s_wv[1600];
  __shared__ float s_cl[8][40], s_k[8][40], s_v[8][40];
  int t = threadIdx.x, chunk = blockIdx.x, b = blockIdx.y;
  for (int p = t; p < 1600; p += 256) { s_wk[p] = wlk[p]; s_wv[p] = wlv[p]; }
  float acc[7] = {0.f, 0.f, 0.f, 0.f, 0.f, 0.f, 0.f};
  for (int c8 = 0; c8 < 20; c8++) {
    int sb = chunk * 160 + c8 * 8;
    __syncthreads();
    for (int p = t; p < 320; p += 256) {
      int sl = p / 40, e = p % 40;
      s_cl[sl][e] = cl[(long)(sb + sl) * 640 + b * 40 + e];
    }
    __syncthreads();
    for (int p = t; p < 640; p += 256) {
      int half = p / 320, q = p % 320, sl = q / 40, d = q % 40;
      const float* w = half ? s_wv : s_wk;
      float r = half ? blv[d] : blk[d];
      for (int e = 0; e < 40; e++) r += w[d * 40 + e] * s_cl[sl][e];
      if (half) s_v[sl][d] = r; else s_k[sl][d] = r;
    }
    __syncthreads();
    int ai = 0;
    for (int p = t; p < 1600; p += 256, ai++) {
      int d = p / 40, e = p % 40;
      float a = acc[ai];
      for (int sl = 0; sl < 8; sl++) a += s_k[sl][d] * s_v[sl][e];
      acc[ai] = a;
    }
  }
  int ai = 0;
  for (int p = t; p < 1600; p += 256, ai++)
    kvp[((long)(b * 25 + chunk)) * 1600 + p] = acc[ai];
}

__global__ void k_kv_reduce(const float* __restrict__ kvp, float* __restrict__ kv) {
  int i = blockIdx.x * blockDim.x + threadIdx.x;
  if (i >= 16 * 1600) return;
  int b = i / 1600, p = i % 1600;
  float s = 0.f;
  for (int c = 0; c < 25; c++) s += kvp[((long)(b * 25 + c)) * 1600 + p];
  kv[i] = s;
}

__global__ __launch_bounds__(256) void k_c1(const float* __restrict__ wcls,
                                            const float* __restrict__ bg, float* __restrict__ c1p) {
  __shared__ float red[256];
  int t = threadIdx.x;
  float s = 0.f;
  for (long i = (long)blockIdx.x * 256 + t; i < 480000; i += (long)gridDim.x * 256)
    s += wcls[i] * bg[i / 120];
  red[t] = s; __syncthreads();
  for (int o = 128; o > 0; o >>= 1) { if (t < o) red[t] += red[t + o]; __syncthreads(); }
  if (t == 0) c1p[blockIdx.x] = red[0];
}

// ---------------------------------------------------------------------------
__global__ __launch_bounds__(256) void k_combine(
    const float* __restrict__ Ufin, const float* __restrict__ kvb,
    const float* __restrict__ vmat, const float* __restrict__ lsp32,
    const float* __restrict__ wgq, const float* __restrict__ wpq, const float* __restrict__ wcq,
    const float* __restrict__ bgq, const float* __restrict__ bpq, const float* __restrict__ bcq,
    const float* __restrict__ svv, const float* __restrict__ c1p,
    const float* __restrict__ bcls, const float* __restrict__ bnw,
    const float* __restrict__ bnb, float* __restrict__ out) {
  __shared__ float s_kv[1600], s_U[4800], s_w[4400], s_bq[120], s_sv[120], s_red[256];
  int b = blockIdx.x, t = threadIdx.x;
  for (int p = t; p < 1600; p += 256) {
    s_kv[p] = kvb[b * 1600 + p];
    s_w[p] = wgq[p];
    s_w[2800 + p] = wcq[p];
  }
  for (int p = t; p < 1200; p += 256) s_w[1600 + p] = wpq[p];
  for (int p = t; p < 4800; p += 256) {
    int tt = p / 1600, r = p % 1600, j = r / 40, e = r % 40;
    float uv = 0.f;
    if (tt == 0) uv = Ufin[(b * 40 + j) * 40 + e];
    else if (tt == 1) { if (j < 30) uv = Ufin[(640 + b * 30 + j) * 40 + e]; }
    else uv = Ufin[(1152 + b * 40 + j) * 40 + e];
    s_U[p] = uv;
  }
  if (t < 40) { s_bq[t] = bgq[t]; s_bq[40 + t] = bpq[t]; s_bq[80 + t] = bcq[t]; }
  for (int p = t; p < 120; p += 256) s_sv[p] = svv[p];
  __syncthreads();
  float y = 0.f;
  for (int p = t; p < 4800; p += 256) {
    int tt = p / 1600, q = p % 1600, d = q / 40, e = q % 40;
    float T = 0.f;
    if (tt == 0) {
      for (int j = 0; j < 40; j++) T += s_w[d * 40 + j] * s_U[j * 40 + e];
    } else if (tt == 1) {
      for (int j = 0; j < 30; j++) T += s_w[1600 + d * 30 + j] * s_U[1600 + j * 40 + e];
    } else {
      for (int j = 0; j < 40; j++) T += s_w[2800 + d * 40 + j] * s_U[3200 + j * 40 + e];
    }
    y += s_kv[d * 40 + e] * (T + s_bq[tt * 40 + d] * s_sv[tt * 40 + e]);
  }
  for (int s = t; s < 4000; s += 256) {
    const f32x4* lp = (const f32x4*)(lsp32 + ((long)b * SEQN + s) * 40);
    const f32x4* vp = (const f32x4*)(vmat + (long)s * 120);
#pragma unroll
    for (int d4 = 0; d4 < 10; d4++) {
      f32x4 l = lp[d4];
      f32x4 vs = vp[d4] + vp[10 + d4] + vp[20 + d4];
      y += l[0] * vs[0] + l[1] * vs[1] + l[2] * vs[2] + l[3] * vs[3];
    }
  }
  s_red[t] = y; __syncthreads();
  for (int o = 128; o > 0; o >>= 1) { if (t < o) s_red[t] += s_red[t + o]; __syncthreads(); }
  if (t == 0) {
    float c1 = bcls[0];
    for (int i = 0; i < 120; i++) c1 += c1p[i];
    float yy = s_red[0] * (1.f / 1024.f) + c1;
    yy = yy * (bnw[0] * rsqrtf(1.f + 1e-5f)) + bnb[0];
    out[b] = 1.f / (1.f + expf(-yy));
  }
}

// ---------------------------------------------------------------------------
extern "C" void kernel_launch(void* const* d_in, const int* in_sizes, int n_in,
                              void* d_out, int out_size, void* d_ws, size_t ws_size,
                              hipStream_t stream) {
  const int*   X        = (const int*)d_in[0];
  const float* emb      = (const float*)d_in[1];
  const float* w_dwc_l  = (const float*)d_in[2];
  const float* b_dwc_l  = (const float*)d_in[3];
  const float* w_dwc_o  = (const float*)d_in[4];
  const float* b_dwc_o  = (const float*)d_in[5];
  const float* w_local  = (const float*)d_in[6];
  const float* b_local  = (const float*)d_in[7];
  const float* w_global = (const float*)d_in[8];
  const float* b_global = (const float*)d_in[9];
  const float* w_gq = (const float*)d_in[10];
  const float* b_gq = (const float*)d_in[11];
  const float* w_cq = (const float*)d_in[12];
  const float* b_cq = (const float*)d_in[13];
  const float* w_pq = (const float*)d_in[14];
  const float* b_pq = (const float*)d_in[15];
  const float* w_lk = (const float*)d_in[16];
  const float* b_lk = (const float*)d_in[17];
  const float* w_lv = (const float*)d_in[18];
  const float* b_lv = (const float*)d_in[19];
  const float* w_cls = (const float*)d_in[20];
  const float* b_cls = (const float*)d_in[21];
  const float* bn_w = (const float*)d_in[22];
  const float* bn_b = (const float*)d_in[23];
  float* out = (float*)d_out;

  char* ws = (char*)d_ws;
  size_t off = 0;
  auto alloc = [&](size_t bytes) -> void* {
    off = (off + 255) & ~(size_t)255;
    void* p = ws + off; off += bytes; return p;
  };

  const size_t sz_p40 = (size_t)7 * 16 * 42 * 800 * 2;
  const size_t sz_p30 = (size_t)7 * 16 * 32 * 800 * 2;
  f16* P_lsp = (f16*)alloc(sz_p40);
  f16* P_pit = (f16*)alloc(sz_p30);
  f16* P_cod = (f16*)alloc(sz_p40);
  f16* P_gai = (f16*)alloc(sz_p40);
  float* lsp32 = (float*)alloc((size_t)16 * 4000 * 40 * 4);
  f16* wp_lsp = (f16*)alloc((size_t)896 * 7200 * 2);
  f16* wlp    = (f16*)alloc((size_t)4000 * 4000 * 2);
  f16* wcT    = (f16*)alloc((size_t)128 * 4000 * 2);
  f16* vT     = (f16*)alloc((size_t)128 * 4000 * 2);
  f16* co     = (f16*)alloc((size_t)640 * 4000 * 2);
  float* cl   = (float*)alloc((size_t)4000 * 640 * 4);
  float* vmat  = (float*)alloc((size_t)480000 * 4);
  float* Vt    = (float*)alloc((size_t)480000 * 4);
  f16* vtT   = (f16*)alloc((size_t)640 * 800 * 2);
  f16* Bp    = (f16*)alloc((size_t)7 * 120 * 2400 * 2);
  float* Upart = (float*)alloc((size_t)21 * 1792 * 40 * 4);
  float* Ufin  = (float*)alloc((size_t)1792 * 40 * 4);
  float* cbblv = (float*)alloc(120 * 4);
  float* svv   = (float*)alloc(120 * 4);
  float* kvp  = (float*)alloc((size_t)400 * 1600 * 4);
  float* kvb  = (float*)alloc((size_t)16 * 1600 * 4);
  float* c1p  = (float*)alloc(120 * 4);
  // big arena: Cp [9][3200][800] fp32 = 92.16MB; A9/woT/vpart/Clp alias inside
  float* Cp = (float*)alloc((size_t)9 * 3200 * 800 * 4);
  float* A9   = Cp;                                    // 18.43MB, dead before conv
  f16*   woT  = (f16*)((char*)Cp + 18500000);          // 11.67MB, dead before conv
  float* vpart = (float*)((char*)Cp + 30200000);       // 19.2MB, dead before conv
  float* Clp  = Cp;                                    // 81.9MB, after co_reduce
  (void)ws_size; (void)in_sizes; (void)n_in; (void)out_size;

  // zero pad borders
  hipMemsetAsync(P_lsp, 0, sz_p40, stream);
  hipMemsetAsync(P_pit, 0, sz_p30, stream);
  hipMemsetAsync(P_cod, 0, sz_p40, stream);
  hipMemsetAsync(P_gai, 0, sz_p40, stream);

  // packs
  k_pack_wconv<<<800, 256, 0, stream>>>(w_dwc_l, wp_lsp);
  hipMemsetAsync(wp_lsp + (size_t)800 * 7200, 0, (size_t)96 * 7200 * 2, stream);
  k_pack_wlocal<<<4000, 256, 0, stream>>>(w_local, wlp);
  {
    dim3 g(4, 125), blk(32, 8);
    k_transpose_cast<<<g, blk, 0, stream>>>(w_cls, wcT, 4000, 120, 4000, 1024.f);
  }
  k_pack_woT<<<2500, 256, 0, stream>>>(w_dwc_o, woT);

  // gather
  k_gather<<<(15 * 16 * 5 * 800 + 255) / 256, 256, 0, stream>>>(
      X, emb, P_lsp, P_pit, P_cod, P_gai, lsp32);

  // v = w_global^T @ (wc*1024): TN GEMM, splitK 10
  {
    dim3 g(32, 10);
    k_gemm_tn<<<g, 256, 0, stream>>>(wcT, 4000, w_global, 4000, vpart, 4000,
                                     13, 125, 480000, 120, 4000);
  }
  k_vredT<<<1875, 256, 0, stream>>>(vpart, vmat, 10);

  // Vt = w_local^T @ v: TN GEMM, splitK 10
  {
    dim3 g(4, 125), blk(32, 8);
    k_transpose_cast<<<g, blk, 0, stream>>>(vmat, vT, 4000, 120, 4000, 1.f);
  }
  {
    dim3 g(32, 10);
    k_gemm_tn<<<g, 256, 0, stream>>>(vT, 4000, w_local, 4000, vpart, 4000,
                                     13, 125, 480000, 120, 4000);
  }
  k_vredT<<<1875, 256, 0, stream>>>(vpart, Vt, 10);

  k_pack_vt<<<2000, 256, 0, stream>>>(Vt, vtT);
  k_consts<<<120, 256, 0, stream>>>(Vt, vmat, b_dwc_o, b_local, cbblv, svv);

  // A9[z][fe][gi] = sum_g vtT[fe][g]*woT[z][gi][g]
  {
    dim3 g(35, 1, 9);
    k_gemm_nt<<<g, 256, 0, stream>>>(vtT, 800, woT, 800, A9, 800,
                                     7, 35, 25, 25, 0, 0, 640000, 512000, 640, 800, 640);
  }
  k_fold_bp<<<7875, 256, 0, stream>>>(A9, Bp);

  // lsp conv GEMM (split-K 9, one tap per slice) + reduce w/ bias
  {
    dim3 g(175, 9);
    k_gemm_conv<<<g, 256, 0, stream>>>(P_lsp, wp_lsp, Cp);
  }
  k_co_reduce<<<2500, 256, 0, stream>>>(Cp, b_dwc_l, co);

  // cl = w_local(permuted) @ co^T + b_local : splitK 8 -> Clp, then reduce
  {
    dim3 g(160, 8);
    k_gemm_nt<<<g, 256, 0, stream>>>(wlp, 4000, co, 4000, Clp, 640,
                                     5, 160, 16, 125, 2560000L, 0, 0, 0, 4000, 640, 4000);
  }
  k_cl_reduce<<<2500, 256, 0, stream>>>(Clp, b_local, cl);

  // kv
  {
    dim3 g(25, 16);
    k_kv_partial<<<g, 256, 0, stream>>>(cl, w_lk, b_lk, w_lv, b_lv, kvp);
  }
  k_kv_reduce<<<100, 256, 0, stream>>>(kvp, kvb);

  // U path (splitK 3 over dw)
  {
    dim3 g(14, 21);
    k_gemm_u<<<g, 256, 0, stream>>>(P_gai, P_pit, P_cod, Bp, Upart);
  }
  k_ured<<<280, 256, 0, stream>>>(Upart, cbblv, Ufin);

  // c1
  k_c1<<<120, 256, 0, stream>>>(w_cls, b_global, c1p);

  // final combine
  k_combine<<<16, 256, 0, stream>>>(Ufin, kvb, vmat, lsp32,
                                    w_gq, w_pq, w_cq, b_gq, b_pq, b_cq,
                                    svv, c1p, b_cls, bn_w, bn_b, out);
}

// Round 5
// 686.690 us; speedup vs baseline: 1.2842x; 1.0133x over previous
//
#include <hip/hip_runtime.h>
#include <hip/hip_bf16.h>

typedef _Float16 f16;
typedef __attribute__((ext_vector_type(8))) _Float16 half8;
typedef __attribute__((ext_vector_type(8))) _Float16 half8_t;
typedef __attribute__((ext_vector_type(4))) _Float16 half4;
typedef __attribute__((ext_vector_type(4))) float f32x4;

static const int BN = 16, SEQN = 4000;

// ---------------------------------------------------------------------------
__device__ __forceinline__ void gload_lds(f16* lds, const f16* g) {
  __builtin_amdgcn_global_load_lds((const __attribute__((address_space(1))) unsigned int*)g,
                                   (__attribute__((address_space(3))) unsigned int*)lds, 16, 0, 0);
}

// bijective XCD swizzle (m204)
__device__ __forceinline__ int xcd_swz(int orig, int nwg) {
  int q = nwg >> 3, r = nwg & 7, x = orig & 7, o = orig >> 3;
  return (x < r ? x * (q + 1) : r * (q + 1) + (x - r) * q) + o;
}

// ---------------------------------------------------------------------------
// prepA: LDS-permute packs. ranges: [0,800) wconv | [800,4800) wlocal | [4800,5300) wcT
__global__ __launch_bounds__(256) void k_prepA(
    const float* __restrict__ w_dwc_l, f16* __restrict__ wp_lsp,
    const float* __restrict__ w_local, f16* __restrict__ wlp,
    const float* __restrict__ w_cls, f16* __restrict__ wcT) {
  __shared__ float sh[7200];
  int bid = blockIdx.x, t = threadIdx.x;
  if (bid < 800) {
    int o = bid;
    for (int p = t; p < 7200; p += 256) sh[p] = w_dwc_l[(long)o * 7200 + p];
    __syncthreads();
    for (int p = t; p < 7200; p += 256) {
      int tap = p / 800, gi = p % 800;
      wp_lsp[(long)o * 7200 + p] = (f16)sh[gi * 9 + tap];
    }
  } else if (bid < 4800) {
    int s = bid - 800;
    for (int p = t; p < 4000; p += 256) sh[p] = w_local[(long)s * 4000 + p];
    __syncthreads();
    for (int p = t; p < 4000; p += 256) {
      int f = p / 800, g = p % 800;
      wlp[(long)s * 4000 + p] = (f16)sh[g * 5 + f];
    }
  } else {
    int id = bid - 4800;
    int c0 = (id % 4) * 32, r0 = (id / 4) * 32;
    int tx = t & 31, ty = t >> 5;
    float (*tile)[33] = (float(*)[33])sh;
    for (int i = ty; i < 32; i += 8) {
      int r = r0 + i, c = c0 + tx;
      tile[i][tx] = (r < 4000 && c < 120) ? w_cls[(long)r * 120 + c] : 0.f;
    }
    __syncthreads();
    for (int i = ty; i < 32; i += 8) {
      int c = c0 + i, r = r0 + tx;
      if (c < 128 && r < 4000) wcT[(long)c * 4000 + r] = (f16)(tile[tx][i] * 1024.f);
    }
  }
}

// prepB: [0,2500) woT | [2500,6250) gather | [6250,6588) zero wp tail | [6588,6708) c1
__global__ __launch_bounds__(256) void k_prepB(
    const float* __restrict__ w_dwc_o, f16* __restrict__ woT,
    const int* __restrict__ X, const float* __restrict__ emb,
    f16* __restrict__ P_lsp, f16* __restrict__ P_pit,
    f16* __restrict__ P_cod, f16* __restrict__ P_gai,
    float* __restrict__ lsp32, f16* __restrict__ wp_lsp,
    const float* __restrict__ wcls, const float* __restrict__ bg,
    float* __restrict__ c1p) {
  __shared__ float red[256];
  int bid = blockIdx.x, t = threadIdx.x;
  if (bid < 2500) {
    int id = bid * 256 + t;
    if (id < 640000) {
      int g = id / 800, gi = id % 800;
      const float* src = w_dwc_o + (long)g * 7200 + gi * 9;
#pragma unroll
      for (int z = 0; z < 9; z++)
        woT[(long)z * 640000 + gi * 800 + g] = (f16)src[z];
    }
  } else if (bid < 6250) {
    const float scale[15] = {1.f,1.f,1.f,1.f,0.8f,0.512f,0.8f,0.64f,0.512f,0.64f,0.512f,0.8f,0.64f,0.512f,0.512f};
    const int br[15] = {0,0,0,0,1,1,2,2,3,3,1,2,2,3,3};
    const int po[15] = {0,1,2,3,0,1,0,1,0,2,2,2,3,1,3};
    int id = (bid - 2500) * 256 + t;
    int g = id % 800; int tmp = id / 800;
    int f = tmp % 5; tmp /= 5;
    int b = tmp % 16; int c = tmp / 16;
    int s = g * 5 + f;
    int idx = X[((long)b * SEQN + s) * 15 + c];
    const float* er = emb + (long)idx * 10;
    int ty = br[c], p = po[c];
    f16* P = (ty == 0) ? P_lsp : (ty == 1) ? P_pit : (ty == 2) ? P_cod : P_gai;
    int Wp = (ty == 1) ? 32 : 42;
    f16* base = P + ((long)((f + 1) * 16 + b) * Wp + (1 + p * 10)) * 800 + g;
    float sc = scale[c];
#pragma unroll
    for (int j = 0; j < 10; j++) {
      float v = er[j] * sc;
      base[(long)j * 800] = (f16)v;
      if (ty == 0) lsp32[((long)b * SEQN + s) * 40 + p * 10 + j] = v;
    }
  } else if (bid < 6588) {
    int idx = (bid - 6250) * 256 + t;
    if (idx < 86400) {
      half8_t z = {};
      *(half8_t*)&wp_lsp[(long)800 * 7200 + (long)idx * 8] = z;
    }
  } else {
    int blk = bid - 6588;
    float s = 0.f;
    for (long i = (long)blk * 256 + t; i < 480000; i += (long)120 * 256)
      s += wcls[i] * bg[i / 120];
    red[t] = s; __syncthreads();
    for (int o = 128; o > 0; o >>= 1) { if (t < o) red[t] += red[t + o]; __syncthreads(); }
    if (t == 0) c1p[blk] = red[0];
  }
}

// ---------------------------------------------------------------------------
// conv GEMM MT=64: grid (350, 3). z=df, K=2400=(de,gi) contiguous.
__global__ __launch_bounds__(256) void k_gemm_conv(
    const f16* __restrict__ P, const f16* __restrict__ wp, float* __restrict__ Cp) {
  __shared__ __align__(16) f16 As[2][2048];
  __shared__ __align__(16) f16 Bs[2][4096];
  int lin = xcd_swz(blockIdx.x, 350);
  int nx = lin % 7, my = lin / 7;
  int m0 = my * 64, n0 = nx * 128;
  int df = blockIdx.y;
  Cp += (long)df * 3200 * 800;
  int t = threadIdx.x;
  const f16 *ap, *bp0, *bp1;
  {
    int row = t >> 2, ch = t & 3;
    int m = m0 + row;
    int f = m / 640, rem = m % 640, b = rem / 40, e = rem % 40;
    ap = P + (((long)((f + df) * 16 + b)) * 42 + e) * 800 + ch * 8;
    bp0 = wp + (long)(n0 + row) * 7200 + df * 2400 + ch * 8;
    bp1 = wp + (long)(n0 + 64 + row) * 7200 + df * 2400 + ch * 8;
  }
  int lane = t & 63, wv = t >> 6, l15 = lane & 15, kg = lane >> 4;
  int wn = wv * 32;
  f32x4 acc[4][2] = {};
  gload_lds(&As[0][t * 8], ap);
  gload_lds(&Bs[0][t * 8], bp0);
  gload_lds(&Bs[0][2048 + t * 8], bp1);
  __syncthreads();
  int cur = 0;
  for (int kt = 0; kt < 75; kt++) {
    if (kt + 1 < 75) {
      int o = (kt + 1) * 32, nb = cur ^ 1;
      gload_lds(&As[nb][t * 8], ap + o);
      gload_lds(&Bs[nb][t * 8], bp0 + o);
      gload_lds(&Bs[nb][2048 + t * 8], bp1 + o);
    }
    half8 av[4], bv[2];
#pragma unroll
    for (int i = 0; i < 4; i++) av[i] = *(const half8*)(&As[cur][(i * 16 + l15) * 32 + kg * 8]);
#pragma unroll
    for (int j = 0; j < 2; j++) bv[j] = *(const half8*)(&Bs[cur][(wn + j * 16 + l15) * 32 + kg * 8]);
#pragma unroll
    for (int i = 0; i < 4; i++)
#pragma unroll
      for (int j = 0; j < 2; j++)
        acc[i][j] = __builtin_amdgcn_mfma_f32_16x16x32_f16(av[i], bv[j], acc[i][j], 0, 0, 0);
    __syncthreads();
    cur ^= 1;
  }
#pragma unroll
  for (int i = 0; i < 4; i++) {
    int mb = m0 + i * 16 + kg * 4;
#pragma unroll
    for (int j = 0; j < 2; j++) {
      int n = n0 + wn + j * 16 + l15;
      if (n >= 800) continue;
      f32x4 d = acc[i][j];
#pragma unroll
      for (int r = 0; r < 4; r++)
        Cp[(long)(mb + r) * 800 + n] = d[r];
    }
  }
}

// co[(b*40+e)][f*800+n] = f16( sum_z Cp[z][m][n] + bias[n] )
__global__ void k_co_reduce(const float* __restrict__ Cp, const float* __restrict__ bias,
                            f16* __restrict__ co) {
  int id = blockIdx.x * blockDim.x + threadIdx.x;
  if (id >= 640000) return;
  int m = id / 200, n4 = (id % 200) * 4;
  long o = (long)m * 800 + n4;
  f32x4 s = *(const f32x4*)&bias[n4];
#pragma unroll
  for (int z = 0; z < 3; z++) s += *(const f32x4*)&Cp[(long)z * 2560000 + o];
  int f = m / 640, r2 = m % 640;
  half4 h = {(f16)s[0], (f16)s[1], (f16)s[2], (f16)s[3]};
  *(half4*)&co[(long)r2 * 4000 + f * 800 + n4] = h;
}

// ---------------------------------------------------------------------------
// generic NT GEMM MT=64 (f16 in, fp32 out), dbuf, splitK(y)+z-slices.
__global__ __launch_bounds__(256) void k_gemm64(
    const f16* __restrict__ A, int lda, const f16* __restrict__ Bm, int ldb,
    float* __restrict__ C, int ldc,
    int gx, int nwg, int nkt, int KTtot, long cslice, long az, long bz, long cz,
    int Mreal, int Nreal, int Aclamp) {
  __shared__ __align__(16) f16 As[2][2048];
  __shared__ __align__(16) f16 Bs[2][4096];
  A += (long)blockIdx.z * az;
  Bm += (long)blockIdx.z * bz;
  C += (long)blockIdx.z * cz + (long)blockIdx.y * cslice;
  int lin = xcd_swz(blockIdx.x, nwg);
  int nx = lin % gx, my = lin / gx;
  int m0 = my * 64, n0 = nx * 128;
  int kt0 = blockIdx.y * nkt;
  int ktn = nkt; if (kt0 + ktn > KTtot) ktn = KTtot - kt0;
  int t = threadIdx.x;
  const f16 *ap, *bp0, *bp1;
  {
    int row = t >> 2, ch = t & 3;
    int ra = m0 + row; if (ra >= Aclamp) ra = Aclamp - 1;
    ap = A + (long)ra * lda + (long)kt0 * 32 + ch * 8;
    bp0 = Bm + (long)(n0 + row) * ldb + (long)kt0 * 32 + ch * 8;
    bp1 = Bm + (long)(n0 + 64 + row) * ldb + (long)kt0 * 32 + ch * 8;
  }
  int lane = t & 63, wv = t >> 6, l15 = lane & 15, kg = lane >> 4;
  int wn = wv * 32;
  f32x4 acc[4][2] = {};
  gload_lds(&As[0][t * 8], ap);
  gload_lds(&Bs[0][t * 8], bp0);
  gload_lds(&Bs[0][2048 + t * 8], bp1);
  __syncthreads();
  int cur = 0;
  for (int kt = 0; kt < ktn; kt++) {
    if (kt + 1 < ktn) {
      int o = (kt + 1) * 32, nb = cur ^ 1;
      gload_lds(&As[nb][t * 8], ap + o);
      gload_lds(&Bs[nb][t * 8], bp0 + o);
      gload_lds(&Bs[nb][2048 + t * 8], bp1 + o);
    }
    half8 av[4], bv[2];
#pragma unroll
    for (int i = 0; i < 4; i++) av[i] = *(const half8*)(&As[cur][(i * 16 + l15) * 32 + kg * 8]);
#pragma unroll
    for (int j = 0; j < 2; j++) bv[j] = *(const half8*)(&Bs[cur][(wn + j * 16 + l15) * 32 + kg * 8]);
#pragma unroll
    for (int i = 0; i < 4; i++)
#pragma unroll
      for (int j = 0; j < 2; j++)
        acc[i][j] = __builtin_amdgcn_mfma_f32_16x16x32_f16(av[i], bv[j], acc[i][j], 0, 0, 0);
    __syncthreads();
    cur ^= 1;
  }
#pragma unroll
  for (int i = 0; i < 4; i++) {
    int mb = m0 + i * 16 + kg * 4;
#pragma unroll
    for (int j = 0; j < 2; j++) {
      int n = n0 + wn + j * 16 + l15;
      if (n >= Nreal) continue;
      f32x4 d = acc[i][j];
#pragma unroll
      for (int r = 0; r < 4; r++) {
        int m = mb + r;
        if (m >= Mreal) continue;
        C[(long)m * ldc + n] = d[r];
      }
    }
  }
}

// ---------------------------------------------------------------------------
// TN GEMM: C[m][n] = sum_k A[m*lda+k](f16) * B[k*ldb+n](f32). Single M-tile.
__global__ __launch_bounds__(256) void k_gemm_tn(
    const f16* __restrict__ A, int lda, const float* __restrict__ B, int ldb,
    float* __restrict__ C, int ldc, int nkt, int KTtot, long cslice,
    int Mreal, int Nreal) {
  __shared__ __align__(16) f16 As[4096];
  __shared__ __align__(16) f16 Bs[128 * 36];
  int n0 = blockIdx.x * 128;
  int kt0 = blockIdx.y * nkt;
  int ktn = nkt; if (kt0 + ktn > KTtot) ktn = KTtot - kt0;
  C += (long)blockIdx.y * cslice;
  int t = threadIdx.x;
  const f16 *ap0, *ap1;
  {
    int r0 = t >> 2, r1 = 64 + (t >> 2);
    if (r0 >= Mreal) r0 = Mreal - 1;
    if (r1 >= Mreal) r1 = Mreal - 1;
    ap0 = A + (long)r0 * lda + (long)kt0 * 32 + (t & 3) * 8;
    ap1 = A + (long)r1 * lda + (long)kt0 * 32 + (t & 3) * 8;
  }
  int lane = t & 63, wv = t >> 6;
  int wm = (wv >> 1) * 64, wn = (wv & 1) * 64;
  int l15 = lane & 15, kg = lane >> 4;
  f32x4 acc[4][4] = {};
  for (int kt = 0; kt < ktn; kt++) {
    float rb[4][4];
    int nli[4], kqi[4];
#pragma unroll
    for (int i = 0; i < 4; i++) {
      int id = i * 256 + t;
      nli[i] = id & 127; kqi[i] = id >> 7;
      int gn = n0 + nli[i]; if (gn >= Nreal) gn = Nreal - 1;
      long kb = ((long)(kt0 + kt) * 32 + kqi[i] * 4);
#pragma unroll
      for (int j = 0; j < 4; j++) rb[i][j] = B[(kb + j) * ldb + gn];
    }
    __syncthreads();
    gload_lds(&As[t * 8], ap0 + kt * 32);
    gload_lds(&As[2048 + t * 8], ap1 + kt * 32);
#pragma unroll
    for (int i = 0; i < 4; i++) {
      half4 h = {(f16)rb[i][0], (f16)rb[i][1], (f16)rb[i][2], (f16)rb[i][3]};
      *(half4*)&Bs[nli[i] * 36 + kqi[i] * 4] = h;
    }
    __syncthreads();
    half8 av[4], bv[4];
#pragma unroll
    for (int i = 0; i < 4; i++) {
      av[i] = *(const half8*)(&As[(wm + i * 16 + l15) * 32 + kg * 8]);
      bv[i] = *(const half8*)(&Bs[(wn + i * 16 + l15) * 36 + kg * 8]);
    }
#pragma unroll
    for (int i = 0; i < 4; i++)
#pragma unroll
      for (int j = 0; j < 4; j++)
        acc[i][j] = __builtin_amdgcn_mfma_f32_16x16x32_f16(av[i], bv[j], acc[i][j], 0, 0, 0);
  }
#pragma unroll
  for (int i = 0; i < 4; i++) {
    int mb = wm + i * 16 + kg * 4;
#pragma unroll
    for (int j = 0; j < 4; j++) {
      int n = n0 + wn + j * 16 + l15;
      if (n >= Nreal) continue;
      f32x4 d = acc[i][j];
#pragma unroll
      for (int r = 0; r < 4; r++) {
        int m = mb + r;
        if (m >= Mreal) continue;
        C[(long)m * ldc + n] = d[r];
      }
    }
  }
}

// vredT2: sum 10 transposed slices; MODE 0 -> (vmat, vT f16), MODE 1 -> (Vt, vtT f16)
template <int MODE>
__global__ void k_vredT2(const float* __restrict__ vp, float* __restrict__ vout,
                         f16* __restrict__ tout) {
  int i = blockIdx.x * blockDim.x + threadIdx.x;
  if (i >= 480000) return;
  int s = i / 120, e = i % 120;
  float sum = 0.f;
#pragma unroll
  for (int z = 0; z < 10; z++) sum += vp[(long)z * 480000 + (long)e * 4000 + s];
  vout[i] = sum;
  if (MODE == 0) {
    tout[(long)e * 4000 + s] = (f16)sum;
  } else {
    int g = s / 5, f = s % 5;
    tout[(long)(f * 120 + e) * 800 + g] = (f16)sum;
  }
}

// cl[m][n] = sum_z Clp[z][m][n] + b_local[m]
__global__ void k_cl_reduce(const float* __restrict__ Clp, const float* __restrict__ bl,
                            float* __restrict__ cl) {
  int id = blockIdx.x * blockDim.x + threadIdx.x;
  if (id >= 640000) return;
  int m = id / 160, n4 = (id % 160) * 4;
  long o = (long)m * 640 + n4;
  f32x4 s = {0.f, 0.f, 0.f, 0.f};
#pragma unroll
  for (int z = 0; z < 4; z++) s += *(const f32x4*)&Clp[(long)z * 2560000 + o];
  float b = bl[m];
  s += (f32x4){b, b, b, b};
  *(f32x4*)&cl[o] = s;
}

// ---------------------------------------------------------------------------
// Bp[fp][eg][dw*800+gi] = f16( sum_dh A9[(dh*3+dw)][ (fp-dh)*120+eg ][gi] )
__global__ void k_fold_bp(const float* __restrict__ A9, f16* __restrict__ Bp) {
  int id = blockIdx.x * blockDim.x + threadIdx.x;
  if (id >= 7 * 120 * 2400) return;
  int fp = id / 288000;
  int r = id % 288000;
  int eg = r / 2400, k = r % 2400;
  int dw = k / 800, gi = k % 800;
  float s = 0.f;
#pragma unroll
  for (int dh = 0; dh < 3; dh++) {
    int f = fp - dh;
    if (f >= 0 && f < 5)
      s += A9[((long)(dh * 3 + dw) * 640 + f * 120 + eg) * 800 + gi];
  }
  Bp[id] = (f16)s;
}

// ---------------------------------------------------------------------------
// U GEMM: waves along M, block 64x48(40 real). grid (28, 21=(fp,zk)).
__global__ __launch_bounds__(256) void k_gemm_u(
    const f16* __restrict__ Pg, const f16* __restrict__ Pp, const f16* __restrict__ Pc,
    const f16* __restrict__ Bp, float* __restrict__ Upart) {
  __shared__ __align__(16) f16 As[2][2048];
  __shared__ __align__(16) f16 Bs[2][2048];
  int m0 = blockIdx.x * 64;
  int y = blockIdx.y, fp = y / 3, zk = y % 3;
  const f16* P; int seg0, jw, Wp, e0;
  if (m0 < 640)       { seg0 = 0;    jw = 40; Wp = 42; e0 = 0;  P = Pg; }
  else if (m0 < 1152) { seg0 = 640;  jw = 30; Wp = 32; e0 = 40; P = Pp; }
  else                { seg0 = 1152; jw = 40; Wp = 42; e0 = 80; P = Pc; }
  P += (long)fp * 16 * Wp * 800;
  int t = threadIdx.x;
  const f16 *ap, *bp;
  {
    int row = t >> 2, ch = t & 3;
    int l = m0 + row - seg0; if (l >= 16 * jw) l = 0;
    ap = P + ((long)(l / jw) * Wp + (l % jw)) * 800 + (long)zk * 800 + ch * 8;
    int brow = row; if (e0 + brow > 119) brow = 119 - e0;
    bp = Bp + ((long)fp * 120 + e0 + brow) * 2400 + (long)zk * 800 + ch * 8;
  }
  int lane = t & 63, wv = t >> 6, l15 = lane & 15, kg = lane >> 4;
  f32x4 acc[3] = {};
  gload_lds(&As[0][t * 8], ap);
  gload_lds(&Bs[0][t * 8], bp);
  __syncthreads();
  int cur = 0;
  for (int kt = 0; kt < 25; kt++) {
    if (kt + 1 < 25) {
      int o = (kt + 1) * 32, nb = cur ^ 1;
      gload_lds(&As[nb][t * 8], ap + o);
      gload_lds(&Bs[nb][t * 8], bp + o);
    }
    half8 av = *(const half8*)(&As[cur][(wv * 16 + l15) * 32 + kg * 8]);
#pragma unroll
    for (int j = 0; j < 3; j++) {
      half8 bv = *(const half8*)(&Bs[cur][(j * 16 + l15) * 32 + kg * 8]);
      acc[j] = __builtin_amdgcn_mfma_f32_16x16x32_f16(av, bv, acc[j], 0, 0, 0);
    }
    __syncthreads();
    cur ^= 1;
  }
#pragma unroll
  for (int j = 0; j < 3; j++) {
    int n = j * 16 + l15;
    if (n >= 40) continue;
    f32x4 d = acc[j];
#pragma unroll
    for (int r = 0; r < 4; r++) {
      int m = m0 + wv * 16 + kg * 4 + r;
      if (m - seg0 >= 16 * jw) continue;
      Upart[((long)y * 1792 + m) * 40 + n] = d[r];
    }
  }
}

// Ufin[m][e] = sum_y Upart + cbblv[e0(m)+e]
__global__ void k_ured(const float* __restrict__ Upart, const float* __restrict__ cbblv,
                       float* __restrict__ Ufin) {
  int id = blockIdx.x * blockDim.x + threadIdx.x;
  if (id >= 1792 * 40) return;
  int m = id / 40, e = id % 40;
  int e0 = m < 640 ? 0 : (m < 1152 ? 40 : 80);
  float s = cbblv[e0 + e];
  for (int y = 0; y < 21; y++) s += Upart[(long)y * 71680 + id];
  Ufin[id] = s;
}

// cbblv[e] = sum_s bconv_o[s/5]*Vt[s,e] + b_local[s]*v[s,e]; svv[e]=sum_s v[s,e]
__global__ __launch_bounds__(256) void k_consts(
    const float* __restrict__ Vt, const float* __restrict__ vmat,
    const float* __restrict__ bconv, const float* __restrict__ blocal,
    float* __restrict__ cbblv, float* __restrict__ svv) {
  __shared__ float r1[256], r2[256];
  int e = blockIdx.x, t = threadIdx.x;
  float a = 0.f, b = 0.f;
  for (int s = t; s < 4000; s += 256) {
    a += bconv[s / 5] * Vt[(long)s * 120 + e] + blocal[s] * vmat[(long)s * 120 + e];
    b += vmat[(long)s * 120 + e];
  }
  r1[t] = a; r2[t] = b; __syncthreads();
  for (int o = 128; o > 0; o >>= 1) {
    if (t < o) { r1[t] += r1[t + o]; r2[t] += r2[t + o]; }
    __syncthreads();
  }
  if (t == 0) { cbblv[e] = r1[0]; svv[e] = r2[0]; }
}

// ---------------------------------------------------------------------------
__global__ __launch_bounds__(256) void k_kv_partial(
    const float* __restrict__ cl, const float* __restrict__ wlk, const float* __restrict__ blk,
    const float* __restrict__ wlv, const float* __restrict__ blv, float* __restrict__ kvp) {
  __shared__ float s_wk[1600], s_wv[1600];
  __shared__ float s_cl[8][40], s_k[8][40], s_v[8][40];
  int t = threadIdx.x, chunk = blockIdx.x, b = blockIdx.y;
  for (int p = t; p < 1600; p += 256) { s_wk[p] = wlk[p]; s_wv[p] = wlv[p]; }
  float acc[7] = {0.f, 0.f, 0.f, 0.f, 0.f, 0.f, 0.f};
  for (int c8 = 0; c8 < 20; c8++) {
    int sb = chunk * 160 + c8 * 8;
    __syncthreads();
    for (int p = t; p < 320; p += 256) {
      int sl = p / 40, e = p % 40;
      s_cl[sl][e] = cl[(long)(sb + sl) * 640 + b * 40 + e];
    }
    __syncthreads();
    for (int p = t; p < 640; p += 256) {
      int half = p / 320, q = p % 320, sl = q / 40, d = q % 40;
      const float* w = half ? s_wv : s_wk;
      float r = half ? blv[d] : blk[d];
      for (int e = 0; e < 40; e++) r += w[d * 40 + e] * s_cl[sl][e];
      if (half) s_v[sl][d] = r; else s_k[sl][d] = r;
    }
    __syncthreads();
    int ai = 0;
    for (int p = t; p < 1600; p += 256, ai++) {
      int d = p / 40, e = p % 40;
      float a = acc[ai];
      for (int sl = 0; sl < 8; sl++) a += s_k[sl][d] * s_v[sl][e];
      acc[ai] = a;
    }
  }
  int ai = 0;
  for (int p = t; p < 1600; p += 256, ai++)
    kvp[((long)(b * 25 + chunk)) * 1600 + p] = acc[ai];
}

__global__ void k_kv_reduce(const float* __restrict__ kvp, float* __restrict__ kv) {
  int i = blockIdx.x * blockDim.x + threadIdx.x;
  if (i >= 16 * 1600) return;
  int b = i / 1600, p = i % 1600;
  float s = 0.f;
  for (int c = 0; c < 25; c++) s += kvp[((long)(b * 25 + c)) * 1600 + p];
  kv[i] = s;
}

// ---------------------------------------------------------------------------
__global__ __launch_bounds__(256) void k_combine(
    const float* __restrict__ Ufin, const float* __restrict__ kvb,
    const float* __restrict__ vmat, const float* __restrict__ lsp32,
    const float* __restrict__ wgq, const float* __restrict__ wpq, const float* __restrict__ wcq,
    const float* __restrict__ bgq, const float* __restrict__ bpq, const float* __restrict__ bcq,
    const float* __restrict__ svv, const float* __restrict__ c1p,
    const float* __restrict__ bcls, const float* __restrict__ bnw,
    const float* __restrict__ bnb, float* __restrict__ out) {
  __shared__ float s_kv[1600], s_U[4800], s_w[4400], s_bq[120], s_sv[120], s_red[256];
  int b = blockIdx.x, t = threadIdx.x;
  for (int p = t; p < 1600; p += 256) {
    s_kv[p] = kvb[b * 1600 + p];
    s_w[p] = wgq[p];
    s_w[2800 + p] = wcq[p];
  }
  for (int p = t; p < 1200; p += 256) s_w[1600 + p] = wpq[p];
  for (int p = t; p < 4800; p += 256) {
    int tt = p / 1600, r = p % 1600, j = r / 40, e = r % 40;
    float uv = 0.f;
    if (tt == 0) uv = Ufin[(b * 40 + j) * 40 + e];
    else if (tt == 1) { if (j < 30) uv = Ufin[(640 + b * 30 + j) * 40 + e]; }
    else uv = Ufin[(1152 + b * 40 + j) * 40 + e];
    s_U[p] = uv;
  }
  if (t < 40) { s_bq[t] = bgq[t]; s_bq[40 + t] = bpq[t]; s_bq[80 + t] = bcq[t]; }
  for (int p = t; p < 120; p += 256) s_sv[p] = svv[p];
  __syncthreads();
  float y = 0.f;
  for (int p = t; p < 4800; p += 256) {
    int tt = p / 1600, q = p % 1600, d = q / 40, e = q % 40;
    float T = 0.f;
    if (tt == 0) {
      for (int j = 0; j < 40; j++) T += s_w[d * 40 + j] * s_U[j * 40 + e];
    } else if (tt == 1) {
      for (int j = 0; j < 30; j++) T += s_w[1600 + d * 30 + j] * s_U[1600 + j * 40 + e];
    } else {
      for (int j = 0; j < 40; j++) T += s_w[2800 + d * 40 + j] * s_U[3200 + j * 40 + e];
    }
    y += s_kv[d * 40 + e] * (T + s_bq[tt * 40 + d] * s_sv[tt * 40 + e]);
  }
  for (int s = t; s < 4000; s += 256) {
    const f32x4* lp = (const f32x4*)(lsp32 + ((long)b * SEQN + s) * 40);
    const f32x4* vp = (const f32x4*)(vmat + (long)s * 120);
#pragma unroll
    for (int d4 = 0; d4 < 10; d4++) {
      f32x4 l = lp[d4];
      f32x4 vs = vp[d4] + vp[10 + d4] + vp[20 + d4];
      y += l[0] * vs[0] + l[1] * vs[1] + l[2] * vs[2] + l[3] * vs[3];
    }
  }
  s_red[t] = y; __syncthreads();
  for (int o = 128; o > 0; o >>= 1) { if (t < o) s_red[t] += s_red[t + o]; __syncthreads(); }
  if (t == 0) {
    float c1 = bcls[0];
    for (int i = 0; i < 120; i++) c1 += c1p[i];
    float yy = s_red[0] * (1.f / 1024.f) + c1;
    yy = yy * (bnw[0] * rsqrtf(1.f + 1e-5f)) + bnb[0];
    out[b] = 1.f / (1.f + expf(-yy));
  }
}

// ---------------------------------------------------------------------------
extern "C" void kernel_launch(void* const* d_in, const int* in_sizes, int n_in,
                              void* d_out, int out_size, void* d_ws, size_t ws_size,
                              hipStream_t stream) {
  const int*   X        = (const int*)d_in[0];
  const float* emb      = (const float*)d_in[1];
  const float* w_dwc_l  = (const float*)d_in[2];
  const float* b_dwc_l  = (const float*)d_in[3];
  const float* w_dwc_o  = (const float*)d_in[4];
  const float* b_dwc_o  = (const float*)d_in[5];
  const float* w_local  = (const float*)d_in[6];
  const float* b_local  = (const float*)d_in[7];
  const float* w_global = (const float*)d_in[8];
  const float* b_global = (const float*)d_in[9];
  const float* w_gq = (const float*)d_in[10];
  const float* b_gq = (const float*)d_in[11];
  const float* w_cq = (const float*)d_in[12];
  const float* b_cq = (const float*)d_in[13];
  const float* w_pq = (const float*)d_in[14];
  const float* b_pq = (const float*)d_in[15];
  const float* w_lk = (const float*)d_in[16];
  const float* b_lk = (const float*)d_in[17];
  const float* w_lv = (const float*)d_in[18];
  const float* b_lv = (const float*)d_in[19];
  const float* w_cls = (const float*)d_in[20];
  const float* b_cls = (const float*)d_in[21];
  const float* bn_w = (const float*)d_in[22];
  const float* bn_b = (const float*)d_in[23];
  float* out = (float*)d_out;

  char* ws = (char*)d_ws;
  size_t off = 0;
  auto alloc = [&](size_t bytes) -> void* {
    off = (off + 255) & ~(size_t)255;
    void* p = ws + off; off += bytes; return p;
  };

  const size_t sz_p40 = (size_t)7 * 16 * 42 * 800 * 2;
  const size_t sz_p30 = (size_t)7 * 16 * 32 * 800 * 2;
  f16* P_lsp = (f16*)alloc(sz_p40);
  f16* P_pit = (f16*)alloc(sz_p30);
  f16* P_cod = (f16*)alloc(sz_p40);
  f16* P_gai = (f16*)alloc(sz_p40);
  float* lsp32 = (float*)alloc((size_t)16 * 4000 * 40 * 4);
  f16* wp_lsp = (f16*)alloc((size_t)896 * 7200 * 2);
  f16* wlp    = (f16*)alloc((size_t)4000 * 4000 * 2);
  f16* wcT    = (f16*)alloc((size_t)128 * 4000 * 2);
  f16* vT     = (f16*)alloc((size_t)128 * 4000 * 2);
  f16* co     = (f16*)alloc((size_t)640 * 4000 * 2);
  float* cl   = (float*)alloc((size_t)4000 * 640 * 4);
  float* vmat  = (float*)alloc((size_t)480000 * 4);
  float* Vt    = (float*)alloc((size_t)480000 * 4);
  f16* vtT   = (f16*)alloc((size_t)640 * 800 * 2);
  f16* Bp    = (f16*)alloc((size_t)7 * 120 * 2400 * 2);
  float* Upart = (float*)alloc((size_t)21 * 1792 * 40 * 4);
  float* Ufin  = (float*)alloc((size_t)1792 * 40 * 4);
  float* cbblv = (float*)alloc(120 * 4);
  float* svv   = (float*)alloc(120 * 4);
  float* kvp  = (float*)alloc((size_t)400 * 1600 * 4);
  float* kvb  = (float*)alloc((size_t)16 * 1600 * 4);
  float* c1p  = (float*)alloc(120 * 4);
  // arena: A9(18.43MB)@0 | woT(11.68MB)@18.5MB | vpart(19.2MB)@30.2MB ; later Cp@0(30.7MB), Clp@0(41MB)
  char* arena = (char*)alloc((size_t)52 * 1024 * 1024);
  float* A9   = (float*)arena;
  f16*   woT  = (f16*)(arena + 18500000);
  float* vpart = (float*)(arena + 30200000);
  float* Cp   = (float*)arena;
  float* Clp  = (float*)arena;
  (void)ws_size; (void)in_sizes; (void)n_in; (void)out_size;

  // zero conv-pad borders
  hipMemsetAsync(P_lsp, 0, sz_p40, stream);
  hipMemsetAsync(P_pit, 0, sz_p30, stream);
  hipMemsetAsync(P_cod, 0, sz_p40, stream);
  hipMemsetAsync(P_gai, 0, sz_p40, stream);

  // merged prep
  k_prepA<<<5300, 256, 0, stream>>>(w_dwc_l, wp_lsp, w_local, wlp, w_cls, wcT);
  k_prepB<<<6708, 256, 0, stream>>>(w_dwc_o, woT, X, emb, P_lsp, P_pit, P_cod, P_gai,
                                    lsp32, wp_lsp, w_cls, b_global, c1p);

  // v = w_global^T @ (wc*1024): TN, splitK 10
  {
    dim3 g(32, 10);
    k_gemm_tn<<<g, 256, 0, stream>>>(wcT, 4000, w_global, 4000, vpart, 4000,
                                     13, 125, 480000, 120, 4000);
  }
  k_vredT2<0><<<1875, 256, 0, stream>>>(vpart, vmat, vT);

  // Vt = w_local^T @ v: TN, splitK 10
  {
    dim3 g(32, 10);
    k_gemm_tn<<<g, 256, 0, stream>>>(vT, 4000, w_local, 4000, vpart, 4000,
                                     13, 125, 480000, 120, 4000);
  }
  k_vredT2<1><<<1875, 256, 0, stream>>>(vpart, Vt, vtT);

  k_consts<<<120, 256, 0, stream>>>(Vt, vmat, b_dwc_o, b_local, cbblv, svv);

  // A9[z][fe][gi] = sum_g vtT[fe][g]*woT[z][gi][g]  (MT=64, z=9)
  {
    dim3 g(70, 1, 9);
    k_gemm64<<<g, 256, 0, stream>>>(vtT, 800, woT, 800, A9, 800,
                                    7, 70, 25, 25, 0, 0, 640000, 512000, 600, 800, 600);
  }
  k_fold_bp<<<7875, 256, 0, stream>>>(A9, Bp);

  // lsp conv GEMM (MT=64, splitK 3 over df) + reduce w/ bias
  {
    dim3 g(350, 3);
    k_gemm_conv<<<g, 256, 0, stream>>>(P_lsp, wp_lsp, Cp);
  }
  k_co_reduce<<<2500, 256, 0, stream>>>(Cp, b_dwc_l, co);

  // cl = w_local(permuted) @ co^T + b_local : MT=64, splitK 4 -> Clp, reduce
  {
    dim3 g(315, 4);
    k_gemm64<<<g, 256, 0, stream>>>(wlp, 4000, co, 4000, Clp, 640,
                                    5, 315, 32, 125, 2560000L, 0, 0, 0, 4000, 640, 4000);
  }
  k_cl_reduce<<<2500, 256, 0, stream>>>(Clp, b_local, cl);

  // kv
  {
    dim3 g(25, 16);
    k_kv_partial<<<g, 256, 0, stream>>>(cl, w_lk, b_lk, w_lv, b_lv, kvp);
  }
  k_kv_reduce<<<100, 256, 0, stream>>>(kvp, kvb);

  // U path (waves-along-M tiles, splitK 3 over dw)
  {
    dim3 g(28, 21);
    k_gemm_u<<<g, 256, 0, stream>>>(P_gai, P_pit, P_cod, Bp, Upart);
  }
  k_ured<<<280, 256, 0, stream>>>(Upart, cbblv, Ufin);

  // final combine
  k_combine<<<16, 256, 0, stream>>>(Ufin, kvb, vmat, lsp32,
                                    w_gq, w_pq, w_cq, b_gq, b_pq, b_cq,
                                    svv, c1p, b_cls, bn_w, bn_b, out);
}

// Round 6
// 587.620 us; speedup vs baseline: 1.5008x; 1.1686x over previous
//
#include <hip/hip_runtime.h>
#include <hip/hip_bf16.h>

typedef _Float16 f16;
typedef __attribute__((ext_vector_type(8))) _Float16 half8;
typedef __attribute__((ext_vector_type(8))) _Float16 half8_t;
typedef __attribute__((ext_vector_type(4))) _Float16 half4;
typedef __attribute__((ext_vector_type(4))) float f32x4;

static const int BN = 16, SEQN = 4000;

// ---------------------------------------------------------------------------
__device__ __forceinline__ void gload_lds(f16* lds, const f16* g) {
  __builtin_amdgcn_global_load_lds((const __attribute__((address_space(1))) unsigned int*)g,
                                   (__attribute__((address_space(3))) unsigned int*)lds, 16, 0, 0);
}

// bijective XCD swizzle (m204)
__device__ __forceinline__ int xcd_swz(int orig, int nwg) {
  int q = nwg >> 3, r = nwg & 7, x = orig & 7, o = orig >> 3;
  return (x < r ? x * (q + 1) : r * (q + 1) + (x - r) * q) + o;
}

// ---------------------------------------------------------------------------
// prepA: LDS-permute packs. ranges: [0,800) wconv | [800,4800) wlocal | [4800,5300) wcT
__global__ __launch_bounds__(256) void k_prepA(
    const float* __restrict__ w_dwc_l, f16* __restrict__ wp_lsp,
    const float* __restrict__ w_local, f16* __restrict__ wlp,
    const float* __restrict__ w_cls, f16* __restrict__ wcT) {
  __shared__ float sh[7200];
  int bid = blockIdx.x, t = threadIdx.x;
  if (bid < 800) {
    int o = bid;
    for (int p = t; p < 7200; p += 256) sh[p] = w_dwc_l[(long)o * 7200 + p];
    __syncthreads();
    for (int p = t; p < 7200; p += 256) {
      int tap = p / 800, gi = p % 800;
      wp_lsp[(long)o * 7200 + p] = (f16)sh[gi * 9 + tap];
    }
  } else if (bid < 4800) {
    int s = bid - 800;
    for (int p = t; p < 4000; p += 256) sh[p] = w_local[(long)s * 4000 + p];
    __syncthreads();
    for (int p = t; p < 4000; p += 256) {
      int f = p / 800, g = p % 800;
      wlp[(long)s * 4000 + p] = (f16)sh[g * 5 + f];
    }
  } else {
    int id = bid - 4800;
    int c0 = (id % 4) * 32, r0 = (id / 4) * 32;
    int tx = t & 31, ty = t >> 5;
    float (*tile)[33] = (float(*)[33])sh;
    for (int i = ty; i < 32; i += 8) {
      int r = r0 + i, c = c0 + tx;
      tile[i][tx] = (r < 4000 && c < 120) ? w_cls[(long)r * 120 + c] : 0.f;
    }
    __syncthreads();
    for (int i = ty; i < 32; i += 8) {
      int c = c0 + i, r = r0 + tx;
      if (c < 128 && r < 4000) wcT[(long)c * 4000 + r] = (f16)(tile[tx][i] * 1024.f);
    }
  }
}

// ---------------------------------------------------------------------------
// woT pack via LDS transpose: woT[z][gi][g] = w_dwc_o[g][gi*9+z], 64B-contiguous
// writes over g. grid 625 = 25 g-tiles x 25 gi-tiles (32x32).
__global__ __launch_bounds__(256) void k_pack_woT(const float* __restrict__ in,
                                                  f16* __restrict__ out) {
  __shared__ float sh[32][289];
  int bg = blockIdx.x % 25, bgi = blockIdx.x / 25;
  int g0 = bg * 32, gi0 = bgi * 32;
  int t = threadIdx.x;
  for (int p = t; p < 32 * 288; p += 256) {
    int gl = p / 288, q = p % 288;
    sh[gl][q] = in[(long)(g0 + gl) * 7200 + gi0 * 9 + q];
  }
  __syncthreads();
  for (int p = t; p < 9 * 32 * 32; p += 256) {
    int gl = p & 31, q = p >> 5;
    int gil = q & 31, z = q >> 5;
    out[(long)z * 640000 + (gi0 + gil) * 800 + g0 + gl] = (f16)sh[gl][gil * 9 + z];
  }
}

// prepB: [0,3750) gather | [3750,4088) zero wp tail | [4088,4208) c1
__global__ __launch_bounds__(256) void k_prepB(
    const int* __restrict__ X, const float* __restrict__ emb,
    f16* __restrict__ P_lsp, f16* __restrict__ P_pit,
    f16* __restrict__ P_cod, f16* __restrict__ P_gai,
    float* __restrict__ lsp32, f16* __restrict__ wp_lsp,
    const float* __restrict__ wcls, const float* __restrict__ bg,
    float* __restrict__ c1p) {
  __shared__ float red[256];
  int bid = blockIdx.x, t = threadIdx.x;
  if (bid < 3750) {
    const float scale[15] = {1.f,1.f,1.f,1.f,0.8f,0.512f,0.8f,0.64f,0.512f,0.64f,0.512f,0.8f,0.64f,0.512f,0.512f};
    const int br[15] = {0,0,0,0,1,1,2,2,3,3,1,2,2,3,3};
    const int po[15] = {0,1,2,3,0,1,0,1,0,2,2,2,3,1,3};
    int id = bid * 256 + t;
    int g = id % 800; int tmp = id / 800;
    int f = tmp % 5; tmp /= 5;
    int b = tmp % 16; int c = tmp / 16;
    int s = g * 5 + f;
    int idx = X[((long)b * SEQN + s) * 15 + c];
    const float* er = emb + (long)idx * 10;
    int ty = br[c], p = po[c];
    f16* P = (ty == 0) ? P_lsp : (ty == 1) ? P_pit : (ty == 2) ? P_cod : P_gai;
    int Wp = (ty == 1) ? 32 : 42;
    f16* base = P + ((long)((f + 1) * 16 + b) * Wp + (1 + p * 10)) * 800 + g;
    float sc = scale[c];
#pragma unroll
    for (int j = 0; j < 10; j++) {
      float v = er[j] * sc;
      base[(long)j * 800] = (f16)v;
      if (ty == 0) lsp32[((long)b * SEQN + s) * 40 + p * 10 + j] = v;
    }
  } else if (bid < 4088) {
    int idx = (bid - 3750) * 256 + t;
    if (idx < 86400) {
      half8_t z = {};
      *(half8_t*)&wp_lsp[(long)800 * 7200 + (long)idx * 8] = z;
    }
  } else {
    int blk = bid - 4088;
    float s = 0.f;
    for (long i = (long)blk * 256 + t; i < 480000; i += (long)120 * 256)
      s += wcls[i] * bg[i / 120];
    red[t] = s; __syncthreads();
    for (int o = 128; o > 0; o >>= 1) { if (t < o) red[t] += red[t + o]; __syncthreads(); }
    if (t == 0) c1p[blk] = red[0];
  }
}

// ---------------------------------------------------------------------------
// conv GEMM MT=64: grid (350, 3). z=df, K=2400=(de,gi) contiguous.
__global__ __launch_bounds__(256) void k_gemm_conv(
    const f16* __restrict__ P, const f16* __restrict__ wp, float* __restrict__ Cp) {
  __shared__ __align__(16) f16 As[2][2048];
  __shared__ __align__(16) f16 Bs[2][4096];
  int lin = xcd_swz(blockIdx.x, 350);
  int nx = lin % 7, my = lin / 7;
  int m0 = my * 64, n0 = nx * 128;
  int df = blockIdx.y;
  Cp += (long)df * 3200 * 800;
  int t = threadIdx.x;
  const f16 *ap, *bp0, *bp1;
  {
    int row = t >> 2, ch = t & 3;
    int m = m0 + row;
    int f = m / 640, rem = m % 640, b = rem / 40, e = rem % 40;
    ap = P + (((long)((f + df) * 16 + b)) * 42 + e) * 800 + ch * 8;
    bp0 = wp + (long)(n0 + row) * 7200 + df * 2400 + ch * 8;
    bp1 = wp + (long)(n0 + 64 + row) * 7200 + df * 2400 + ch * 8;
  }
  int lane = t & 63, wv = t >> 6, l15 = lane & 15, kg = lane >> 4;
  int wn = wv * 32;
  f32x4 acc[4][2] = {};
  gload_lds(&As[0][t * 8], ap);
  gload_lds(&Bs[0][t * 8], bp0);
  gload_lds(&Bs[0][2048 + t * 8], bp1);
  __syncthreads();
  int cur = 0;
  for (int kt = 0; kt < 75; kt++) {
    if (kt + 1 < 75) {
      int o = (kt + 1) * 32, nb = cur ^ 1;
      gload_lds(&As[nb][t * 8], ap + o);
      gload_lds(&Bs[nb][t * 8], bp0 + o);
      gload_lds(&Bs[nb][2048 + t * 8], bp1 + o);
    }
    half8 av[4], bv[2];
#pragma unroll
    for (int i = 0; i < 4; i++) av[i] = *(const half8*)(&As[cur][(i * 16 + l15) * 32 + kg * 8]);
#pragma unroll
    for (int j = 0; j < 2; j++) bv[j] = *(const half8*)(&Bs[cur][(wn + j * 16 + l15) * 32 + kg * 8]);
#pragma unroll
    for (int i = 0; i < 4; i++)
#pragma unroll
      for (int j = 0; j < 2; j++)
        acc[i][j] = __builtin_amdgcn_mfma_f32_16x16x32_f16(av[i], bv[j], acc[i][j], 0, 0, 0);
    __syncthreads();
    cur ^= 1;
  }
#pragma unroll
  for (int i = 0; i < 4; i++) {
    int mb = m0 + i * 16 + kg * 4;
#pragma unroll
    for (int j = 0; j < 2; j++) {
      int n = n0 + wn + j * 16 + l15;
      if (n >= 800) continue;
      f32x4 d = acc[i][j];
#pragma unroll
      for (int r = 0; r < 4; r++)
        Cp[(long)(mb + r) * 800 + n] = d[r];
    }
  }
}

// co[(b*40+e)][f*800+n] = f16( sum_z Cp[z][m][n] + bias[n] )
__global__ void k_co_reduce(const float* __restrict__ Cp, const float* __restrict__ bias,
                            f16* __restrict__ co) {
  int id = blockIdx.x * blockDim.x + threadIdx.x;
  if (id >= 640000) return;
  int m = id / 200, n4 = (id % 200) * 4;
  long o = (long)m * 800 + n4;
  f32x4 s = *(const f32x4*)&bias[n4];
#pragma unroll
  for (int z = 0; z < 3; z++) s += *(const f32x4*)&Cp[(long)z * 2560000 + o];
  int f = m / 640, r2 = m % 640;
  half4 h = {(f16)s[0], (f16)s[1], (f16)s[2], (f16)s[3]};
  *(half4*)&co[(long)r2 * 4000 + f * 800 + n4] = h;
}

// ---------------------------------------------------------------------------
// generic NT GEMM MT=64 (f16 in, fp32 out), dbuf, splitK(y)+z-slices.
__global__ __launch_bounds__(256) void k_gemm64(
    const f16* __restrict__ A, int lda, const f16* __restrict__ Bm, int ldb,
    float* __restrict__ C, int ldc,
    int gx, int nwg, int nkt, int KTtot, long cslice, long az, long bz, long cz,
    int Mreal, int Nreal, int Aclamp) {
  __shared__ __align__(16) f16 As[2][2048];
  __shared__ __align__(16) f16 Bs[2][4096];
  A += (long)blockIdx.z * az;
  Bm += (long)blockIdx.z * bz;
  C += (long)blockIdx.z * cz + (long)blockIdx.y * cslice;
  int lin = xcd_swz(blockIdx.x, nwg);
  int nx = lin % gx, my = lin / gx;
  int m0 = my * 64, n0 = nx * 128;
  int kt0 = blockIdx.y * nkt;
  int ktn = nkt; if (kt0 + ktn > KTtot) ktn = KTtot - kt0;
  int t = threadIdx.x;
  const f16 *ap, *bp0, *bp1;
  {
    int row = t >> 2, ch = t & 3;
    int ra = m0 + row; if (ra >= Aclamp) ra = Aclamp - 1;
    ap = A + (long)ra * lda + (long)kt0 * 32 + ch * 8;
    bp0 = Bm + (long)(n0 + row) * ldb + (long)kt0 * 32 + ch * 8;
    bp1 = Bm + (long)(n0 + 64 + row) * ldb + (long)kt0 * 32 + ch * 8;
  }
  int lane = t & 63, wv = t >> 6, l15 = lane & 15, kg = lane >> 4;
  int wn = wv * 32;
  f32x4 acc[4][2] = {};
  gload_lds(&As[0][t * 8], ap);
  gload_lds(&Bs[0][t * 8], bp0);
  gload_lds(&Bs[0][2048 + t * 8], bp1);
  __syncthreads();
  int cur = 0;
  for (int kt = 0; kt < ktn; kt++) {
    if (kt + 1 < ktn) {
      int o = (kt + 1) * 32, nb = cur ^ 1;
      gload_lds(&As[nb][t * 8], ap + o);
      gload_lds(&Bs[nb][t * 8], bp0 + o);
      gload_lds(&Bs[nb][2048 + t * 8], bp1 + o);
    }
    half8 av[4], bv[2];
#pragma unroll
    for (int i = 0; i < 4; i++) av[i] = *(const half8*)(&As[cur][(i * 16 + l15) * 32 + kg * 8]);
#pragma unroll
    for (int j = 0; j < 2; j++) bv[j] = *(const half8*)(&Bs[cur][(wn + j * 16 + l15) * 32 + kg * 8]);
#pragma unroll
    for (int i = 0; i < 4; i++)
#pragma unroll
      for (int j = 0; j < 2; j++)
        acc[i][j] = __builtin_amdgcn_mfma_f32_16x16x32_f16(av[i], bv[j], acc[i][j], 0, 0, 0);
    __syncthreads();
    cur ^= 1;
  }
#pragma unroll
  for (int i = 0; i < 4; i++) {
    int mb = m0 + i * 16 + kg * 4;
#pragma unroll
    for (int j = 0; j < 2; j++) {
      int n = n0 + wn + j * 16 + l15;
      if (n >= Nreal) continue;
      f32x4 d = acc[i][j];
#pragma unroll
      for (int r = 0; r < 4; r++) {
        int m = mb + r;
        if (m >= Mreal) continue;
        C[(long)m * ldc + n] = d[r];
      }
    }
  }
}

// ---------------------------------------------------------------------------
// TN GEMM: C[m][n] = sum_k A[m*lda+k](f16) * B[k*ldb+n](f32). Single M-tile.
__global__ __launch_bounds__(256) void k_gemm_tn(
    const f16* __restrict__ A, int lda, const float* __restrict__ B, int ldb,
    float* __restrict__ C, int ldc, int nkt, int KTtot, long cslice,
    int Mreal, int Nreal) {
  __shared__ __align__(16) f16 As[4096];
  __shared__ __align__(16) f16 Bs[128 * 36];
  int n0 = blockIdx.x * 128;
  int kt0 = blockIdx.y * nkt;
  int ktn = nkt; if (kt0 + ktn > KTtot) ktn = KTtot - kt0;
  C += (long)blockIdx.y * cslice;
  int t = threadIdx.x;
  const f16 *ap0, *ap1;
  {
    int r0 = t >> 2, r1 = 64 + (t >> 2);
    if (r0 >= Mreal) r0 = Mreal - 1;
    if (r1 >= Mreal) r1 = Mreal - 1;
    ap0 = A + (long)r0 * lda + (long)kt0 * 32 + (t & 3) * 8;
    ap1 = A + (long)r1 * lda + (long)kt0 * 32 + (t & 3) * 8;
  }
  int lane = t & 63, wv = t >> 6;
  int wm = (wv >> 1) * 64, wn = (wv & 1) * 64;
  int l15 = lane & 15, kg = lane >> 4;
  f32x4 acc[4][4] = {};
  for (int kt = 0; kt < ktn; kt++) {
    float rb[4][4];
    int nli[4], kqi[4];
#pragma unroll
    for (int i = 0; i < 4; i++) {
      int id = i * 256 + t;
      nli[i] = id & 127; kqi[i] = id >> 7;
      int gn = n0 + nli[i]; if (gn >= Nreal) gn = Nreal - 1;
      long kb = ((long)(kt0 + kt) * 32 + kqi[i] * 4);
#pragma unroll
      for (int j = 0; j < 4; j++) rb[i][j] = B[(kb + j) * ldb + gn];
    }
    __syncthreads();
    gload_lds(&As[t * 8], ap0 + kt * 32);
    gload_lds(&As[2048 + t * 8], ap1 + kt * 32);
#pragma unroll
    for (int i = 0; i < 4; i++) {
      half4 h = {(f16)rb[i][0], (f16)rb[i][1], (f16)rb[i][2], (f16)rb[i][3]};
      *(half4*)&Bs[nli[i] * 36 + kqi[i] * 4] = h;
    }
    __syncthreads();
    half8 av[4], bv[4];
#pragma unroll
    for (int i = 0; i < 4; i++) {
      av[i] = *(const half8*)(&As[(wm + i * 16 + l15) * 32 + kg * 8]);
      bv[i] = *(const half8*)(&Bs[(wn + i * 16 + l15) * 36 + kg * 8]);
    }
#pragma unroll
    for (int i = 0; i < 4; i++)
#pragma unroll
      for (int j = 0; j < 4; j++)
        acc[i][j] = __builtin_amdgcn_mfma_f32_16x16x32_f16(av[i], bv[j], acc[i][j], 0, 0, 0);
  }
#pragma unroll
  for (int i = 0; i < 4; i++) {
    int mb = wm + i * 16 + kg * 4;
#pragma unroll
    for (int j = 0; j < 4; j++) {
      int n = n0 + wn + j * 16 + l15;
      if (n >= Nreal) continue;
      f32x4 d = acc[i][j];
#pragma unroll
      for (int r = 0; r < 4; r++) {
        int m = mb + r;
        if (m >= Mreal) continue;
        C[(long)m * ldc + n] = d[r];
      }
    }
  }
}

// vredT2: sum 10 transposed slices, s-tiled (coalesced reads + contiguous writes).
// grid (32, 3), block 128. MODE 0 -> (vmat, vT f16), MODE 1 -> (Vt, vtT f16)
template <int MODE>
__global__ __launch_bounds__(128) void k_vredT2(const float* __restrict__ vp,
                                                float* __restrict__ vout,
                                                f16* __restrict__ tout) {
  int s = blockIdx.x * 128 + threadIdx.x;
  int ec = blockIdx.y;
  if (s >= 4000) return;
  int g = s / 5, f = s % 5;
  float sums[40];
#pragma unroll
  for (int eo = 0; eo < 40; eo++) {
    int e = ec * 40 + eo;
    float sum = 0.f;
#pragma unroll
    for (int z = 0; z < 10; z++) sum += vp[(long)z * 480000 + (long)e * 4000 + s];
    sums[eo] = sum;
    if (MODE == 0) tout[(long)e * 4000 + s] = (f16)sum;
    else tout[(long)(f * 120 + e) * 800 + g] = (f16)sum;
  }
#pragma unroll
  for (int q = 0; q < 10; q++)
    *(f32x4*)&vout[(long)s * 120 + ec * 40 + q * 4] = *(f32x4*)&sums[q * 4];
}

// cl[m][n] = sum_z Clp[z][m][n] + b_local[m]
__global__ void k_cl_reduce(const float* __restrict__ Clp, const float* __restrict__ bl,
                            float* __restrict__ cl) {
  int id = blockIdx.x * blockDim.x + threadIdx.x;
  if (id >= 640000) return;
  int m = id / 160, n4 = (id % 160) * 4;
  long o = (long)m * 640 + n4;
  f32x4 s = {0.f, 0.f, 0.f, 0.f};
#pragma unroll
  for (int z = 0; z < 4; z++) s += *(const f32x4*)&Clp[(long)z * 2560000 + o];
  float b = bl[m];
  s += (f32x4){b, b, b, b};
  *(f32x4*)&cl[o] = s;
}

// ---------------------------------------------------------------------------
// Bp[fp][eg][dw*800+gi] = f16( sum_dh A9[(dh*3+dw)][ (fp-dh)*120+eg ][gi] )
__global__ void k_fold_bp(const float* __restrict__ A9, f16* __restrict__ Bp) {
  int id = blockIdx.x * blockDim.x + threadIdx.x;
  if (id >= 7 * 120 * 2400) return;
  int fp = id / 288000;
  int r = id % 288000;
  int eg = r / 2400, k = r % 2400;
  int dw = k / 800, gi = k % 800;
  float s = 0.f;
#pragma unroll
  for (int dh = 0; dh < 3; dh++) {
    int f = fp - dh;
    if (f >= 0 && f < 5)
      s += A9[((long)(dh * 3 + dw) * 640 + f * 120 + eg) * 800 + gi];
  }
  Bp[id] = (f16)s;
}

// ---------------------------------------------------------------------------
// U GEMM: waves along M, block 64x48(40 real). grid (28, 21=(fp,zk)).
__global__ __launch_bounds__(256) void k_gemm_u(
    const f16* __restrict__ Pg, const f16* __restrict__ Pp, const f16* __restrict__ Pc,
    const f16* __restrict__ Bp, float* __restrict__ Upart) {
  __shared__ __align__(16) f16 As[2][2048];
  __shared__ __align__(16) f16 Bs[2][2048];
  int m0 = blockIdx.x * 64;
  int y = blockIdx.y, fp = y / 3, zk = y % 3;
  const f16* P; int seg0, jw, Wp, e0;
  if (m0 < 640)       { seg0 = 0;    jw = 40; Wp = 42; e0 = 0;  P = Pg; }
  else if (m0 < 1152) { seg0 = 640;  jw = 30; Wp = 32; e0 = 40; P = Pp; }
  else                { seg0 = 1152; jw = 40; Wp = 42; e0 = 80; P = Pc; }
  P += (long)fp * 16 * Wp * 800;
  int t = threadIdx.x;
  const f16 *ap, *bp;
  {
    int row = t >> 2, ch = t & 3;
    int l = m0 + row - seg0; if (l >= 16 * jw) l = 0;
    ap = P + ((long)(l / jw) * Wp + (l % jw)) * 800 + (long)zk * 800 + ch * 8;
    int brow = row; if (e0 + brow > 119) brow = 119 - e0;
    bp = Bp + ((long)fp * 120 + e0 + brow) * 2400 + (long)zk * 800 + ch * 8;
  }
  int lane = t & 63, wv = t >> 6, l15 = lane & 15, kg = lane >> 4;
  f32x4 acc[3] = {};
  gload_lds(&As[0][t * 8], ap);
  gload_lds(&Bs[0][t * 8], bp);
  __syncthreads();
  int cur = 0;
  for (int kt = 0; kt < 25; kt++) {
    if (kt + 1 < 25) {
      int o = (kt + 1) * 32, nb = cur ^ 1;
      gload_lds(&As[nb][t * 8], ap + o);
      gload_lds(&Bs[nb][t * 8], bp + o);
    }
    half8 av = *(const half8*)(&As[cur][(wv * 16 + l15) * 32 + kg * 8]);
#pragma unroll
    for (int j = 0; j < 3; j++) {
      half8 bv = *(const half8*)(&Bs[cur][(j * 16 + l15) * 32 + kg * 8]);
      acc[j] = __builtin_amdgcn_mfma_f32_16x16x32_f16(av, bv, acc[j], 0, 0, 0);
    }
    __syncthreads();
    cur ^= 1;
  }
#pragma unroll
  for (int j = 0; j < 3; j++) {
    int n = j * 16 + l15;
    if (n >= 40) continue;
    f32x4 d = acc[j];
#pragma unroll
    for (int r = 0; r < 4; r++) {
      int m = m0 + wv * 16 + kg * 4 + r;
      if (m - seg0 >= 16 * jw) continue;
      Upart[((long)y * 1792 + m) * 40 + n] = d[r];
    }
  }
}

// Ufin[m][e] = sum_y Upart + cbblv[e0(m)+e]
__global__ void k_ured(const float* __restrict__ Upart, const float* __restrict__ cbblv,
                       float* __restrict__ Ufin) {
  int id = blockIdx.x * blockDim.x + threadIdx.x;
  if (id >= 1792 * 40) return;
  int m = id / 40, e = id % 40;
  int e0 = m < 640 ? 0 : (m < 1152 ? 40 : 80);
  float s = cbblv[e0 + e];
  for (int y = 0; y < 21; y++) s += Upart[(long)y * 71680 + id];
  Ufin[id] = s;
}

// cbblv[e] = sum_s bconv_o[s/5]*Vt[s,e] + b_local[s]*v[s,e]; svv[e]=sum_s v[s,e]
__global__ __launch_bounds__(256) void k_consts(
    const float* __restrict__ Vt, const float* __restrict__ vmat,
    const float* __restrict__ bconv, const float* __restrict__ blocal,
    float* __restrict__ cbblv, float* __restrict__ svv) {
  __shared__ float r1[256], r2[256];
  int e = blockIdx.x, t = threadIdx.x;
  float a = 0.f, b = 0.f;
  for (int s = t; s < 4000; s += 256) {
    a += bconv[s / 5] * Vt[(long)s * 120 + e] + blocal[s] * vmat[(long)s * 120 + e];
    b += vmat[(long)s * 120 + e];
  }
  r1[t] = a; r2[t] = b; __syncthreads();
  for (int o = 128; o > 0; o >>= 1) {
    if (t < o) { r1[t] += r1[t + o]; r2[t] += r2[t + o]; }
    __syncthreads();
  }
  if (t == 0) { cbblv[e] = r1[0]; svv[e] = r2[0]; }
}

// ---------------------------------------------------------------------------
__global__ __launch_bounds__(256) void k_kv_partial(
    const float* __restrict__ cl, const float* __restrict__ wlk, const float* __restrict__ blk,
    const float* __restrict__ wlv, const float* __restrict__ blv, float* __restrict__ kvp) {
  __shared__ float s_wk[1600], s_wv[1600];
  __shared__ float s_cl[8][40], s_k[8][40], s_v[8][40];
  int t = threadIdx.x, chunk = blockIdx.x, b = blockIdx.y;
  for (int p = t; p < 1600; p += 256) { s_wk[p] = wlk[p]; s_wv[p] = wlv[p]; }
  float acc[7] = {0.f, 0.f, 0.f, 0.f, 0.f, 0.f, 0.f};
  for (int c8 = 0; c8 < 20; c8++) {
    int sb = chunk * 160 + c8 * 8;
    __syncthreads();
    for (int p = t; p < 320; p += 256) {
      int sl = p / 40, e = p % 40;
      s_cl[sl][e] = cl[(long)(sb + sl) * 640 + b * 40 + e];
    }
    __syncthreads();
    for (int p = t; p < 640; p += 256) {
      int half = p / 320, q = p % 320, sl = q / 40, d = q % 40;
      const float* w = half ? s_wv : s_wk;
      float r = half ? blv[d] : blk[d];
      for (int e = 0; e < 40; e++) r += w[d * 40 + e] * s_cl[sl][e];
      if (half) s_v[sl][d] = r; else s_k[sl][d] = r;
    }
    __syncthreads();
    int ai = 0;
    for (int p = t; p < 1600; p += 256, ai++) {
      int d = p / 40, e = p % 40;
      float a = acc[ai];
      for (int sl = 0; sl < 8; sl++) a += s_k[sl][d] * s_v[sl][e];
      acc[ai] = a;
    }
  }
  int ai = 0;
  for (int p = t; p < 1600; p += 256, ai++)
    kvp[((long)(b * 25 + chunk)) * 1600 + p] = acc[ai];
}

__global__ void k_kv_reduce(const float* __restrict__ kvp, float* __restrict__ kv) {
  int i = blockIdx.x * blockDim.x + threadIdx.x;
  if (i >= 16 * 1600) return;
  int b = i / 1600, p = i % 1600;
  float s = 0.f;
  for (int c = 0; c < 25; c++) s += kvp[((long)(b * 25 + c)) * 1600 + p];
  kv[i] = s;
}

// ---------------------------------------------------------------------------
__global__ __launch_bounds__(256) void k_combine(
    const float* __restrict__ Ufin, const float* __restrict__ kvb,
    const float* __restrict__ vmat, const float* __restrict__ lsp32,
    const float* __restrict__ wgq, const float* __restrict__ wpq, const float* __restrict__ wcq,
    const float* __restrict__ bgq, const float* __restrict__ bpq, const float* __restrict__ bcq,
    const float* __restrict__ svv, const float* __restrict__ c1p,
    const float* __restrict__ bcls, const float* __restrict__ bnw,
    const float* __restrict__ bnb, float* __restrict__ out) {
  __shared__ float s_kv[1600], s_U[4800], s_w[4400], s_bq[120], s_sv[120], s_red[256];
  int b = blockIdx.x, t = threadIdx.x;
  for (int p = t; p < 1600; p += 256) {
    s_kv[p] = kvb[b * 1600 + p];
    s_w[p] = wgq[p];
    s_w[2800 + p] = wcq[p];
  }
  for (int p = t; p < 1200; p += 256) s_w[1600 + p] = wpq[p];
  for (int p = t; p < 4800; p += 256) {
    int tt = p / 1600, r = p % 1600, j = r / 40, e = r % 40;
    float uv = 0.f;
    if (tt == 0) uv = Ufin[(b * 40 + j) * 40 + e];
    else if (tt == 1) { if (j < 30) uv = Ufin[(640 + b * 30 + j) * 40 + e]; }
    else uv = Ufin[(1152 + b * 40 + j) * 40 + e];
    s_U[p] = uv;
  }
  if (t < 40) { s_bq[t] = bgq[t]; s_bq[40 + t] = bpq[t]; s_bq[80 + t] = bcq[t]; }
  for (int p = t; p < 120; p += 256) s_sv[p] = svv[p];
  __syncthreads();
  float y = 0.f;
  for (int p = t; p < 4800; p += 256) {
    int tt = p / 1600, q = p % 1600, d = q / 40, e = q % 40;
    float T = 0.f;
    if (tt == 0) {
      for (int j = 0; j < 40; j++) T += s_w[d * 40 + j] * s_U[j * 40 + e];
    } else if (tt == 1) {
      for (int j = 0; j < 30; j++) T += s_w[1600 + d * 30 + j] * s_U[1600 + j * 40 + e];
    } else {
      for (int j = 0; j < 40; j++) T += s_w[2800 + d * 40 + j] * s_U[3200 + j * 40 + e];
    }
    y += s_kv[d * 40 + e] * (T + s_bq[tt * 40 + d] * s_sv[tt * 40 + e]);
  }
  for (int s = t; s < 4000; s += 256) {
    const f32x4* lp = (const f32x4*)(lsp32 + ((long)b * SEQN + s) * 40);
    const f32x4* vp = (const f32x4*)(vmat + (long)s * 120);
#pragma unroll
    for (int d4 = 0; d4 < 10; d4++) {
      f32x4 l = lp[d4];
      f32x4 vs = vp[d4] + vp[10 + d4] + vp[20 + d4];
      y += l[0] * vs[0] + l[1] * vs[1] + l[2] * vs[2] + l[3] * vs[3];
    }
  }
  s_red[t] = y; __syncthreads();
  for (int o = 128; o > 0; o >>= 1) { if (t < o) s_red[t] += s_red[t + o]; __syncthreads(); }
  if (t == 0) {
    float c1 = bcls[0];
    for (int i = 0; i < 120; i++) c1 += c1p[i];
    float yy = s_red[0] * (1.f / 1024.f) + c1;
    yy = yy * (bnw[0] * rsqrtf(1.f + 1e-5f)) + bnb[0];
    out[b] = 1.f / (1.f + expf(-yy));
  }
}

// ---------------------------------------------------------------------------
extern "C" void kernel_launch(void* const* d_in, const int* in_sizes, int n_in,
                              void* d_out, int out_size, void* d_ws, size_t ws_size,
                              hipStream_t stream) {
  const int*   X        = (const int*)d_in[0];
  const float* emb      = (const float*)d_in[1];
  const float* w_dwc_l  = (const float*)d_in[2];
  const float* b_dwc_l  = (const float*)d_in[3];
  const float* w_dwc_o  = (const float*)d_in[4];
  const float* b_dwc_o  = (const float*)d_in[5];
  const float* w_local  = (const float*)d_in[6];
  const float* b_local  = (const float*)d_in[7];
  const float* w_global = (const float*)d_in[8];
  const float* b_global = (const float*)d_in[9];
  const float* w_gq = (const float*)d_in[10];
  const float* b_gq = (const float*)d_in[11];
  const float* w_cq = (const float*)d_in[12];
  const float* b_cq = (const float*)d_in[13];
  const float* w_pq = (const float*)d_in[14];
  const float* b_pq = (const float*)d_in[15];
  const float* w_lk = (const float*)d_in[16];
  const float* b_lk = (const float*)d_in[17];
  const float* w_lv = (const float*)d_in[18];
  const float* b_lv = (const float*)d_in[19];
  const float* w_cls = (const float*)d_in[20];
  const float* b_cls = (const float*)d_in[21];
  const float* bn_w = (const float*)d_in[22];
  const float* bn_b = (const float*)d_in[23];
  float* out = (float*)d_out;

  char* ws = (char*)d_ws;
  size_t off = 0;
  auto alloc = [&](size_t bytes) -> void* {
    off = (off + 255) & ~(size_t)255;
    void* p = ws + off; off += bytes; return p;
  };

  const size_t sz_p40 = (size_t)7 * 16 * 42 * 800 * 2;
  const size_t sz_p30 = (size_t)7 * 16 * 32 * 800 * 2;
  f16* P_lsp = (f16*)alloc(sz_p40);
  f16* P_pit = (f16*)alloc(sz_p30);
  f16* P_cod = (f16*)alloc(sz_p40);
  f16* P_gai = (f16*)alloc(sz_p40);
  float* lsp32 = (float*)alloc((size_t)16 * 4000 * 40 * 4);
  f16* wp_lsp = (f16*)alloc((size_t)896 * 7200 * 2);
  f16* wlp    = (f16*)alloc((size_t)4000 * 4000 * 2);
  f16* wcT    = (f16*)alloc((size_t)128 * 4000 * 2);
  f16* vT     = (f16*)alloc((size_t)128 * 4000 * 2);
  f16* co     = (f16*)alloc((size_t)640 * 4000 * 2);
  float* cl   = (float*)alloc((size_t)4000 * 640 * 4);
  float* vmat  = (float*)alloc((size_t)480000 * 4);
  float* Vt    = (float*)alloc((size_t)480000 * 4);
  f16* vtT   = (f16*)alloc((size_t)640 * 800 * 2);
  f16* Bp    = (f16*)alloc((size_t)7 * 120 * 2400 * 2);
  float* Upart = (float*)alloc((size_t)21 * 1792 * 40 * 4);
  float* Ufin  = (float*)alloc((size_t)1792 * 40 * 4);
  float* cbblv = (float*)alloc(120 * 4);
  float* svv   = (float*)alloc(120 * 4);
  float* kvp  = (float*)alloc((size_t)400 * 1600 * 4);
  float* kvb  = (float*)alloc((size_t)16 * 1600 * 4);
  float* c1p  = (float*)alloc(120 * 4);
  // arena: A9(18.43MB)@0 | woT(11.68MB)@18.5MB | vpart(19.2MB)@30.2MB ; later Cp@0(30.7MB), Clp@0(41MB)
  char* arena = (char*)alloc((size_t)52 * 1024 * 1024);
  float* A9   = (float*)arena;
  f16*   woT  = (f16*)(arena + 18500000);
  float* vpart = (float*)(arena + 30200000);
  float* Cp   = (float*)arena;
  float* Clp  = (float*)arena;
  (void)ws_size; (void)in_sizes; (void)n_in; (void)out_size;

  // zero conv-pad borders
  hipMemsetAsync(P_lsp, 0, sz_p40, stream);
  hipMemsetAsync(P_pit, 0, sz_p30, stream);
  hipMemsetAsync(P_cod, 0, sz_p40, stream);
  hipMemsetAsync(P_gai, 0, sz_p40, stream);

  // prep
  k_prepA<<<5300, 256, 0, stream>>>(w_dwc_l, wp_lsp, w_local, wlp, w_cls, wcT);
  k_pack_woT<<<625, 256, 0, stream>>>(w_dwc_o, woT);
  k_prepB<<<4208, 256, 0, stream>>>(X, emb, P_lsp, P_pit, P_cod, P_gai,
                                    lsp32, wp_lsp, w_cls, b_global, c1p);

  // v = w_global^T @ (wc*1024): TN, splitK 10
  {
    dim3 g(32, 10);
    k_gemm_tn<<<g, 256, 0, stream>>>(wcT, 4000, w_global, 4000, vpart, 4000,
                                     13, 125, 480000, 120, 4000);
  }
  {
    dim3 g(32, 3);
    k_vredT2<0><<<g, 128, 0, stream>>>(vpart, vmat, vT);
  }

  // Vt = w_local^T @ v: TN, splitK 10
  {
    dim3 g(32, 10);
    k_gemm_tn<<<g, 256, 0, stream>>>(vT, 4000, w_local, 4000, vpart, 4000,
                                     13, 125, 480000, 120, 4000);
  }
  {
    dim3 g(32, 3);
    k_vredT2<1><<<g, 128, 0, stream>>>(vpart, Vt, vtT);
  }

  k_consts<<<120, 256, 0, stream>>>(Vt, vmat, b_dwc_o, b_local, cbblv, svv);

  // A9[z][fe][gi] = sum_g vtT[fe][g]*woT[z][gi][g]  (MT=64, z=9)
  {
    dim3 g(70, 1, 9);
    k_gemm64<<<g, 256, 0, stream>>>(vtT, 800, woT, 800, A9, 800,
                                    7, 70, 25, 25, 0, 0, 640000, 512000, 600, 800, 600);
  }
  k_fold_bp<<<7875, 256, 0, stream>>>(A9, Bp);

  // lsp conv GEMM (MT=64, splitK 3 over df) + reduce w/ bias
  {
    dim3 g(350, 3);
    k_gemm_conv<<<g, 256, 0, stream>>>(P_lsp, wp_lsp, Cp);
  }
  k_co_reduce<<<2500, 256, 0, stream>>>(Cp, b_dwc_l, co);

  // cl = w_local(permuted) @ co^T + b_local : MT=64, splitK 4 -> Clp, reduce
  {
    dim3 g(315, 4);
    k_gemm64<<<g, 256, 0, stream>>>(wlp, 4000, co, 4000, Clp, 640,
                                    5, 315, 32, 125, 2560000L, 0, 0, 0, 4000, 640, 4000);
  }
  k_cl_reduce<<<2500, 256, 0, stream>>>(Clp, b_local, cl);

  // kv
  {
    dim3 g(25, 16);
    k_kv_partial<<<g, 256, 0, stream>>>(cl, w_lk, b_lk, w_lv, b_lv, kvp);
  }
  k_kv_reduce<<<100, 256, 0, stream>>>(kvp, kvb);

  // U path (waves-along-M tiles, splitK 3 over dw)
  {
    dim3 g(28, 21);
    k_gemm_u<<<g, 256, 0, stream>>>(P_gai, P_pit, P_cod, Bp, Upart);
  }
  k_ured<<<280, 256, 0, stream>>>(Upart, cbblv, Ufin);

  // final combine
  k_combine<<<16, 256, 0, stream>>>(Ufin, kvb, vmat, lsp32,
                                    w_gq, w_pq, w_cq, b_gq, b_pq, b_cq,
                                    svv, c1p, b_cls, bn_w, bn_b, out);
}

// Round 7
// 569.795 us; speedup vs baseline: 1.5477x; 1.0313x over previous
//
#include <hip/hip_runtime.h>
#include <hip/hip_bf16.h>

typedef _Float16 f16;
typedef __attribute__((ext_vector_type(8))) _Float16 half8;
typedef __attribute__((ext_vector_type(4))) _Float16 half4;
typedef __attribute__((ext_vector_type(4))) float f32x4;

static const int BN = 16, SEQN = 4000;

// ---------------------------------------------------------------------------
__device__ __forceinline__ void gload_lds(f16* lds, const f16* g) {
  __builtin_amdgcn_global_load_lds((const __attribute__((address_space(1))) unsigned int*)g,
                                   (__attribute__((address_space(3))) unsigned int*)lds, 16, 0, 0);
}

// bijective XCD swizzle (m204)
__device__ __forceinline__ int xcd_swz(int orig, int nwg) {
  int q = nwg >> 3, r = nwg & 7, x = orig & 7, o = orig >> 3;
  return (x < r ? x * (q + 1) : r * (q + 1) + (x - r) * q) + o;
}

// ---------------------------------------------------------------------------
// prepA: LDS-permute packs. [0,800) wconv->7296 | [800,4800) wlocal->4096 | [4800,5300) wcT
__global__ __launch_bounds__(256) void k_prepA(
    const float* __restrict__ w_dwc_l, f16* __restrict__ wp_lsp,
    const float* __restrict__ w_local, f16* __restrict__ wlp,
    const float* __restrict__ w_cls, f16* __restrict__ wcT) {
  __shared__ float sh[7200];
  int bid = blockIdx.x, t = threadIdx.x;
  if (bid < 800) {
    int o = bid;
    for (int p = t; p < 7200; p += 256) sh[p] = w_dwc_l[(long)o * 7200 + p];
    __syncthreads();
    // wp[o][df*2432 + de*800 + gi] = w[o][gi*9 + df*3+de], zero tail per df
    for (int p = t; p < 7296; p += 256) {
      int seg = p / 2432, r = p - seg * 2432;
      f16 v = (f16)0.f;
      if (r < 2400) { int de = r / 800, gi = r % 800; v = (f16)sh[gi * 9 + seg * 3 + de]; }
      wp_lsp[(long)o * 7296 + p] = v;
    }
  } else if (bid < 4800) {
    int s = bid - 800;
    for (int p = t; p < 4000; p += 256) sh[p] = w_local[(long)s * 4000 + p];
    __syncthreads();
    for (int p = t; p < 4096; p += 256) {
      f16 v = (f16)0.f;
      if (p < 4000) { int f = p / 800, g = p % 800; v = (f16)sh[g * 5 + f]; }
      wlp[(long)s * 4096 + p] = v;
    }
  } else {
    int id = bid - 4800;
    int c0 = (id % 4) * 32, r0 = (id / 4) * 32;
    int tx = t & 31, ty = t >> 5;
    float (*tile)[33] = (float(*)[33])sh;
    for (int i = ty; i < 32; i += 8) {
      int r = r0 + i, c = c0 + tx;
      tile[i][tx] = (r < 4000 && c < 120) ? w_cls[(long)r * 120 + c] : 0.f;
    }
    __syncthreads();
    for (int i = ty; i < 32; i += 8) {
      int c = c0 + i, r = r0 + tx;
      if (c < 128 && r < 4000) wcT[(long)c * 4000 + r] = (f16)(tile[tx][i] * 1024.f);
    }
  }
}

// ---------------------------------------------------------------------------
// woT pack via LDS transpose: woT[z][gi][g] = w_dwc_o[g][gi*9+z]
__global__ __launch_bounds__(256) void k_pack_woT(const float* __restrict__ in,
                                                  f16* __restrict__ out) {
  __shared__ float sh[32][289];
  int bg = blockIdx.x % 25, bgi = blockIdx.x / 25;
  int g0 = bg * 32, gi0 = bgi * 32;
  int t = threadIdx.x;
  for (int p = t; p < 32 * 288; p += 256) {
    int gl = p / 288, q = p % 288;
    sh[gl][q] = in[(long)(g0 + gl) * 7200 + gi0 * 9 + q];
  }
  __syncthreads();
  for (int p = t; p < 9 * 32 * 32; p += 256) {
    int gl = p & 31, q = p >> 5;
    int gil = q & 31, z = q >> 5;
    out[(long)z * 640000 + (gi0 + gil) * 800 + g0 + gl] = (f16)sh[gl][gil * 9 + z];
  }
}

// prepB: [0,3750) gather | [3750,3870) c1
__global__ __launch_bounds__(256) void k_prepB(
    const int* __restrict__ X, const float* __restrict__ emb,
    f16* __restrict__ P_lsp, f16* __restrict__ P_pit,
    f16* __restrict__ P_cod, f16* __restrict__ P_gai,
    float* __restrict__ lsp32,
    const float* __restrict__ wcls, const float* __restrict__ bg,
    float* __restrict__ c1p) {
  __shared__ float red[256];
  int bid = blockIdx.x, t = threadIdx.x;
  if (bid < 3750) {
    const float scale[15] = {1.f,1.f,1.f,1.f,0.8f,0.512f,0.8f,0.64f,0.512f,0.64f,0.512f,0.8f,0.64f,0.512f,0.512f};
    const int br[15] = {0,0,0,0,1,1,2,2,3,3,1,2,2,3,3};
    const int po[15] = {0,1,2,3,0,1,0,1,0,2,2,2,3,1,3};
    int id = bid * 256 + t;
    int g = id % 800; int tmp = id / 800;
    int f = tmp % 5; tmp /= 5;
    int b = tmp % 16; int c = tmp / 16;
    int s = g * 5 + f;
    int idx = X[((long)b * SEQN + s) * 15 + c];
    const float* er = emb + (long)idx * 10;
    int ty = br[c], p = po[c];
    f16* P = (ty == 0) ? P_lsp : (ty == 1) ? P_pit : (ty == 2) ? P_cod : P_gai;
    int Wp = (ty == 1) ? 32 : 42;
    f16* base = P + ((long)((f + 1) * 16 + b) * Wp + (1 + p * 10)) * 800 + g;
    float sc = scale[c];
#pragma unroll
    for (int j = 0; j < 10; j++) {
      float v = er[j] * sc;
      base[(long)j * 800] = (f16)v;
      if (ty == 0) lsp32[((long)b * SEQN + s) * 40 + p * 10 + j] = v;
    }
  } else {
    int blk = bid - 3750;
    float s = 0.f;
    for (long i = (long)blk * 256 + t; i < 480000; i += (long)120 * 256)
      s += wcls[i] * bg[i / 120];
    red[t] = s; __syncthreads();
    for (int o = 128; o > 0; o >>= 1) { if (t < o) red[t] += red[t + o]; __syncthreads(); }
    if (t == 0) c1p[blk] = red[0];
  }
}

// ---------------------------------------------------------------------------
// conv GEMM MT=64, BK=64 + XOR-swizzled LDS (conflict-free ds_read_b128).
// grid (350, 3). z=df, K=2432 (zero-tail in wp). Partials -> Cp[df][3200][800].
__global__ __launch_bounds__(256) void k_gemm_conv(
    const f16* __restrict__ P, const f16* __restrict__ wp, float* __restrict__ Cp) {
  __shared__ __align__(16) f16 As[2][4096];
  __shared__ __align__(16) f16 Bs[2][8192];
  int lin = xcd_swz(blockIdx.x, 350);
  int nx = lin % 7, my = lin / 7;
  int m0 = my * 64, n0 = nx * 128;
  int df = blockIdx.y;
  Cp += (long)df * 3200 * 800;
  int t = threadIdx.x;
  int gslot = (t & 7) ^ ((t >> 3) & 7);  // pre-swizzled global k-slot
  const f16 *ap[2], *bp[4];
#pragma unroll
  for (int q = 0; q < 2; q++) {
    int row = q * 32 + (t >> 3);
    int m = m0 + row;
    int f = m / 640, rem = m % 640, b = rem / 40, e = rem % 40;
    ap[q] = P + ((long)((f + df) * 16 + b) * 42 + e) * 800 + gslot * 8;
  }
#pragma unroll
  for (int q = 0; q < 4; q++) {
    int row = q * 32 + (t >> 3);
    bp[q] = wp + (long)(n0 + row) * 7296 + df * 2432 + gslot * 8;
  }
  int lane = t & 63, wv = t >> 6, l15 = lane & 15, kg = lane >> 4;
  int wn = wv * 32, sx = l15 & 7;
  f32x4 acc[4][2] = {};
  gload_lds(&As[0][t * 8], ap[0]); gload_lds(&As[0][2048 + t * 8], ap[1]);
  gload_lds(&Bs[0][t * 8], bp[0]); gload_lds(&Bs[0][2048 + t * 8], bp[1]);
  gload_lds(&Bs[0][4096 + t * 8], bp[2]); gload_lds(&Bs[0][6144 + t * 8], bp[3]);
  __syncthreads();
  int cur = 0;
  for (int kt = 0; kt < 38; kt++) {
    if (kt + 1 < 38) {
      int o = (kt + 1) * 64, nb = cur ^ 1;
      gload_lds(&As[nb][t * 8], ap[0] + o); gload_lds(&As[nb][2048 + t * 8], ap[1] + o);
      gload_lds(&Bs[nb][t * 8], bp[0] + o); gload_lds(&Bs[nb][2048 + t * 8], bp[1] + o);
      gload_lds(&Bs[nb][4096 + t * 8], bp[2] + o); gload_lds(&Bs[nb][6144 + t * 8], bp[3] + o);
    }
#pragma unroll
    for (int ks = 0; ks < 2; ks++) {
      int so = ((ks * 4 + kg) ^ sx) << 3;
      half8 av[4], bv[2];
#pragma unroll
      for (int i = 0; i < 4; i++) av[i] = *(const half8*)&As[cur][(i * 16 + l15) * 64 + so];
#pragma unroll
      for (int j = 0; j < 2; j++) bv[j] = *(const half8*)&Bs[cur][(wn + j * 16 + l15) * 64 + so];
#pragma unroll
      for (int i = 0; i < 4; i++)
#pragma unroll
        for (int j = 0; j < 2; j++)
          acc[i][j] = __builtin_amdgcn_mfma_f32_16x16x32_f16(av[i], bv[j], acc[i][j], 0, 0, 0);
    }
    __syncthreads();
    cur ^= 1;
  }
#pragma unroll
  for (int i = 0; i < 4; i++) {
    int mb = m0 + i * 16 + kg * 4;
#pragma unroll
    for (int j = 0; j < 2; j++) {
      int n = n0 + wn + j * 16 + l15;
      if (n >= 800) continue;
      f32x4 d = acc[i][j];
#pragma unroll
      for (int r = 0; r < 4; r++)
        Cp[(long)(mb + r) * 800 + n] = d[r];
    }
  }
}

// co[(b*40+e)][f*800+n] = f16( sum_z Cp[z][m][n] + bias[n] )
__global__ void k_co_reduce(const float* __restrict__ Cp, const float* __restrict__ bias,
                            f16* __restrict__ co) {
  int id = blockIdx.x * blockDim.x + threadIdx.x;
  if (id >= 640000) return;
  int m = id / 200, n4 = (id % 200) * 4;
  long o = (long)m * 800 + n4;
  f32x4 s = *(const f32x4*)&bias[n4];
#pragma unroll
  for (int z = 0; z < 3; z++) s += *(const f32x4*)&Cp[(long)z * 2560000 + o];
  int f = m / 640, r2 = m % 640;
  half4 h = {(f16)s[0], (f16)s[1], (f16)s[2], (f16)s[3]};
  *(half4*)&co[(long)r2 * 4000 + f * 800 + n4] = h;
}

// ---------------------------------------------------------------------------
// generic NT GEMM MT=64/NT=128, BK=64 swizzled, dbuf, splitK(y)+z-slices.
__global__ __launch_bounds__(256) void k_gemm64(
    const f16* __restrict__ A, int lda, const f16* __restrict__ Bm, int ldb,
    float* __restrict__ C, int ldc,
    int gx, int nwg, int nkt, int KTtot, long cslice, long az, long bz, long cz,
    int Mreal, int Nreal, int Aclamp) {
  __shared__ __align__(16) f16 As[2][4096];
  __shared__ __align__(16) f16 Bs[2][8192];
  A += (long)blockIdx.z * az;
  Bm += (long)blockIdx.z * bz;
  C += (long)blockIdx.z * cz + (long)blockIdx.y * cslice;
  int lin = xcd_swz(blockIdx.x, nwg);
  int nx = lin % gx, my = lin / gx;
  int m0 = my * 64, n0 = nx * 128;
  int kt0 = blockIdx.y * nkt;
  int ktn = nkt; if (kt0 + ktn > KTtot) ktn = KTtot - kt0;
  int t = threadIdx.x;
  int gslot = (t & 7) ^ ((t >> 3) & 7);
  const f16 *ap[2], *bp[4];
#pragma unroll
  for (int q = 0; q < 2; q++) {
    int row = q * 32 + (t >> 3);
    int ra = m0 + row; if (ra >= Aclamp) ra = Aclamp - 1;
    ap[q] = A + (long)ra * lda + (long)kt0 * 64 + gslot * 8;
  }
#pragma unroll
  for (int q = 0; q < 4; q++) {
    int row = q * 32 + (t >> 3);
    bp[q] = Bm + (long)(n0 + row) * ldb + (long)kt0 * 64 + gslot * 8;
  }
  int lane = t & 63, wv = t >> 6, l15 = lane & 15, kg = lane >> 4;
  int wn = wv * 32, sx = l15 & 7;
  f32x4 acc[4][2] = {};
  gload_lds(&As[0][t * 8], ap[0]); gload_lds(&As[0][2048 + t * 8], ap[1]);
  gload_lds(&Bs[0][t * 8], bp[0]); gload_lds(&Bs[0][2048 + t * 8], bp[1]);
  gload_lds(&Bs[0][4096 + t * 8], bp[2]); gload_lds(&Bs[0][6144 + t * 8], bp[3]);
  __syncthreads();
  int cur = 0;
  for (int kt = 0; kt < ktn; kt++) {
    if (kt + 1 < ktn) {
      int o = (kt + 1) * 64, nb = cur ^ 1;
      gload_lds(&As[nb][t * 8], ap[0] + o); gload_lds(&As[nb][2048 + t * 8], ap[1] + o);
      gload_lds(&Bs[nb][t * 8], bp[0] + o); gload_lds(&Bs[nb][2048 + t * 8], bp[1] + o);
      gload_lds(&Bs[nb][4096 + t * 8], bp[2] + o); gload_lds(&Bs[nb][6144 + t * 8], bp[3] + o);
    }
#pragma unroll
    for (int ks = 0; ks < 2; ks++) {
      int so = ((ks * 4 + kg) ^ sx) << 3;
      half8 av[4], bv[2];
#pragma unroll
      for (int i = 0; i < 4; i++) av[i] = *(const half8*)&As[cur][(i * 16 + l15) * 64 + so];
#pragma unroll
      for (int j = 0; j < 2; j++) bv[j] = *(const half8*)&Bs[cur][(wn + j * 16 + l15) * 64 + so];
#pragma unroll
      for (int i = 0; i < 4; i++)
#pragma unroll
        for (int j = 0; j < 2; j++)
          acc[i][j] = __builtin_amdgcn_mfma_f32_16x16x32_f16(av[i], bv[j], acc[i][j], 0, 0, 0);
    }
    __syncthreads();
    cur ^= 1;
  }
#pragma unroll
  for (int i = 0; i < 4; i++) {
    int mb = m0 + i * 16 + kg * 4;
#pragma unroll
    for (int j = 0; j < 2; j++) {
      int n = n0 + wn + j * 16 + l15;
      if (n >= Nreal) continue;
      f32x4 d = acc[i][j];
#pragma unroll
      for (int r = 0; r < 4; r++) {
        int m = mb + r;
        if (m >= Mreal) continue;
        C[(long)m * ldc + n] = d[r];
      }
    }
  }
}

// ---------------------------------------------------------------------------
// TN GEMM: C[m][n] = sum_k A[m*lda+k](f16) * B[k*ldb+n](f32). Single M-tile.
__global__ __launch_bounds__(256) void k_gemm_tn(
    const f16* __restrict__ A, int lda, const float* __restrict__ B, int ldb,
    float* __restrict__ C, int ldc, int nkt, int KTtot, long cslice,
    int Mreal, int Nreal) {
  __shared__ __align__(16) f16 As[4096];
  __shared__ __align__(16) f16 Bs[128 * 36];
  int n0 = blockIdx.x * 128;
  int kt0 = blockIdx.y * nkt;
  int ktn = nkt; if (kt0 + ktn > KTtot) ktn = KTtot - kt0;
  C += (long)blockIdx.y * cslice;
  int t = threadIdx.x;
  const f16 *ap0, *ap1;
  {
    int r0 = t >> 2, r1 = 64 + (t >> 2);
    if (r0 >= Mreal) r0 = Mreal - 1;
    if (r1 >= Mreal) r1 = Mreal - 1;
    ap0 = A + (long)r0 * lda + (long)kt0 * 32 + (t & 3) * 8;
    ap1 = A + (long)r1 * lda + (long)kt0 * 32 + (t & 3) * 8;
  }
  int lane = t & 63, wv = t >> 6;
  int wm = (wv >> 1) * 64, wn = (wv & 1) * 64;
  int l15 = lane & 15, kg = lane >> 4;
  f32x4 acc[4][4] = {};
  for (int kt = 0; kt < ktn; kt++) {
    float rb[4][4];
    int nli[4], kqi[4];
#pragma unroll
    for (int i = 0; i < 4; i++) {
      int id = i * 256 + t;
      nli[i] = id & 127; kqi[i] = id >> 7;
      int gn = n0 + nli[i]; if (gn >= Nreal) gn = Nreal - 1;
      long kb = ((long)(kt0 + kt) * 32 + kqi[i] * 4);
#pragma unroll
      for (int j = 0; j < 4; j++) rb[i][j] = B[(kb + j) * ldb + gn];
    }
    __syncthreads();
    gload_lds(&As[t * 8], ap0 + kt * 32);
    gload_lds(&As[2048 + t * 8], ap1 + kt * 32);
#pragma unroll
    for (int i = 0; i < 4; i++) {
      half4 h = {(f16)rb[i][0], (f16)rb[i][1], (f16)rb[i][2], (f16)rb[i][3]};
      *(half4*)&Bs[nli[i] * 36 + kqi[i] * 4] = h;
    }
    __syncthreads();
    half8 av[4], bv[4];
#pragma unroll
    for (int i = 0; i < 4; i++) {
      av[i] = *(const half8*)(&As[(wm + i * 16 + l15) * 32 + kg * 8]);
      bv[i] = *(const half8*)(&Bs[(wn + i * 16 + l15) * 36 + kg * 8]);
    }
#pragma unroll
    for (int i = 0; i < 4; i++)
#pragma unroll
      for (int j = 0; j < 4; j++)
        acc[i][j] = __builtin_amdgcn_mfma_f32_16x16x32_f16(av[i], bv[j], acc[i][j], 0, 0, 0);
  }
#pragma unroll
  for (int i = 0; i < 4; i++) {
    int mb = wm + i * 16 + kg * 4;
#pragma unroll
    for (int j = 0; j < 4; j++) {
      int n = n0 + wn + j * 16 + l15;
      if (n >= Nreal) continue;
      f32x4 d = acc[i][j];
#pragma unroll
      for (int r = 0; r < 4; r++) {
        int m = mb + r;
        if (m >= Mreal) continue;
        C[(long)m * ldc + n] = d[r];
      }
    }
  }
}

// vredT2: sum 10 transposed slices, s-tiled. MODE 0 -> (vmat, vT), MODE 1 -> (Vt, vtT@832)
template <int MODE>
__global__ __launch_bounds__(128) void k_vredT2(const float* __restrict__ vp,
                                                float* __restrict__ vout,
                                                f16* __restrict__ tout) {
  int s = blockIdx.x * 128 + threadIdx.x;
  int ec = blockIdx.y;
  if (s >= 4000) return;
  int g = s / 5, f = s % 5;
  float sums[40];
#pragma unroll
  for (int eo = 0; eo < 40; eo++) {
    int e = ec * 40 + eo;
    float sum = 0.f;
#pragma unroll
    for (int z = 0; z < 10; z++) sum += vp[(long)z * 480000 + (long)e * 4000 + s];
    sums[eo] = sum;
    if (MODE == 0) tout[(long)e * 4000 + s] = (f16)sum;
    else tout[(long)(f * 120 + e) * 832 + g] = (f16)sum;
  }
#pragma unroll
  for (int q = 0; q < 10; q++)
    *(f32x4*)&vout[(long)s * 120 + ec * 40 + q * 4] = *(f32x4*)&sums[q * 4];
}

// cl[m][n] = sum_z Clp[z][m][n] + b_local[m]
__global__ void k_cl_reduce(const float* __restrict__ Clp, const float* __restrict__ bl,
                            float* __restrict__ cl) {
  int id = blockIdx.x * blockDim.x + threadIdx.x;
  if (id >= 640000) return;
  int m = id / 160, n4 = (id % 160) * 4;
  long o = (long)m * 640 + n4;
  f32x4 s = {0.f, 0.f, 0.f, 0.f};
#pragma unroll
  for (int z = 0; z < 4; z++) s += *(const f32x4*)&Clp[(long)z * 2560000 + o];
  float b = bl[m];
  s += (f32x4){b, b, b, b};
  *(f32x4*)&cl[o] = s;
}

// ---------------------------------------------------------------------------
// Bp[fp][eg][zk*832+kk] = f16( sum_dh A9[(dh*3+zk)][ (fp-dh)*120+eg ][kk] ), tail zero
__global__ void k_fold_bp(const float* __restrict__ A9, f16* __restrict__ Bp) {
  int id = blockIdx.x * blockDim.x + threadIdx.x;
  if (id >= 7 * 120 * 2496) return;
  int fp = id / 299520;
  int r = id % 299520;
  int eg = r / 2496, k2 = r % 2496;
  int zk = k2 / 832, kk = k2 % 832;
  if (kk >= 800) { Bp[id] = (f16)0.f; return; }
  float s = 0.f;
#pragma unroll
  for (int dh = 0; dh < 3; dh++) {
    int f = fp - dh;
    if (f >= 0 && f < 5)
      s += A9[((long)(dh * 3 + zk) * 640 + f * 120 + eg) * 800 + kk];
  }
  Bp[id] = (f16)s;
}

// ---------------------------------------------------------------------------
// U GEMM: BK=64 swizzled, block 64x48(40 real). grid (28, 21=(fp,zk)).
__global__ __launch_bounds__(256) void k_gemm_u(
    const f16* __restrict__ Pg, const f16* __restrict__ Pp, const f16* __restrict__ Pc,
    const f16* __restrict__ Bp, float* __restrict__ Upart) {
  __shared__ __align__(16) f16 As[2][4096];
  __shared__ __align__(16) f16 Bs[2][4096];
  int m0 = blockIdx.x * 64;
  int y = blockIdx.y, fp = y / 3, zk = y % 3;
  const f16* P; int seg0, jw, Wp, e0;
  if (m0 < 640)       { seg0 = 0;    jw = 40; Wp = 42; e0 = 0;  P = Pg; }
  else if (m0 < 1152) { seg0 = 640;  jw = 30; Wp = 32; e0 = 40; P = Pp; }
  else                { seg0 = 1152; jw = 40; Wp = 42; e0 = 80; P = Pc; }
  P += (long)fp * 16 * Wp * 800;
  int t = threadIdx.x;
  int gslot = (t & 7) ^ ((t >> 3) & 7);
  const f16 *ap[2], *bp[2];
#pragma unroll
  for (int q = 0; q < 2; q++) {
    int row = q * 32 + (t >> 3);
    int l = m0 + row - seg0; if (l >= 16 * jw) l = 0;
    ap[q] = P + ((long)(l / jw) * Wp + (l % jw)) * 800 + (long)zk * 800 + gslot * 8;
    int brow = row; if (e0 + brow > 119) brow = 119 - e0;
    bp[q] = Bp + ((long)fp * 120 + e0 + brow) * 2496 + zk * 832 + gslot * 8;
  }
  int lane = t & 63, wv = t >> 6, l15 = lane & 15, kg = lane >> 4;
  int sx = l15 & 7;
  f32x4 acc[3] = {};
  gload_lds(&As[0][t * 8], ap[0]); gload_lds(&As[0][2048 + t * 8], ap[1]);
  gload_lds(&Bs[0][t * 8], bp[0]); gload_lds(&Bs[0][2048 + t * 8], bp[1]);
  __syncthreads();
  int cur = 0;
  for (int kt = 0; kt < 13; kt++) {
    if (kt + 1 < 13) {
      int o = (kt + 1) * 64, nb = cur ^ 1;
      gload_lds(&As[nb][t * 8], ap[0] + o); gload_lds(&As[nb][2048 + t * 8], ap[1] + o);
      gload_lds(&Bs[nb][t * 8], bp[0] + o); gload_lds(&Bs[nb][2048 + t * 8], bp[1] + o);
    }
#pragma unroll
    for (int ks = 0; ks < 2; ks++) {
      int so = ((ks * 4 + kg) ^ sx) << 3;
      half8 av = *(const half8*)&As[cur][(wv * 16 + l15) * 64 + so];
#pragma unroll
      for (int j = 0; j < 3; j++) {
        half8 bv = *(const half8*)&Bs[cur][(j * 16 + l15) * 64 + so];
        acc[j] = __builtin_amdgcn_mfma_f32_16x16x32_f16(av, bv, acc[j], 0, 0, 0);
      }
    }
    __syncthreads();
    cur ^= 1;
  }
#pragma unroll
  for (int j = 0; j < 3; j++) {
    int n = j * 16 + l15;
    if (n >= 40) continue;
    f32x4 d = acc[j];
#pragma unroll
    for (int r = 0; r < 4; r++) {
      int m = m0 + wv * 16 + kg * 4 + r;
      if (m - seg0 >= 16 * jw) continue;
      Upart[((long)y * 1792 + m) * 40 + n] = d[r];
    }
  }
}

// Ufin[m][e] = sum_y Upart + cbblv[e0(m)+e]
__global__ void k_ured(const float* __restrict__ Upart, const float* __restrict__ cbblv,
                       float* __restrict__ Ufin) {
  int id = blockIdx.x * blockDim.x + threadIdx.x;
  if (id >= 1792 * 40) return;
  int m = id / 40, e = id % 40;
  int e0 = m < 640 ? 0 : (m < 1152 ? 40 : 80);
  float s = cbblv[e0 + e];
  for (int y = 0; y < 21; y++) s += Upart[(long)y * 71680 + id];
  Ufin[id] = s;
}

// cbblv[e] = sum_s bconv_o[s/5]*Vt[s,e] + b_local[s]*v[s,e]; svv[e]=sum_s v[s,e]
__global__ __launch_bounds__(256) void k_consts(
    const float* __restrict__ Vt, const float* __restrict__ vmat,
    const float* __restrict__ bconv, const float* __restrict__ blocal,
    float* __restrict__ cbblv, float* __restrict__ svv) {
  __shared__ float r1[256], r2[256];
  int e = blockIdx.x, t = threadIdx.x;
  float a = 0.f, b = 0.f;
  for (int s = t; s < 4000; s += 256) {
    a += bconv[s / 5] * Vt[(long)s * 120 + e] + blocal[s] * vmat[(long)s * 120 + e];
    b += vmat[(long)s * 120 + e];
  }
  r1[t] = a; r2[t] = b; __syncthreads();
  for (int o = 128; o > 0; o >>= 1) {
    if (t < o) { r1[t] += r1[t + o]; r2[t] += r2[t + o]; }
    __syncthreads();
  }
  if (t == 0) { cbblv[e] = r1[0]; svv[e] = r2[0]; }
}

// ---------------------------------------------------------------------------
__global__ __launch_bounds__(256) void k_kv_partial(
    const float* __restrict__ cl, const float* __restrict__ wlk, const float* __restrict__ blk,
    const float* __restrict__ wlv, const float* __restrict__ blv, float* __restrict__ kvp) {
  __shared__ float s_wk[1600], s_wv[1600];
  __shared__ float s_cl[8][40], s_k[8][40], s_v[8][40];
  int t = threadIdx.x, chunk = blockIdx.x, b = blockIdx.y;
  for (int p = t; p < 1600; p += 256) { s_wk[p] = wlk[p]; s_wv[p] = wlv[p]; }
  float acc[7] = {0.f, 0.f, 0.f, 0.f, 0.f, 0.f, 0.f};
  for (int c8 = 0; c8 < 20; c8++) {
    int sb = chunk * 160 + c8 * 8;
    __syncthreads();
    for (int p = t; p < 320; p += 256) {
      int sl = p / 40, e = p % 40;
      s_cl[sl][e] = cl[(long)(sb + sl) * 640 + b * 40 + e];
    }
    __syncthreads();
    for (int p = t; p < 640; p += 256) {
      int half = p / 320, q = p % 320, sl = q / 40, d = q % 40;
      const float* w = half ? s_wv : s_wk;
      float r = half ? blv[d] : blk[d];
      for (int e = 0; e < 40; e++) r += w[d * 40 + e] * s_cl[sl][e];
      if (half) s_v[sl][d] = r; else s_k[sl][d] = r;
    }
    __syncthreads();
    int ai = 0;
    for (int p = t; p < 1600; p += 256, ai++) {
      int d = p / 40, e = p % 40;
      float a = acc[ai];
      for (int sl = 0; sl < 8; sl++) a += s_k[sl][d] * s_v[sl][e];
      acc[ai] = a;
    }
  }
  int ai = 0;
  for (int p = t; p < 1600; p += 256, ai++)
    kvp[((long)(b * 25 + chunk)) * 1600 + p] = acc[ai];
}

__global__ void k_kv_reduce(const float* __restrict__ kvp, float* __restrict__ kv) {
  int i = blockIdx.x * blockDim.x + threadIdx.x;
  if (i >= 16 * 1600) return;
  int b = i / 1600, p = i % 1600;
  float s = 0.f;
  for (int c = 0; c < 25; c++) s += kvp[((long)(b * 25 + c)) * 1600 + p];
  kv[i] = s;
}

// ---------------------------------------------------------------------------
__global__ __launch_bounds__(256) void k_combine(
    const float* __restrict__ Ufin, const float* __restrict__ kvb,
    const float* __restrict__ vmat, const float* __restrict__ lsp32,
    const float* __restrict__ wgq, const float* __restrict__ wpq, const float* __restrict__ wcq,
    const float* __restrict__ bgq, const float* __restrict__ bpq, const float* __restrict__ bcq,
    const float* __restrict__ svv, const float* __restrict__ c1p,
    const float* __restrict__ bcls, const float* __restrict__ bnw,
    const float* __restrict__ bnb, float* __restrict__ out) {
  __shared__ float s_kv[1600], s_U[4800], s_w[4400], s_bq[120], s_sv[120], s_red[256];
  int b = blockIdx.x, t = threadIdx.x;
  for (int p = t; p < 1600; p += 256) {
    s_kv[p] = kvb[b * 1600 + p];
    s_w[p] = wgq[p];
    s_w[2800 + p] = wcq[p];
  }
  for (int p = t; p < 1200; p += 256) s_w[1600 + p] = wpq[p];
  for (int p = t; p < 4800; p += 256) {
    int tt = p / 1600, r = p % 1600, j = r / 40, e = r % 40;
    float uv = 0.f;
    if (tt == 0) uv = Ufin[(b * 40 + j) * 40 + e];
    else if (tt == 1) { if (j < 30) uv = Ufin[(640 + b * 30 + j) * 40 + e]; }
    else uv = Ufin[(1152 + b * 40 + j) * 40 + e];
    s_U[p] = uv;
  }
  if (t < 40) { s_bq[t] = bgq[t]; s_bq[40 + t] = bpq[t]; s_bq[80 + t] = bcq[t]; }
  for (int p = t; p < 120; p += 256) s_sv[p] = svv[p];
  __syncthreads();
  float y = 0.f;
  for (int p = t; p < 4800; p += 256) {
    int tt = p / 1600, q = p % 1600, d = q / 40, e = q % 40;
    float T = 0.f;
    if (tt == 0) {
      for (int j = 0; j < 40; j++) T += s_w[d * 40 + j] * s_U[j * 40 + e];
    } else if (tt == 1) {
      for (int j = 0; j < 30; j++) T += s_w[1600 + d * 30 + j] * s_U[1600 + j * 40 + e];
    } else {
      for (int j = 0; j < 40; j++) T += s_w[2800 + d * 40 + j] * s_U[3200 + j * 40 + e];
    }
    y += s_kv[d * 40 + e] * (T + s_bq[tt * 40 + d] * s_sv[tt * 40 + e]);
  }
  for (int s = t; s < 4000; s += 256) {
    const f32x4* lp = (const f32x4*)(lsp32 + ((long)b * SEQN + s) * 40);
    const f32x4* vp = (const f32x4*)(vmat + (long)s * 120);
#pragma unroll
    for (int d4 = 0; d4 < 10; d4++) {
      f32x4 l = lp[d4];
      f32x4 vs = vp[d4] + vp[10 + d4] + vp[20 + d4];
      y += l[0] * vs[0] + l[1] * vs[1] + l[2] * vs[2] + l[3] * vs[3];
    }
  }
  s_red[t] = y; __syncthreads();
  for (int o = 128; o > 0; o >>= 1) { if (t < o) s_red[t] += s_red[t + o]; __syncthreads(); }
  if (t == 0) {
    float c1 = bcls[0];
    for (int i = 0; i < 120; i++) c1 += c1p[i];
    float yy = s_red[0] * (1.f / 1024.f) + c1;
    yy = yy * (bnw[0] * rsqrtf(1.f + 1e-5f)) + bnb[0];
    out[b] = 1.f / (1.f + expf(-yy));
  }
}

// ---------------------------------------------------------------------------
extern "C" void kernel_launch(void* const* d_in, const int* in_sizes, int n_in,
                              void* d_out, int out_size, void* d_ws, size_t ws_size,
                              hipStream_t stream) {
  const int*   X        = (const int*)d_in[0];
  const float* emb      = (const float*)d_in[1];
  const float* w_dwc_l  = (const float*)d_in[2];
  const float* b_dwc_l  = (const float*)d_in[3];
  const float* w_dwc_o  = (const float*)d_in[4];
  const float* b_dwc_o  = (const float*)d_in[5];
  const float* w_local  = (const float*)d_in[6];
  const float* b_local  = (const float*)d_in[7];
  const float* w_global = (const float*)d_in[8];
  const float* b_global = (const float*)d_in[9];
  const float* w_gq = (const float*)d_in[10];
  const float* b_gq = (const float*)d_in[11];
  const float* w_cq = (const float*)d_in[12];
  const float* b_cq = (const float*)d_in[13];
  const float* w_pq = (const float*)d_in[14];
  const float* b_pq = (const float*)d_in[15];
  const float* w_lk = (const float*)d_in[16];
  const float* b_lk = (const float*)d_in[17];
  const float* w_lv = (const float*)d_in[18];
  const float* b_lv = (const float*)d_in[19];
  const float* w_cls = (const float*)d_in[20];
  const float* b_cls = (const float*)d_in[21];
  const float* bn_w = (const float*)d_in[22];
  const float* bn_b = (const float*)d_in[23];
  float* out = (float*)d_out;

  char* ws = (char*)d_ws;
  size_t off = 0;
  auto alloc = [&](size_t bytes) -> void* {
    off = (off + 255) & ~(size_t)255;
    void* p = ws + off; off += bytes; return p;
  };

  const size_t sz_p40 = (size_t)7 * 16 * 42 * 800 * 2;
  const size_t sz_p30 = (size_t)7 * 16 * 32 * 800 * 2;
  f16* P_lsp = (f16*)alloc(sz_p40 + 256);
  f16* P_pit = (f16*)alloc(sz_p30 + 256);
  f16* P_cod = (f16*)alloc(sz_p40 + 256);
  f16* P_gai = (f16*)alloc(sz_p40 + 256);
  float* lsp32 = (float*)alloc((size_t)16 * 4000 * 40 * 4);
  f16* wp_lsp = (f16*)alloc((size_t)896 * 7296 * 2);
  f16* wlp    = (f16*)alloc((size_t)4000 * 4096 * 2);
  f16* wcT    = (f16*)alloc((size_t)128 * 4000 * 2);
  f16* vT     = (f16*)alloc((size_t)128 * 4000 * 2);
  f16* co     = (f16*)alloc((size_t)640 * 4000 * 2 + 256);
  float* cl   = (float*)alloc((size_t)4000 * 640 * 4);
  float* vmat  = (float*)alloc((size_t)480000 * 4);
  float* Vt    = (float*)alloc((size_t)480000 * 4);
  f16* vtT   = (f16*)alloc((size_t)640 * 832 * 2 + 256);
  f16* Bp    = (f16*)alloc((size_t)7 * 120 * 2496 * 2);
  float* Upart = (float*)alloc((size_t)21 * 1792 * 40 * 4);
  float* Ufin  = (float*)alloc((size_t)1792 * 40 * 4);
  float* cbblv = (float*)alloc(120 * 4);
  float* svv   = (float*)alloc(120 * 4);
  float* kvp  = (float*)alloc((size_t)400 * 1600 * 4);
  float* kvb  = (float*)alloc((size_t)16 * 1600 * 4);
  float* c1p  = (float*)alloc(120 * 4);
  // arena: A9(18.43MB)@0 | woT(11.68MB)@18.5MB | vpart(19.2MB)@30.2MB ; later Cp@0(30.7MB), Clp@0(41MB)
  char* arena = (char*)alloc((size_t)52 * 1024 * 1024);
  float* A9   = (float*)arena;
  f16*   woT  = (f16*)(arena + 18500000);
  float* vpart = (float*)(arena + 30200000);
  float* Cp   = (float*)arena;
  float* Clp  = (float*)arena;
  (void)ws_size; (void)in_sizes; (void)n_in; (void)out_size;

  // zero conv-pad borders + vtT (K-tail zeros for A9 GEMM)
  hipMemsetAsync(P_lsp, 0, sz_p40, stream);
  hipMemsetAsync(P_pit, 0, sz_p30, stream);
  hipMemsetAsync(P_cod, 0, sz_p40, stream);
  hipMemsetAsync(P_gai, 0, sz_p40, stream);
  hipMemsetAsync(vtT, 0, (size_t)640 * 832 * 2, stream);

  // prep
  k_prepA<<<5300, 256, 0, stream>>>(w_dwc_l, wp_lsp, w_local, wlp, w_cls, wcT);
  k_pack_woT<<<625, 256, 0, stream>>>(w_dwc_o, woT);
  k_prepB<<<3870, 256, 0, stream>>>(X, emb, P_lsp, P_pit, P_cod, P_gai,
                                    lsp32, w_cls, b_global, c1p);

  // v = w_global^T @ (wc*1024): TN, splitK 10
  {
    dim3 g(32, 10);
    k_gemm_tn<<<g, 256, 0, stream>>>(wcT, 4000, w_global, 4000, vpart, 4000,
                                     13, 125, 480000, 120, 4000);
  }
  {
    dim3 g(32, 3);
    k_vredT2<0><<<g, 128, 0, stream>>>(vpart, vmat, vT);
  }

  // Vt = w_local^T @ v: TN, splitK 10
  {
    dim3 g(32, 10);
    k_gemm_tn<<<g, 256, 0, stream>>>(vT, 4000, w_local, 4000, vpart, 4000,
                                     13, 125, 480000, 120, 4000);
  }
  {
    dim3 g(32, 3);
    k_vredT2<1><<<g, 128, 0, stream>>>(vpart, Vt, vtT);
  }

  k_consts<<<120, 256, 0, stream>>>(Vt, vmat, b_dwc_o, b_local, cbblv, svv);

  // A9[z][fe][gi] = sum_g vtT[fe][g]*woT[z][gi][g]  (BK=64 swz, K=832)
  {
    dim3 g(70, 1, 9);
    k_gemm64<<<g, 256, 0, stream>>>(vtT, 832, woT, 800, A9, 800,
                                    7, 70, 13, 13, 0, 0, 640000, 512000, 600, 800, 600);
  }
  k_fold_bp<<<8190, 256, 0, stream>>>(A9, Bp);

  // lsp conv GEMM (BK=64 swz, splitK 3 over df) + reduce w/ bias
  {
    dim3 g(350, 3);
    k_gemm_conv<<<g, 256, 0, stream>>>(P_lsp, wp_lsp, Cp);
  }
  k_co_reduce<<<2500, 256, 0, stream>>>(Cp, b_dwc_l, co);

  // cl = w_local(permuted) @ co^T + b_local : BK=64 swz, splitK 4 -> Clp, reduce
  {
    dim3 g(315, 4);
    k_gemm64<<<g, 256, 0, stream>>>(wlp, 4096, co, 4000, Clp, 640,
                                    5, 315, 16, 64, 2560000L, 0, 0, 0, 4000, 640, 4000);
  }
  k_cl_reduce<<<2500, 256, 0, stream>>>(Clp, b_local, cl);

  // kv
  {
    dim3 g(25, 16);
    k_kv_partial<<<g, 256, 0, stream>>>(cl, w_lk, b_lk, w_lv, b_lv, kvp);
  }
  k_kv_reduce<<<100, 256, 0, stream>>>(kvp, kvb);

  // U path (BK=64 swz, splitK 3 over dw)
  {
    dim3 g(28, 21);
    k_gemm_u<<<g, 256, 0, stream>>>(P_gai, P_pit, P_cod, Bp, Upart);
  }
  k_ured<<<280, 256, 0, stream>>>(Upart, cbblv, Ufin);

  // final combine
  k_combine<<<16, 256, 0, stream>>>(Ufin, kvb, vmat, lsp32,
                                    w_gq, w_pq, w_cq, b_gq, b_pq, b_cq,
                                    svv, c1p, b_cls, bn_w, bn_b, out);
}

// Round 8
// 550.147 us; speedup vs baseline: 1.6030x; 1.0357x over previous
//
#include <hip/hip_runtime.h>
#include <hip/hip_bf16.h>

typedef _Float16 f16;
typedef __attribute__((ext_vector_type(8))) _Float16 half8;
typedef __attribute__((ext_vector_type(4))) _Float16 half4;
typedef __attribute__((ext_vector_type(4))) float f32x4;

static const int BN = 16, SEQN = 4000;

// ---------------------------------------------------------------------------
__device__ __forceinline__ void gload_lds(f16* lds, const f16* g) {
  __builtin_amdgcn_global_load_lds((const __attribute__((address_space(1))) unsigned int*)g,
                                   (__attribute__((address_space(3))) unsigned int*)lds, 16, 0, 0);
}

// bijective XCD swizzle (m204)
__device__ __forceinline__ int xcd_swz(int orig, int nwg) {
  int q = nwg >> 3, r = nwg & 7, x = orig & 7, o = orig >> 3;
  return (x < r ? x * (q + 1) : r * (q + 1) + (x - r) * q) + o;
}

// ---------------------------------------------------------------------------
// prepA: LDS-permute packs. [0,800) wconv->7296 | [800,4800) wlocal->4096 | [4800,5300) wcT
__global__ __launch_bounds__(256) void k_prepA(
    const float* __restrict__ w_dwc_l, f16* __restrict__ wp_lsp,
    const float* __restrict__ w_local, f16* __restrict__ wlp,
    const float* __restrict__ w_cls, f16* __restrict__ wcT) {
  __shared__ float sh[7200];
  int bid = blockIdx.x, t = threadIdx.x;
  if (bid < 800) {
    int o = bid;
    for (int p = t; p < 7200; p += 256) sh[p] = w_dwc_l[(long)o * 7200 + p];
    __syncthreads();
    for (int p = t; p < 7296; p += 256) {
      int seg = p / 2432, r = p - seg * 2432;
      f16 v = (f16)0.f;
      if (r < 2400) { int de = r / 800, gi = r % 800; v = (f16)sh[gi * 9 + seg * 3 + de]; }
      wp_lsp[(long)o * 7296 + p] = v;
    }
  } else if (bid < 4800) {
    int s = bid - 800;
    for (int p = t; p < 4000; p += 256) sh[p] = w_local[(long)s * 4000 + p];
    __syncthreads();
    for (int p = t; p < 4096; p += 256) {
      f16 v = (f16)0.f;
      if (p < 4000) { int f = p / 800, g = p % 800; v = (f16)sh[g * 5 + f]; }
      wlp[(long)s * 4096 + p] = v;
    }
  } else {
    int id = bid - 4800;
    int c0 = (id % 4) * 32, r0 = (id / 4) * 32;
    int tx = t & 31, ty = t >> 5;
    float (*tile)[33] = (float(*)[33])sh;
    for (int i = ty; i < 32; i += 8) {
      int r = r0 + i, c = c0 + tx;
      tile[i][tx] = (r < 4000 && c < 120) ? w_cls[(long)r * 120 + c] : 0.f;
    }
    __syncthreads();
    for (int i = ty; i < 32; i += 8) {
      int c = c0 + i, r = r0 + tx;
      if (c < 128 && r < 4000) wcT[(long)c * 4000 + r] = (f16)(tile[tx][i] * 1024.f);
    }
  }
}

// ---------------------------------------------------------------------------
// woT pack via LDS transpose: woT[z][gi][g] = w_dwc_o[g][gi*9+z]
__global__ __launch_bounds__(256) void k_pack_woT(const float* __restrict__ in,
                                                  f16* __restrict__ out) {
  __shared__ float sh[32][289];
  int bg = blockIdx.x % 25, bgi = blockIdx.x / 25;
  int g0 = bg * 32, gi0 = bgi * 32;
  int t = threadIdx.x;
  for (int p = t; p < 32 * 288; p += 256) {
    int gl = p / 288, q = p % 288;
    sh[gl][q] = in[(long)(g0 + gl) * 7200 + gi0 * 9 + q];
  }
  __syncthreads();
  for (int p = t; p < 9 * 32 * 32; p += 256) {
    int gl = p & 31, q = p >> 5;
    int gil = q & 31, z = q >> 5;
    out[(long)z * 640000 + (gi0 + gil) * 800 + g0 + gl] = (f16)sh[gl][gil * 9 + z];
  }
}

// ---------------------------------------------------------------------------
// gather, LDS-staged: block = (b, 32-g chunk). X rows staged coalesced; P writes
// in 64B g-runs; lsp32 buffered in LDS, dumped coalesced.
__global__ __launch_bounds__(256) void k_gather(
    const int* __restrict__ X, const float* __restrict__ emb,
    f16* __restrict__ P_lsp, f16* __restrict__ P_pit,
    f16* __restrict__ P_cod, f16* __restrict__ P_gai,
    float* __restrict__ lsp32) {
  __shared__ int sx_[2400];
  __shared__ float slsp[6400];
  const float scale[15] = {1.f,1.f,1.f,1.f,0.8f,0.512f,0.8f,0.64f,0.512f,0.64f,0.512f,0.8f,0.64f,0.512f,0.512f};
  const int br[15] = {0,0,0,0,1,1,2,2,3,3,1,2,2,3,3};
  const int po[15] = {0,1,2,3,0,1,0,1,0,2,2,2,3,1,3};
  int bid = blockIdx.x, t = threadIdx.x;
  int b = bid / 25, gc = bid % 25;
  int g0 = gc * 32, s0 = g0 * 5;
  const int* xbase = X + ((long)b * SEQN + s0) * 15;
  for (int p = t; p < 2400; p += 256) sx_[p] = xbase[p];
  __syncthreads();
  for (int it = t; it < 2400; it += 256) {
    int gl = it & 31, q = it >> 5, f = q % 5, c = q / 5;
    int idx = sx_[(gl * 5 + f) * 15 + c];
    const float* er = emb + (long)idx * 10;
    int ty = br[c], p = po[c];
    f16* P = (ty == 0) ? P_lsp : (ty == 1) ? P_pit : (ty == 2) ? P_cod : P_gai;
    int Wp = (ty == 1) ? 32 : 42;
    f16* base = P + ((long)((f + 1) * 16 + b) * Wp + (1 + p * 10)) * 800 + g0 + gl;
    float sc = scale[c];
#pragma unroll
    for (int j = 0; j < 10; j++) {
      float v = er[j] * sc;
      base[(long)j * 800] = (f16)v;
      if (ty == 0) slsp[(gl * 5 + f) * 40 + p * 10 + j] = v;
    }
  }
  __syncthreads();
  float* ldst = lsp32 + ((long)b * SEQN + s0) * 40;
  for (int p = t; p < 6400; p += 256) ldst[p] = slsp[p];
}

// c1 partial: sum wc[o,l]*b_global[o]
__global__ __launch_bounds__(256) void k_c1(const float* __restrict__ wcls,
                                            const float* __restrict__ bg, float* __restrict__ c1p) {
  __shared__ float red[256];
  int t = threadIdx.x;
  float s = 0.f;
  for (long i = (long)blockIdx.x * 256 + t; i < 480000; i += (long)120 * 256)
    s += wcls[i] * bg[i / 120];
  red[t] = s; __syncthreads();
  for (int o = 128; o > 0; o >>= 1) { if (t < o) red[t] += red[t + o]; __syncthreads(); }
  if (t == 0) c1p[blockIdx.x] = red[0];
}

// ---------------------------------------------------------------------------
// conv GEMM 128x128, BK=32, dbuf, XOR-swizzled. grid (175, 3). z=df, K=2432.
__global__ __launch_bounds__(256) void k_gemm_conv(
    const f16* __restrict__ P, const f16* __restrict__ wp, float* __restrict__ Cp) {
  __shared__ __align__(16) f16 As[2][4096];
  __shared__ __align__(16) f16 Bs[2][4096];
  int lin = xcd_swz(blockIdx.x, 175);
  int nx = lin % 7, my = lin / 7;
  int m0 = my * 128, n0 = nx * 128;
  int df = blockIdx.y;
  Cp += (long)df * 3200 * 800;
  int t = threadIdx.x;
  int gslot = (t & 3) ^ ((t >> 2) & 3);
  const f16 *ap[2], *bp[2];
#pragma unroll
  for (int q = 0; q < 2; q++) {
    int row = q * 64 + (t >> 2);
    int m = m0 + row;
    int f = m / 640, rem = m % 640, b = rem / 40, e = rem % 40;
    ap[q] = P + ((long)((f + df) * 16 + b) * 42 + e) * 800 + gslot * 8;
    bp[q] = wp + (long)(n0 + row) * 7296 + df * 2432 + gslot * 8;
  }
  int lane = t & 63, wv = t >> 6, l15 = lane & 15, kg = lane >> 4;
  int wm = (wv >> 1) * 64, wn = (wv & 1) * 64;
  int so = ((kg ^ (l15 & 3))) << 3;
  f32x4 acc[4][4] = {};
  gload_lds(&As[0][t * 8], ap[0]); gload_lds(&As[0][2048 + t * 8], ap[1]);
  gload_lds(&Bs[0][t * 8], bp[0]); gload_lds(&Bs[0][2048 + t * 8], bp[1]);
  __syncthreads();
  int cur = 0;
  for (int kt = 0; kt < 76; kt++) {
    if (kt + 1 < 76) {
      int o = (kt + 1) * 32, nb = cur ^ 1;
      gload_lds(&As[nb][t * 8], ap[0] + o); gload_lds(&As[nb][2048 + t * 8], ap[1] + o);
      gload_lds(&Bs[nb][t * 8], bp[0] + o); gload_lds(&Bs[nb][2048 + t * 8], bp[1] + o);
    }
    half8 av[4], bv[4];
#pragma unroll
    for (int i = 0; i < 4; i++) av[i] = *(const half8*)&As[cur][(wm + i * 16 + l15) * 32 + so];
#pragma unroll
    for (int j = 0; j < 4; j++) bv[j] = *(const half8*)&Bs[cur][(wn + j * 16 + l15) * 32 + so];
#pragma unroll
    for (int i = 0; i < 4; i++)
#pragma unroll
      for (int j = 0; j < 4; j++)
        acc[i][j] = __builtin_amdgcn_mfma_f32_16x16x32_f16(av[i], bv[j], acc[i][j], 0, 0, 0);
    __syncthreads();
    cur ^= 1;
  }
#pragma unroll
  for (int i = 0; i < 4; i++) {
    int mb = m0 + wm + i * 16 + kg * 4;
#pragma unroll
    for (int j = 0; j < 4; j++) {
      int n = n0 + wn + j * 16 + l15;
      if (n >= 800) continue;
      f32x4 d = acc[i][j];
#pragma unroll
      for (int r = 0; r < 4; r++)
        Cp[(long)(mb + r) * 800 + n] = d[r];
    }
  }
}

// co[(b*40+e)][f*800+n] = f16( sum_z Cp[z][m][n] + bias[n] )
__global__ void k_co_reduce(const float* __restrict__ Cp, const float* __restrict__ bias,
                            f16* __restrict__ co) {
  int id = blockIdx.x * blockDim.x + threadIdx.x;
  if (id >= 640000) return;
  int m = id / 200, n4 = (id % 200) * 4;
  long o = (long)m * 800 + n4;
  f32x4 s = *(const f32x4*)&bias[n4];
#pragma unroll
  for (int z = 0; z < 3; z++) s += *(const f32x4*)&Cp[(long)z * 2560000 + o];
  int f = m / 640, r2 = m % 640;
  half4 h = {(f16)s[0], (f16)s[1], (f16)s[2], (f16)s[3]};
  *(half4*)&co[(long)r2 * 4000 + f * 800 + n4] = h;
}

// ---------------------------------------------------------------------------
// generic NT GEMM 128x128, BK=32 swizzled, dbuf, splitK(y)+z-slices.
__global__ __launch_bounds__(256) void k_gemm128(
    const f16* __restrict__ A, int lda, const f16* __restrict__ Bm, int ldb,
    float* __restrict__ C, int ldc,
    int gx, int nwg, int nkt, int KTtot, long cslice, long az, long bz, long cz,
    int Mreal, int Nreal, int Aclamp) {
  __shared__ __align__(16) f16 As[2][4096];
  __shared__ __align__(16) f16 Bs[2][4096];
  A += (long)blockIdx.z * az;
  Bm += (long)blockIdx.z * bz;
  C += (long)blockIdx.z * cz + (long)blockIdx.y * cslice;
  int lin = xcd_swz(blockIdx.x, nwg);
  int nx = lin % gx, my = lin / gx;
  int m0 = my * 128, n0 = nx * 128;
  int kt0 = blockIdx.y * nkt;
  int ktn = nkt; if (kt0 + ktn > KTtot) ktn = KTtot - kt0;
  int t = threadIdx.x;
  int gslot = (t & 3) ^ ((t >> 2) & 3);
  const f16 *ap[2], *bp[2];
#pragma unroll
  for (int q = 0; q < 2; q++) {
    int row = q * 64 + (t >> 2);
    int ra = m0 + row; if (ra >= Aclamp) ra = Aclamp - 1;
    ap[q] = A + (long)ra * lda + (long)kt0 * 32 + gslot * 8;
    bp[q] = Bm + (long)(n0 + row) * ldb + (long)kt0 * 32 + gslot * 8;
  }
  int lane = t & 63, wv = t >> 6, l15 = lane & 15, kg = lane >> 4;
  int wm = (wv >> 1) * 64, wn = (wv & 1) * 64;
  int so = ((kg ^ (l15 & 3))) << 3;
  f32x4 acc[4][4] = {};
  gload_lds(&As[0][t * 8], ap[0]); gload_lds(&As[0][2048 + t * 8], ap[1]);
  gload_lds(&Bs[0][t * 8], bp[0]); gload_lds(&Bs[0][2048 + t * 8], bp[1]);
  __syncthreads();
  int cur = 0;
  for (int kt = 0; kt < ktn; kt++) {
    if (kt + 1 < ktn) {
      int o = (kt + 1) * 32, nb = cur ^ 1;
      gload_lds(&As[nb][t * 8], ap[0] + o); gload_lds(&As[nb][2048 + t * 8], ap[1] + o);
      gload_lds(&Bs[nb][t * 8], bp[0] + o); gload_lds(&Bs[nb][2048 + t * 8], bp[1] + o);
    }
    half8 av[4], bv[4];
#pragma unroll
    for (int i = 0; i < 4; i++) av[i] = *(const half8*)&As[cur][(wm + i * 16 + l15) * 32 + so];
#pragma unroll
    for (int j = 0; j < 4; j++) bv[j] = *(const half8*)&Bs[cur][(wn + j * 16 + l15) * 32 + so];
#pragma unroll
    for (int i = 0; i < 4; i++)
#pragma unroll
      for (int j = 0; j < 4; j++)
        acc[i][j] = __builtin_amdgcn_mfma_f32_16x16x32_f16(av[i], bv[j], acc[i][j], 0, 0, 0);
    __syncthreads();
    cur ^= 1;
  }
#pragma unroll
  for (int i = 0; i < 4; i++) {
    int mb = m0 + wm + i * 16 + kg * 4;
#pragma unroll
    for (int j = 0; j < 4; j++) {
      int n = n0 + wn + j * 16 + l15;
      if (n >= Nreal) continue;
      f32x4 d = acc[i][j];
#pragma unroll
      for (int r = 0; r < 4; r++) {
        int m = mb + r;
        if (m >= Mreal) continue;
        C[(long)m * ldc + n] = d[r];
      }
    }
  }
}

// ---------------------------------------------------------------------------
// TN GEMM: C[m][n] = sum_k A[m*lda+k](f16) * B[k*ldb+n](f32). Single M-tile.
__global__ __launch_bounds__(256) void k_gemm_tn(
    const f16* __restrict__ A, int lda, const float* __restrict__ B, int ldb,
    float* __restrict__ C, int ldc, int nkt, int KTtot, long cslice,
    int Mreal, int Nreal) {
  __shared__ __align__(16) f16 As[4096];
  __shared__ __align__(16) f16 Bs[128 * 36];
  int n0 = blockIdx.x * 128;
  int kt0 = blockIdx.y * nkt;
  int ktn = nkt; if (kt0 + ktn > KTtot) ktn = KTtot - kt0;
  C += (long)blockIdx.y * cslice;
  int t = threadIdx.x;
  const f16 *ap0, *ap1;
  {
    int r0 = t >> 2, r1 = 64 + (t >> 2);
    if (r0 >= Mreal) r0 = Mreal - 1;
    if (r1 >= Mreal) r1 = Mreal - 1;
    ap0 = A + (long)r0 * lda + (long)kt0 * 32 + (t & 3) * 8;
    ap1 = A + (long)r1 * lda + (long)kt0 * 32 + (t & 3) * 8;
  }
  int lane = t & 63, wv = t >> 6;
  int wm = (wv >> 1) * 64, wn = (wv & 1) * 64;
  int l15 = lane & 15, kg = lane >> 4;
  f32x4 acc[4][4] = {};
  for (int kt = 0; kt < ktn; kt++) {
    float rb[4][4];
    int nli[4], kqi[4];
#pragma unroll
    for (int i = 0; i < 4; i++) {
      int id = i * 256 + t;
      nli[i] = id & 127; kqi[i] = id >> 7;
      int gn = n0 + nli[i]; if (gn >= Nreal) gn = Nreal - 1;
      long kb = ((long)(kt0 + kt) * 32 + kqi[i] * 4);
#pragma unroll
      for (int j = 0; j < 4; j++) rb[i][j] = B[(kb + j) * ldb + gn];
    }
    __syncthreads();
    gload_lds(&As[t * 8], ap0 + kt * 32);
    gload_lds(&As[2048 + t * 8], ap1 + kt * 32);
#pragma unroll
    for (int i = 0; i < 4; i++) {
      half4 h = {(f16)rb[i][0], (f16)rb[i][1], (f16)rb[i][2], (f16)rb[i][3]};
      *(half4*)&Bs[nli[i] * 36 + kqi[i] * 4] = h;
    }
    __syncthreads();
    half8 av[4], bv[4];
#pragma unroll
    for (int i = 0; i < 4; i++) {
      av[i] = *(const half8*)(&As[(wm + i * 16 + l15) * 32 + kg * 8]);
      bv[i] = *(const half8*)(&Bs[(wn + i * 16 + l15) * 36 + kg * 8]);
    }
#pragma unroll
    for (int i = 0; i < 4; i++)
#pragma unroll
      for (int j = 0; j < 4; j++)
        acc[i][j] = __builtin_amdgcn_mfma_f32_16x16x32_f16(av[i], bv[j], acc[i][j], 0, 0, 0);
  }
#pragma unroll
  for (int i = 0; i < 4; i++) {
    int mb = wm + i * 16 + kg * 4;
#pragma unroll
    for (int j = 0; j < 4; j++) {
      int n = n0 + wn + j * 16 + l15;
      if (n >= Nreal) continue;
      f32x4 d = acc[i][j];
#pragma unroll
      for (int r = 0; r < 4; r++) {
        int m = mb + r;
        if (m >= Mreal) continue;
        C[(long)m * ldc + n] = d[r];
      }
    }
  }
}

// vredT2: sum 10 transposed slices, s-tiled. MODE 0 -> (vmat, vT), MODE 1 -> (Vt, vtT@832)
template <int MODE>
__global__ __launch_bounds__(128) void k_vredT2(const float* __restrict__ vp,
                                                float* __restrict__ vout,
                                                f16* __restrict__ tout) {
  int s = blockIdx.x * 128 + threadIdx.x;
  int ec = blockIdx.y;
  if (s >= 4000) return;
  int g = s / 5, f = s % 5;
  float sums[40];
#pragma unroll
  for (int eo = 0; eo < 40; eo++) {
    int e = ec * 40 + eo;
    float sum = 0.f;
#pragma unroll
    for (int z = 0; z < 10; z++) sum += vp[(long)z * 480000 + (long)e * 4000 + s];
    sums[eo] = sum;
    if (MODE == 0) tout[(long)e * 4000 + s] = (f16)sum;
    else tout[(long)(f * 120 + e) * 832 + g] = (f16)sum;
  }
#pragma unroll
  for (int q = 0; q < 10; q++)
    *(f32x4*)&vout[(long)s * 120 + ec * 40 + q * 4] = *(f32x4*)&sums[q * 4];
}

// cl[m][n] = sum_z Clp[z][m][n] + b_local[m]
__global__ void k_cl_reduce(const float* __restrict__ Clp, const float* __restrict__ bl,
                            float* __restrict__ cl) {
  int id = blockIdx.x * blockDim.x + threadIdx.x;
  if (id >= 640000) return;
  int m = id / 160, n4 = (id % 160) * 4;
  long o = (long)m * 640 + n4;
  f32x4 s = {0.f, 0.f, 0.f, 0.f};
#pragma unroll
  for (int z = 0; z < 4; z++) s += *(const f32x4*)&Clp[(long)z * 2560000 + o];
  float b = bl[m];
  s += (f32x4){b, b, b, b};
  *(f32x4*)&cl[o] = s;
}

// ---------------------------------------------------------------------------
// Bp[fp][eg][zk*832+kk] = f16( sum_dh A9[(dh*3+zk)][ (fp-dh)*120+eg ][kk] ), tail zero
__global__ void k_fold_bp(const float* __restrict__ A9, f16* __restrict__ Bp) {
  int id = blockIdx.x * blockDim.x + threadIdx.x;
  if (id >= 7 * 120 * 2496) return;
  int fp = id / 299520;
  int r = id % 299520;
  int eg = r / 2496, k2 = r % 2496;
  int zk = k2 / 832, kk = k2 % 832;
  if (kk >= 800) { Bp[id] = (f16)0.f; return; }
  float s = 0.f;
#pragma unroll
  for (int dh = 0; dh < 3; dh++) {
    int f = fp - dh;
    if (f >= 0 && f < 5)
      s += A9[((long)(dh * 3 + zk) * 640 + f * 120 + eg) * 800 + kk];
  }
  Bp[id] = (f16)s;
}

// ---------------------------------------------------------------------------
// U GEMM: BK=64 swizzled, block 64x48(40 real). grid (28, 21=(fp,zk)).
__global__ __launch_bounds__(256) void k_gemm_u(
    const f16* __restrict__ Pg, const f16* __restrict__ Pp, const f16* __restrict__ Pc,
    const f16* __restrict__ Bp, float* __restrict__ Upart) {
  __shared__ __align__(16) f16 As[2][4096];
  __shared__ __align__(16) f16 Bs[2][4096];
  int m0 = blockIdx.x * 64;
  int y = blockIdx.y, fp = y / 3, zk = y % 3;
  const f16* P; int seg0, jw, Wp, e0;
  if (m0 < 640)       { seg0 = 0;    jw = 40; Wp = 42; e0 = 0;  P = Pg; }
  else if (m0 < 1152) { seg0 = 640;  jw = 30; Wp = 32; e0 = 40; P = Pp; }
  else                { seg0 = 1152; jw = 40; Wp = 42; e0 = 80; P = Pc; }
  P += (long)fp * 16 * Wp * 800;
  int t = threadIdx.x;
  int gslot = (t & 7) ^ ((t >> 3) & 7);
  const f16 *ap[2], *bp[2];
#pragma unroll
  for (int q = 0; q < 2; q++) {
    int row = q * 32 + (t >> 3);
    int l = m0 + row - seg0; if (l >= 16 * jw) l = 0;
    ap[q] = P + ((long)(l / jw) * Wp + (l % jw)) * 800 + (long)zk * 800 + gslot * 8;
    int brow = row; if (e0 + brow > 119) brow = 119 - e0;
    bp[q] = Bp + ((long)fp * 120 + e0 + brow) * 2496 + zk * 832 + gslot * 8;
  }
  int lane = t & 63, wv = t >> 6, l15 = lane & 15, kg = lane >> 4;
  int sx = l15 & 7;
  f32x4 acc[3] = {};
  gload_lds(&As[0][t * 8], ap[0]); gload_lds(&As[0][2048 + t * 8], ap[1]);
  gload_lds(&Bs[0][t * 8], bp[0]); gload_lds(&Bs[0][2048 + t * 8], bp[1]);
  __syncthreads();
  int cur = 0;
  for (int kt = 0; kt < 13; kt++) {
    if (kt + 1 < 13) {
      int o = (kt + 1) * 64, nb = cur ^ 1;
      gload_lds(&As[nb][t * 8], ap[0] + o); gload_lds(&As[nb][2048 + t * 8], ap[1] + o);
      gload_lds(&Bs[nb][t * 8], bp[0] + o); gload_lds(&Bs[nb][2048 + t * 8], bp[1] + o);
    }
#pragma unroll
    for (int ks = 0; ks < 2; ks++) {
      int so = ((ks * 4 + kg) ^ sx) << 3;
      half8 av = *(const half8*)&As[cur][(wv * 16 + l15) * 64 + so];
#pragma unroll
      for (int j = 0; j < 3; j++) {
        half8 bv = *(const half8*)&Bs[cur][(j * 16 + l15) * 64 + so];
        acc[j] = __builtin_amdgcn_mfma_f32_16x16x32_f16(av, bv, acc[j], 0, 0, 0);
      }
    }
    __syncthreads();
    cur ^= 1;
  }
#pragma unroll
  for (int j = 0; j < 3; j++) {
    int n = j * 16 + l15;
    if (n >= 40) continue;
    f32x4 d = acc[j];
#pragma unroll
    for (int r = 0; r < 4; r++) {
      int m = m0 + wv * 16 + kg * 4 + r;
      if (m - seg0 >= 16 * jw) continue;
      Upart[((long)y * 1792 + m) * 40 + n] = d[r];
    }
  }
}

// Ufin[m][e] = sum_y Upart + cbblv[e0(m)+e]
__global__ void k_ured(const float* __restrict__ Upart, const float* __restrict__ cbblv,
                       float* __restrict__ Ufin) {
  int id = blockIdx.x * blockDim.x + threadIdx.x;
  if (id >= 1792 * 40) return;
  int m = id / 40, e = id % 40;
  int e0 = m < 640 ? 0 : (m < 1152 ? 40 : 80);
  float s = cbblv[e0 + e];
  for (int y = 0; y < 21; y++) s += Upart[(long)y * 71680 + id];
  Ufin[id] = s;
}

// cbblv[e] = sum_s bconv_o[s/5]*Vt[s,e] + b_local[s]*v[s,e]; svv[e]=sum_s v[s,e]
__global__ __launch_bounds__(256) void k_consts(
    const float* __restrict__ Vt, const float* __restrict__ vmat,
    const float* __restrict__ bconv, const float* __restrict__ blocal,
    float* __restrict__ cbblv, float* __restrict__ svv) {
  __shared__ float r1[256], r2[256];
  int e = blockIdx.x, t = threadIdx.x;
  float a = 0.f, b = 0.f;
  for (int s = t; s < 4000; s += 256) {
    a += bconv[s / 5] * Vt[(long)s * 120 + e] + blocal[s] * vmat[(long)s * 120 + e];
    b += vmat[(long)s * 120 + e];
  }
  r1[t] = a; r2[t] = b; __syncthreads();
  for (int o = 128; o > 0; o >>= 1) {
    if (t < o) { r1[t] += r1[t + o]; r2[t] += r2[t + o]; }
    __syncthreads();
  }
  if (t == 0) { cbblv[e] = r1[0]; svv[e] = r2[0]; }
}

// ---------------------------------------------------------------------------
__global__ __launch_bounds__(256) void k_kv_partial(
    const float* __restrict__ cl, const float* __restrict__ wlk, const float* __restrict__ blk,
    const float* __restrict__ wlv, const float* __restrict__ blv, float* __restrict__ kvp) {
  __shared__ float s_wk[1600], s_wv[1600];
  __shared__ float s_cl[8][40], s_k[8][40], s_v[8][40];
  int t = threadIdx.x, chunk = blockIdx.x, b = blockIdx.y;
  for (int p = t; p < 1600; p += 256) { s_wk[p] = wlk[p]; s_wv[p] = wlv[p]; }
  float acc[7] = {0.f, 0.f, 0.f, 0.f, 0.f, 0.f, 0.f};
  for (int c8 = 0; c8 < 20; c8++) {
    int sb = chunk * 160 + c8 * 8;
    __syncthreads();
    for (int p = t; p < 320; p += 256) {
      int sl = p / 40, e = p % 40;
      s_cl[sl][e] = cl[(long)(sb + sl) * 640 + b * 40 + e];
    }
    __syncthreads();
    for (int p = t; p < 640; p += 256) {
      int half = p / 320, q = p % 320, sl = q / 40, d = q % 40;
      const float* w = half ? s_wv : s_wk;
      float r = half ? blv[d] : blk[d];
      for (int e = 0; e < 40; e++) r += w[d * 40 + e] * s_cl[sl][e];
      if (half) s_v[sl][d] = r; else s_k[sl][d] = r;
    }
    __syncthreads();
    int ai = 0;
    for (int p = t; p < 1600; p += 256, ai++) {
      int d = p / 40, e = p % 40;
      float a = acc[ai];
      for (int sl = 0; sl < 8; sl++) a += s_k[sl][d] * s_v[sl][e];
      acc[ai] = a;
    }
  }
  int ai = 0;
  for (int p = t; p < 1600; p += 256, ai++)
    kvp[((long)(b * 25 + chunk)) * 1600 + p] = acc[ai];
}

__global__ void k_kv_reduce(const float* __restrict__ kvp, float* __restrict__ kv) {
  int i = blockIdx.x * blockDim.x + threadIdx.x;
  if (i >= 16 * 1600) return;
  int b = i / 1600, p = i % 1600;
  float s = 0.f;
  for (int c = 0; c < 25; c++) s += kvp[((long)(b * 25 + c)) * 1600 + p];
  kv[i] = s;
}

// ---------------------------------------------------------------------------
__global__ __launch_bounds__(256) void k_combine(
    const float* __restrict__ Ufin, const float* __restrict__ kvb,
    const float* __restrict__ vmat, const float* __restrict__ lsp32,
    const float* __restrict__ wgq, const float* __restrict__ wpq, const float* __restrict__ wcq,
    const float* __restrict__ bgq, const float* __restrict__ bpq, const float* __restrict__ bcq,
    const float* __restrict__ svv, const float* __restrict__ c1p,
    const float* __restrict__ bcls, const float* __restrict__ bnw,
    const float* __restrict__ bnb, float* __restrict__ out) {
  __shared__ float s_kv[1600], s_U[4800], s_w[4400], s_bq[120], s_sv[120], s_red[256];
  int b = blockIdx.x, t = threadIdx.x;
  for (int p = t; p < 1600; p += 256) {
    s_kv[p] = kvb[b * 1600 + p];
    s_w[p] = wgq[p];
    s_w[2800 + p] = wcq[p];
  }
  for (int p = t; p < 1200; p += 256) s_w[1600 + p] = wpq[p];
  for (int p = t; p < 4800; p += 256) {
    int tt = p / 1600, r = p % 1600, j = r / 40, e = r % 40;
    float uv = 0.f;
    if (tt == 0) uv = Ufin[(b * 40 + j) * 40 + e];
    else if (tt == 1) { if (j < 30) uv = Ufin[(640 + b * 30 + j) * 40 + e]; }
    else uv = Ufin[(1152 + b * 40 + j) * 40 + e];
    s_U[p] = uv;
  }
  if (t < 40) { s_bq[t] = bgq[t]; s_bq[40 + t] = bpq[t]; s_bq[80 + t] = bcq[t]; }
  for (int p = t; p < 120; p += 256) s_sv[p] = svv[p];
  __syncthreads();
  float y = 0.f;
  for (int p = t; p < 4800; p += 256) {
    int tt = p / 1600, q = p % 1600, d = q / 40, e = q % 40;
    float T = 0.f;
    if (tt == 0) {
      for (int j = 0; j < 40; j++) T += s_w[d * 40 + j] * s_U[j * 40 + e];
    } else if (tt == 1) {
      for (int j = 0; j < 30; j++) T += s_w[1600 + d * 30 + j] * s_U[1600 + j * 40 + e];
    } else {
      for (int j = 0; j < 40; j++) T += s_w[2800 + d * 40 + j] * s_U[3200 + j * 40 + e];
    }
    y += s_kv[d * 40 + e] * (T + s_bq[tt * 40 + d] * s_sv[tt * 40 + e]);
  }
  for (int s = t; s < 4000; s += 256) {
    const f32x4* lp = (const f32x4*)(lsp32 + ((long)b * SEQN + s) * 40);
    const f32x4* vp = (const f32x4*)(vmat + (long)s * 120);
#pragma unroll
    for (int d4 = 0; d4 < 10; d4++) {
      f32x4 l = lp[d4];
      f32x4 vs = vp[d4] + vp[10 + d4] + vp[20 + d4];
      y += l[0] * vs[0] + l[1] * vs[1] + l[2] * vs[2] + l[3] * vs[3];
    }
  }
  s_red[t] = y; __syncthreads();
  for (int o = 128; o > 0; o >>= 1) { if (t < o) s_red[t] += s_red[t + o]; __syncthreads(); }
  if (t == 0) {
    float c1 = bcls[0];
    for (int i = 0; i < 120; i++) c1 += c1p[i];
    float yy = s_red[0] * (1.f / 1024.f) + c1;
    yy = yy * (bnw[0] * rsqrtf(1.f + 1e-5f)) + bnb[0];
    out[b] = 1.f / (1.f + expf(-yy));
  }
}

// ---------------------------------------------------------------------------
extern "C" void kernel_launch(void* const* d_in, const int* in_sizes, int n_in,
                              void* d_out, int out_size, void* d_ws, size_t ws_size,
                              hipStream_t stream) {
  const int*   X        = (const int*)d_in[0];
  const float* emb      = (const float*)d_in[1];
  const float* w_dwc_l  = (const float*)d_in[2];
  const float* b_dwc_l  = (const float*)d_in[3];
  const float* w_dwc_o  = (const float*)d_in[4];
  const float* b_dwc_o  = (const float*)d_in[5];
  const float* w_local  = (const float*)d_in[6];
  const float* b_local  = (const float*)d_in[7];
  const float* w_global = (const float*)d_in[8];
  const float* b_global = (const float*)d_in[9];
  const float* w_gq = (const float*)d_in[10];
  const float* b_gq = (const float*)d_in[11];
  const float* w_cq = (const float*)d_in[12];
  const float* b_cq = (const float*)d_in[13];
  const float* w_pq = (const float*)d_in[14];
  const float* b_pq = (const float*)d_in[15];
  const float* w_lk = (const float*)d_in[16];
  const float* b_lk = (const float*)d_in[17];
  const float* w_lv = (const float*)d_in[18];
  const float* b_lv = (const float*)d_in[19];
  const float* w_cls = (const float*)d_in[20];
  const float* b_cls = (const float*)d_in[21];
  const float* bn_w = (const float*)d_in[22];
  const float* bn_b = (const float*)d_in[23];
  float* out = (float*)d_out;

  char* ws = (char*)d_ws;
  size_t off = 0;
  auto alloc = [&](size_t bytes) -> void* {
    off = (off + 255) & ~(size_t)255;
    void* p = ws + off; off += bytes; return p;
  };

  const size_t sz_p40 = (size_t)7 * 16 * 42 * 800 * 2;
  const size_t sz_p30 = (size_t)7 * 16 * 32 * 800 * 2;
  f16* P_lsp = (f16*)alloc(sz_p40 + 256);
  f16* P_pit = (f16*)alloc(sz_p30 + 256);
  f16* P_cod = (f16*)alloc(sz_p40 + 256);
  f16* P_gai = (f16*)alloc(sz_p40 + 256);
  float* lsp32 = (float*)alloc((size_t)16 * 4000 * 40 * 4);
  f16* wp_lsp = (f16*)alloc((size_t)896 * 7296 * 2);
  f16* wlp    = (f16*)alloc((size_t)4000 * 4096 * 2 + 256);
  f16* wcT    = (f16*)alloc((size_t)128 * 4000 * 2);
  f16* vT     = (f16*)alloc((size_t)128 * 4000 * 2);
  f16* co     = (f16*)alloc((size_t)640 * 4000 * 2 + 256);
  float* cl   = (float*)alloc((size_t)4000 * 640 * 4);
  float* vmat  = (float*)alloc((size_t)480000 * 4);
  float* Vt    = (float*)alloc((size_t)480000 * 4);
  f16* vtT   = (f16*)alloc((size_t)640 * 832 * 2 + 256);
  f16* Bp    = (f16*)alloc((size_t)7 * 120 * 2496 * 2);
  float* Upart = (float*)alloc((size_t)21 * 1792 * 40 * 4);
  float* Ufin  = (float*)alloc((size_t)1792 * 40 * 4);
  float* cbblv = (float*)alloc(120 * 4);
  float* svv   = (float*)alloc(120 * 4);
  float* kvp  = (float*)alloc((size_t)400 * 1600 * 4);
  float* kvb  = (float*)alloc((size_t)16 * 1600 * 4);
  float* c1p  = (float*)alloc(120 * 4);
  // arena: A9(18.43MB)@0 | woT(11.68MB)@18.5MB | vpart(19.2MB)@30.2MB ; later Cp@0(30.7MB), Clp@0(41MB)
  char* arena = (char*)alloc((size_t)52 * 1024 * 1024);
  float* A9   = (float*)arena;
  f16*   woT  = (f16*)(arena + 18500000);
  float* vpart = (float*)(arena + 30200000);
  float* Cp   = (float*)arena;
  float* Clp  = (float*)arena;
  (void)ws_size; (void)in_sizes; (void)n_in; (void)out_size;

  // zero conv-pad borders + vtT (K-tail zeros for A9 GEMM)
  hipMemsetAsync(P_lsp, 0, sz_p40, stream);
  hipMemsetAsync(P_pit, 0, sz_p30, stream);
  hipMemsetAsync(P_cod, 0, sz_p40, stream);
  hipMemsetAsync(P_gai, 0, sz_p40, stream);
  hipMemsetAsync(vtT, 0, (size_t)640 * 832 * 2, stream);

  // prep
  k_prepA<<<5300, 256, 0, stream>>>(w_dwc_l, wp_lsp, w_local, wlp, w_cls, wcT);
  k_pack_woT<<<625, 256, 0, stream>>>(w_dwc_o, woT);
  k_gather<<<400, 256, 0, stream>>>(X, emb, P_lsp, P_pit, P_cod, P_gai, lsp32);
  k_c1<<<120, 256, 0, stream>>>(w_cls, b_global, c1p);

  // v = w_global^T @ (wc*1024): TN, splitK 10
  {
    dim3 g(32, 10);
    k_gemm_tn<<<g, 256, 0, stream>>>(wcT, 4000, w_global, 4000, vpart, 4000,
                                     13, 125, 480000, 120, 4000);
  }
  {
    dim3 g(32, 3);
    k_vredT2<0><<<g, 128, 0, stream>>>(vpart, vmat, vT);
  }

  // Vt = w_local^T @ v: TN, splitK 10
  {
    dim3 g(32, 10);
    k_gemm_tn<<<g, 256, 0, stream>>>(vT, 4000, w_local, 4000, vpart, 4000,
                                     13, 125, 480000, 120, 4000);
  }
  {
    dim3 g(32, 3);
    k_vredT2<1><<<g, 128, 0, stream>>>(vpart, Vt, vtT);
  }

  k_consts<<<120, 256, 0, stream>>>(Vt, vmat, b_dwc_o, b_local, cbblv, svv);

  // A9[z][fe][gi] = sum_g vtT[fe][g]*woT[z][gi][g]  (128^2 BK=32 swz, K=832)
  {
    dim3 g(35, 1, 9);
    k_gemm128<<<g, 256, 0, stream>>>(vtT, 832, woT, 800, A9, 800,
                                     7, 35, 26, 26, 0, 0, 640000, 512000, 600, 800, 600);
  }
  k_fold_bp<<<8190, 256, 0, stream>>>(A9, Bp);

  // lsp conv GEMM (128^2 BK=32 swz, splitK 3 over df) + reduce w/ bias
  {
    dim3 g(175, 3);
    k_gemm_conv<<<g, 256, 0, stream>>>(P_lsp, wp_lsp, Cp);
  }
  k_co_reduce<<<2500, 256, 0, stream>>>(Cp, b_dwc_l, co);

  // cl = w_local(permuted) @ co^T + b_local : 128^2 BK=32 swz, splitK 4 -> Clp, reduce
  {
    dim3 g(160, 4);
    k_gemm128<<<g, 256, 0, stream>>>(wlp, 4096, co, 4000, Clp, 640,
                                     5, 160, 32, 128, 2560000L, 0, 0, 0, 4000, 640, 4000);
  }
  k_cl_reduce<<<2500, 256, 0, stream>>>(Clp, b_local, cl);

  // kv
  {
    dim3 g(25, 16);
    k_kv_partial<<<g, 256, 0, stream>>>(cl, w_lk, b_lk, w_lv, b_lv, kvp);
  }
  k_kv_reduce<<<100, 256, 0, stream>>>(kvp, kvb);

  // U path (BK=64 swz, splitK 3 over dw)
  {
    dim3 g(28, 21);
    k_gemm_u<<<g, 256, 0, stream>>>(P_gai, P_pit, P_cod, Bp, Upart);
  }
  k_ured<<<280, 256, 0, stream>>>(Upart, cbblv, Ufin);

  // final combine
  k_combine<<<16, 256, 0, stream>>>(Ufin, kvb, vmat, lsp32,
                                    w_gq, w_pq, w_cq, b_gq, b_pq, b_cq,
                                    svv, c1p, b_cls, bn_w, bn_b, out);
}

// Round 9
// 496.379 us; speedup vs baseline: 1.7766x; 1.1083x over previous
//
#include <hip/hip_runtime.h>
#include <hip/hip_bf16.h>

typedef _Float16 f16;
typedef __attribute__((ext_vector_type(8))) _Float16 half8;
typedef __attribute__((ext_vector_type(4))) _Float16 half4;
typedef __attribute__((ext_vector_type(4))) float f32x4;

static const int BN = 16, SEQN = 4000;

// ---------------------------------------------------------------------------
__device__ __forceinline__ void gload_lds(f16* lds, const f16* g) {
  __builtin_amdgcn_global_load_lds((const __attribute__((address_space(1))) unsigned int*)g,
                                   (__attribute__((address_space(3))) unsigned int*)lds, 16, 0, 0);
}

// bijective XCD swizzle (m204)
__device__ __forceinline__ int xcd_swz(int orig, int nwg) {
  int q = nwg >> 3, r = nwg & 7, x = orig & 7, o = orig >> 3;
  return (x < r ? x * (q + 1) : r * (q + 1) + (x - r) * q) + o;
}

// ---------------------------------------------------------------------------
// prepA: LDS-permute packs. [0,800) wconv->7296 | [800,4800) wlocal->4096 | [4800,5300) wcT
__global__ __launch_bounds__(256) void k_prepA(
    const float* __restrict__ w_dwc_l, f16* __restrict__ wp_lsp,
    const float* __restrict__ w_local, f16* __restrict__ wlp,
    const float* __restrict__ w_cls, f16* __restrict__ wcT) {
  __shared__ float sh[7200];
  int bid = blockIdx.x, t = threadIdx.x;
  if (bid < 800) {
    int o = bid;
    for (int p = t; p < 7200; p += 256) sh[p] = w_dwc_l[(long)o * 7200 + p];
    __syncthreads();
    for (int p = t; p < 7296; p += 256) {
      int seg = p / 2432, r = p - seg * 2432;
      f16 v = (f16)0.f;
      if (r < 2400) { int de = r / 800, gi = r % 800; v = (f16)sh[gi * 9 + seg * 3 + de]; }
      wp_lsp[(long)o * 7296 + p] = v;
    }
  } else if (bid < 4800) {
    int s = bid - 800;
    for (int p = t; p < 4000; p += 256) sh[p] = w_local[(long)s * 4000 + p];
    __syncthreads();
    for (int p = t; p < 4096; p += 256) {
      f16 v = (f16)0.f;
      if (p < 4000) { int f = p / 800, g = p % 800; v = (f16)sh[g * 5 + f]; }
      wlp[(long)s * 4096 + p] = v;
    }
  } else {
    int id = bid - 4800;
    int c0 = (id % 4) * 32, r0 = (id / 4) * 32;
    int tx = t & 31, ty = t >> 5;
    float (*tile)[33] = (float(*)[33])sh;
    for (int i = ty; i < 32; i += 8) {
      int r = r0 + i, c = c0 + tx;
      tile[i][tx] = (r < 4000 && c < 120) ? w_cls[(long)r * 120 + c] : 0.f;
    }
    __syncthreads();
    for (int i = ty; i < 32; i += 8) {
      int c = c0 + i, r = r0 + tx;
      if (c < 128 && r < 4000) wcT[(long)c * 4000 + r] = (f16)(tile[tx][i] * 1024.f);
    }
  }
}

// ---------------------------------------------------------------------------
// woT pack via LDS transpose: woT[z][gi][g] = w_dwc_o[g][gi*9+z]
__global__ __launch_bounds__(256) void k_pack_woT(const float* __restrict__ in,
                                                  f16* __restrict__ out) {
  __shared__ float sh[32][289];
  int bg = blockIdx.x % 25, bgi = blockIdx.x / 25;
  int g0 = bg * 32, gi0 = bgi * 32;
  int t = threadIdx.x;
  for (int p = t; p < 32 * 288; p += 256) {
    int gl = p / 288, q = p % 288;
    sh[gl][q] = in[(long)(g0 + gl) * 7200 + gi0 * 9 + q];
  }
  __syncthreads();
  for (int p = t; p < 9 * 32 * 32; p += 256) {
    int gl = p & 31, q = p >> 5;
    int gil = q & 31, z = q >> 5;
    out[(long)z * 640000 + (gi0 + gil) * 800 + g0 + gl] = (f16)sh[gl][gil * 9 + z];
  }
}

// ---------------------------------------------------------------------------
// gather, LDS-staged: block = (b, 32-g chunk).
__global__ __launch_bounds__(256) void k_gather(
    const int* __restrict__ X, const float* __restrict__ emb,
    f16* __restrict__ P_lsp, f16* __restrict__ P_pit,
    f16* __restrict__ P_cod, f16* __restrict__ P_gai,
    float* __restrict__ lsp32) {
  __shared__ int sx_[2400];
  __shared__ float slsp[6400];
  const float scale[15] = {1.f,1.f,1.f,1.f,0.8f,0.512f,0.8f,0.64f,0.512f,0.64f,0.512f,0.8f,0.64f,0.512f,0.512f};
  const int br[15] = {0,0,0,0,1,1,2,2,3,3,1,2,2,3,3};
  const int po[15] = {0,1,2,3,0,1,0,1,0,2,2,2,3,1,3};
  int bid = blockIdx.x, t = threadIdx.x;
  int b = bid / 25, gc = bid % 25;
  int g0 = gc * 32, s0 = g0 * 5;
  const int* xbase = X + ((long)b * SEQN + s0) * 15;
  for (int p = t; p < 2400; p += 256) sx_[p] = xbase[p];
  __syncthreads();
  for (int it = t; it < 2400; it += 256) {
    int gl = it & 31, q = it >> 5, f = q % 5, c = q / 5;
    int idx = sx_[(gl * 5 + f) * 15 + c];
    const float* er = emb + (long)idx * 10;
    int ty = br[c], p = po[c];
    f16* P = (ty == 0) ? P_lsp : (ty == 1) ? P_pit : (ty == 2) ? P_cod : P_gai;
    int Wp = (ty == 1) ? 32 : 42;
    f16* base = P + ((long)((f + 1) * 16 + b) * Wp + (1 + p * 10)) * 800 + g0 + gl;
    float sc = scale[c];
#pragma unroll
    for (int j = 0; j < 10; j++) {
      float v = er[j] * sc;
      base[(long)j * 800] = (f16)v;
      if (ty == 0) slsp[(gl * 5 + f) * 40 + p * 10 + j] = v;
    }
  }
  __syncthreads();
  float* ldst = lsp32 + ((long)b * SEQN + s0) * 40;
  for (int p = t; p < 6400; p += 256) ldst[p] = slsp[p];
}

// c1 partial: sum wc[o,l]*b_global[o]
__global__ __launch_bounds__(256) void k_c1(const float* __restrict__ wcls,
                                            const float* __restrict__ bg, float* __restrict__ c1p) {
  __shared__ float red[256];
  int t = threadIdx.x;
  float s = 0.f;
  for (long i = (long)blockIdx.x * 256 + t; i < 480000; i += (long)120 * 256)
    s += wcls[i] * bg[i / 120];
  red[t] = s; __syncthreads();
  for (int o = 128; o > 0; o >>= 1) { if (t < o) red[t] += red[t + o]; __syncthreads(); }
  if (t == 0) c1p[blockIdx.x] = red[0];
}

// ---------------------------------------------------------------------------
// conv GEMM 128x128, BK=32, dbuf, XOR-swizzled. grid (175, 3). z=df, K=2432.
__global__ __launch_bounds__(256) void k_gemm_conv(
    const f16* __restrict__ P, const f16* __restrict__ wp, float* __restrict__ Cp) {
  __shared__ __align__(16) f16 As[2][4096];
  __shared__ __align__(16) f16 Bs[2][4096];
  int lin = xcd_swz(blockIdx.x, 175);
  int nx = lin % 7, my = lin / 7;
  int m0 = my * 128, n0 = nx * 128;
  int df = blockIdx.y;
  Cp += (long)df * 3200 * 800;
  int t = threadIdx.x;
  int gslot = (t & 3) ^ ((t >> 2) & 3);
  const f16 *ap[2], *bp[2];
#pragma unroll
  for (int q = 0; q < 2; q++) {
    int row = q * 64 + (t >> 2);
    int m = m0 + row;
    int f = m / 640, rem = m % 640, b = rem / 40, e = rem % 40;
    ap[q] = P + ((long)((f + df) * 16 + b) * 42 + e) * 800 + gslot * 8;
    bp[q] = wp + (long)(n0 + row) * 7296 + df * 2432 + gslot * 8;
  }
  int lane = t & 63, wv = t >> 6, l15 = lane & 15, kg = lane >> 4;
  int wm = (wv >> 1) * 64, wn = (wv & 1) * 64;
  int so = ((kg ^ (l15 & 3))) << 3;
  f32x4 acc[4][4] = {};
  gload_lds(&As[0][t * 8], ap[0]); gload_lds(&As[0][2048 + t * 8], ap[1]);
  gload_lds(&Bs[0][t * 8], bp[0]); gload_lds(&Bs[0][2048 + t * 8], bp[1]);
  __syncthreads();
  int cur = 0;
  for (int kt = 0; kt < 76; kt++) {
    if (kt + 1 < 76) {
      int o = (kt + 1) * 32, nb = cur ^ 1;
      gload_lds(&As[nb][t * 8], ap[0] + o); gload_lds(&As[nb][2048 + t * 8], ap[1] + o);
      gload_lds(&Bs[nb][t * 8], bp[0] + o); gload_lds(&Bs[nb][2048 + t * 8], bp[1] + o);
    }
    half8 av[4], bv[4];
#pragma unroll
    for (int i = 0; i < 4; i++) av[i] = *(const half8*)&As[cur][(wm + i * 16 + l15) * 32 + so];
#pragma unroll
    for (int j = 0; j < 4; j++) bv[j] = *(const half8*)&Bs[cur][(wn + j * 16 + l15) * 32 + so];
#pragma unroll
    for (int i = 0; i < 4; i++)
#pragma unroll
      for (int j = 0; j < 4; j++)
        acc[i][j] = __builtin_amdgcn_mfma_f32_16x16x32_f16(av[i], bv[j], acc[i][j], 0, 0, 0);
    __syncthreads();
    cur ^= 1;
  }
#pragma unroll
  for (int i = 0; i < 4; i++) {
    int mb = m0 + wm + i * 16 + kg * 4;
#pragma unroll
    for (int j = 0; j < 4; j++) {
      int n = n0 + wn + j * 16 + l15;
      if (n >= 800) continue;
      f32x4 d = acc[i][j];
#pragma unroll
      for (int r = 0; r < 4; r++)
        Cp[(long)(mb + r) * 800 + n] = d[r];
    }
  }
}

// co[(b*40+e)][f*800+n] = f16( sum_z Cp[z][m][n] + bias[n] )
__global__ void k_co_reduce(const float* __restrict__ Cp, const float* __restrict__ bias,
                            f16* __restrict__ co) {
  int id = blockIdx.x * blockDim.x + threadIdx.x;
  if (id >= 640000) return;
  int m = id / 200, n4 = (id % 200) * 4;
  long o = (long)m * 800 + n4;
  f32x4 s = *(const f32x4*)&bias[n4];
#pragma unroll
  for (int z = 0; z < 3; z++) s += *(const f32x4*)&Cp[(long)z * 2560000 + o];
  int f = m / 640, r2 = m % 640;
  half4 h = {(f16)s[0], (f16)s[1], (f16)s[2], (f16)s[3]};
  *(half4*)&co[(long)r2 * 4000 + f * 800 + n4] = h;
}

// ---------------------------------------------------------------------------
// generic NT GEMM 128x128, BK=32 swizzled, dbuf, splitK(y)+z-slices.
__global__ __launch_bounds__(256) void k_gemm128(
    const f16* __restrict__ A, int lda, const f16* __restrict__ Bm, int ldb,
    float* __restrict__ C, int ldc,
    int gx, int nwg, int nkt, int KTtot, long cslice, long az, long bz, long cz,
    int Mreal, int Nreal, int Aclamp) {
  __shared__ __align__(16) f16 As[2][4096];
  __shared__ __align__(16) f16 Bs[2][4096];
  A += (long)blockIdx.z * az;
  Bm += (long)blockIdx.z * bz;
  C += (long)blockIdx.z * cz + (long)blockIdx.y * cslice;
  int lin = xcd_swz(blockIdx.x, nwg);
  int nx = lin % gx, my = lin / gx;
  int m0 = my * 128, n0 = nx * 128;
  int kt0 = blockIdx.y * nkt;
  int ktn = nkt; if (kt0 + ktn > KTtot) ktn = KTtot - kt0;
  int t = threadIdx.x;
  int gslot = (t & 3) ^ ((t >> 2) & 3);
  const f16 *ap[2], *bp[2];
#pragma unroll
  for (int q = 0; q < 2; q++) {
    int row = q * 64 + (t >> 2);
    int ra = m0 + row; if (ra >= Aclamp) ra = Aclamp - 1;
    ap[q] = A + (long)ra * lda + (long)kt0 * 32 + gslot * 8;
    bp[q] = Bm + (long)(n0 + row) * ldb + (long)kt0 * 32 + gslot * 8;
  }
  int lane = t & 63, wv = t >> 6, l15 = lane & 15, kg = lane >> 4;
  int wm = (wv >> 1) * 64, wn = (wv & 1) * 64;
  int so = ((kg ^ (l15 & 3))) << 3;
  f32x4 acc[4][4] = {};
  gload_lds(&As[0][t * 8], ap[0]); gload_lds(&As[0][2048 + t * 8], ap[1]);
  gload_lds(&Bs[0][t * 8], bp[0]); gload_lds(&Bs[0][2048 + t * 8], bp[1]);
  __syncthreads();
  int cur = 0;
  for (int kt = 0; kt < ktn; kt++) {
    if (kt + 1 < ktn) {
      int o = (kt + 1) * 32, nb = cur ^ 1;
      gload_lds(&As[nb][t * 8], ap[0] + o); gload_lds(&As[nb][2048 + t * 8], ap[1] + o);
      gload_lds(&Bs[nb][t * 8], bp[0] + o); gload_lds(&Bs[nb][2048 + t * 8], bp[1] + o);
    }
    half8 av[4], bv[4];
#pragma unroll
    for (int i = 0; i < 4; i++) av[i] = *(const half8*)&As[cur][(wm + i * 16 + l15) * 32 + so];
#pragma unroll
    for (int j = 0; j < 4; j++) bv[j] = *(const half8*)&Bs[cur][(wn + j * 16 + l15) * 32 + so];
#pragma unroll
    for (int i = 0; i < 4; i++)
#pragma unroll
      for (int j = 0; j < 4; j++)
        acc[i][j] = __builtin_amdgcn_mfma_f32_16x16x32_f16(av[i], bv[j], acc[i][j], 0, 0, 0);
    __syncthreads();
    cur ^= 1;
  }
#pragma unroll
  for (int i = 0; i < 4; i++) {
    int mb = m0 + wm + i * 16 + kg * 4;
#pragma unroll
    for (int j = 0; j < 4; j++) {
      int n = n0 + wn + j * 16 + l15;
      if (n >= Nreal) continue;
      f32x4 d = acc[i][j];
#pragma unroll
      for (int r = 0; r < 4; r++) {
        int m = mb + r;
        if (m >= Mreal) continue;
        C[(long)m * ldc + n] = d[r];
      }
    }
  }
}

// ---------------------------------------------------------------------------
// TN GEMM: C[m][n] = sum_k A[m*lda+k](f16) * B[k*ldb+n](f32). Single M-tile.
__global__ __launch_bounds__(256) void k_gemm_tn(
    const f16* __restrict__ A, int lda, const float* __restrict__ B, int ldb,
    float* __restrict__ C, int ldc, int nkt, int KTtot, long cslice,
    int Mreal, int Nreal) {
  __shared__ __align__(16) f16 As[4096];
  __shared__ __align__(16) f16 Bs[128 * 36];
  int n0 = blockIdx.x * 128;
  int kt0 = blockIdx.y * nkt;
  int ktn = nkt; if (kt0 + ktn > KTtot) ktn = KTtot - kt0;
  C += (long)blockIdx.y * cslice;
  int t = threadIdx.x;
  const f16 *ap0, *ap1;
  {
    int r0 = t >> 2, r1 = 64 + (t >> 2);
    if (r0 >= Mreal) r0 = Mreal - 1;
    if (r1 >= Mreal) r1 = Mreal - 1;
    ap0 = A + (long)r0 * lda + (long)kt0 * 32 + (t & 3) * 8;
    ap1 = A + (long)r1 * lda + (long)kt0 * 32 + (t & 3) * 8;
  }
  int lane = t & 63, wv = t >> 6;
  int wm = (wv >> 1) * 64, wn = (wv & 1) * 64;
  int l15 = lane & 15, kg = lane >> 4;
  f32x4 acc[4][4] = {};
  for (int kt = 0; kt < ktn; kt++) {
    float rb[4][4];
    int nli[4], kqi[4];
#pragma unroll
    for (int i = 0; i < 4; i++) {
      int id = i * 256 + t;
      nli[i] = id & 127; kqi[i] = id >> 7;
      int gn = n0 + nli[i]; if (gn >= Nreal) gn = Nreal - 1;
      long kb = ((long)(kt0 + kt) * 32 + kqi[i] * 4);
#pragma unroll
      for (int j = 0; j < 4; j++) rb[i][j] = B[(kb + j) * ldb + gn];
    }
    __syncthreads();
    gload_lds(&As[t * 8], ap0 + kt * 32);
    gload_lds(&As[2048 + t * 8], ap1 + kt * 32);
#pragma unroll
    for (int i = 0; i < 4; i++) {
      half4 h = {(f16)rb[i][0], (f16)rb[i][1], (f16)rb[i][2], (f16)rb[i][3]};
      *(half4*)&Bs[nli[i] * 36 + kqi[i] * 4] = h;
    }
    __syncthreads();
    half8 av[4], bv[4];
#pragma unroll
    for (int i = 0; i < 4; i++) {
      av[i] = *(const half8*)(&As[(wm + i * 16 + l15) * 32 + kg * 8]);
      bv[i] = *(const half8*)(&Bs[(wn + i * 16 + l15) * 36 + kg * 8]);
    }
#pragma unroll
    for (int i = 0; i < 4; i++)
#pragma unroll
      for (int j = 0; j < 4; j++)
        acc[i][j] = __builtin_amdgcn_mfma_f32_16x16x32_f16(av[i], bv[j], acc[i][j], 0, 0, 0);
  }
#pragma unroll
  for (int i = 0; i < 4; i++) {
    int mb = wm + i * 16 + kg * 4;
#pragma unroll
    for (int j = 0; j < 4; j++) {
      int n = n0 + wn + j * 16 + l15;
      if (n >= Nreal) continue;
      f32x4 d = acc[i][j];
#pragma unroll
      for (int r = 0; r < 4; r++) {
        int m = mb + r;
        if (m >= Mreal) continue;
        C[(long)m * ldc + n] = d[r];
      }
    }
  }
}

// vredT2: sum 10 transposed slices, s-tiled. MODE 0 -> (vmat, vT), MODE 1 -> (Vt, vtT@832)
template <int MODE>
__global__ __launch_bounds__(128) void k_vredT2(const float* __restrict__ vp,
                                                float* __restrict__ vout,
                                                f16* __restrict__ tout) {
  int s = blockIdx.x * 128 + threadIdx.x;
  int ec = blockIdx.y;
  if (s >= 4000) return;
  int g = s / 5, f = s % 5;
  float sums[40];
#pragma unroll
  for (int eo = 0; eo < 40; eo++) {
    int e = ec * 40 + eo;
    float sum = 0.f;
#pragma unroll
    for (int z = 0; z < 10; z++) sum += vp[(long)z * 480000 + (long)e * 4000 + s];
    sums[eo] = sum;
    if (MODE == 0) tout[(long)e * 4000 + s] = (f16)sum;
    else tout[(long)(f * 120 + e) * 832 + g] = (f16)sum;
  }
#pragma unroll
  for (int q = 0; q < 10; q++)
    *(f32x4*)&vout[(long)s * 120 + ec * 40 + q * 4] = *(f32x4*)&sums[q * 4];
}

// cl[m][n] = sum_z Clp[z][m][n] + b_local[m]
__global__ void k_cl_reduce(const float* __restrict__ Clp, const float* __restrict__ bl,
                            float* __restrict__ cl) {
  int id = blockIdx.x * blockDim.x + threadIdx.x;
  if (id >= 640000) return;
  int m = id / 160, n4 = (id % 160) * 4;
  long o = (long)m * 640 + n4;
  f32x4 s = {0.f, 0.f, 0.f, 0.f};
#pragma unroll
  for (int z = 0; z < 4; z++) s += *(const f32x4*)&Clp[(long)z * 2560000 + o];
  float b = bl[m];
  s += (f32x4){b, b, b, b};
  *(f32x4*)&cl[o] = s;
}

// ---------------------------------------------------------------------------
// Bp[fp][eg][zk*832+kk] = f16( sum_dh A9[(dh*3+zk)][ (fp-dh)*120+eg ][kk] ), tail zero
__global__ void k_fold_bp(const float* __restrict__ A9, f16* __restrict__ Bp) {
  int id = blockIdx.x * blockDim.x + threadIdx.x;
  if (id >= 7 * 120 * 2496) return;
  int fp = id / 299520;
  int r = id % 299520;
  int eg = r / 2496, k2 = r % 2496;
  int zk = k2 / 832, kk = k2 % 832;
  if (kk >= 800) { Bp[id] = (f16)0.f; return; }
  float s = 0.f;
#pragma unroll
  for (int dh = 0; dh < 3; dh++) {
    int f = fp - dh;
    if (f >= 0 && f < 5)
      s += A9[((long)(dh * 3 + zk) * 640 + f * 120 + eg) * 800 + kk];
  }
  Bp[id] = (f16)s;
}

// ---------------------------------------------------------------------------
// U GEMM: BK=64 swizzled, block 64x48(40 real). grid (28, 21=(fp,zk)).
__global__ __launch_bounds__(256) void k_gemm_u(
    const f16* __restrict__ Pg, const f16* __restrict__ Pp, const f16* __restrict__ Pc,
    const f16* __restrict__ Bp, float* __restrict__ Upart) {
  __shared__ __align__(16) f16 As[2][4096];
  __shared__ __align__(16) f16 Bs[2][4096];
  int m0 = blockIdx.x * 64;
  int y = blockIdx.y, fp = y / 3, zk = y % 3;
  const f16* P; int seg0, jw, Wp, e0;
  if (m0 < 640)       { seg0 = 0;    jw = 40; Wp = 42; e0 = 0;  P = Pg; }
  else if (m0 < 1152) { seg0 = 640;  jw = 30; Wp = 32; e0 = 40; P = Pp; }
  else                { seg0 = 1152; jw = 40; Wp = 42; e0 = 80; P = Pc; }
  P += (long)fp * 16 * Wp * 800;
  int t = threadIdx.x;
  int gslot = (t & 7) ^ ((t >> 3) & 7);
  const f16 *ap[2], *bp[2];
#pragma unroll
  for (int q = 0; q < 2; q++) {
    int row = q * 32 + (t >> 3);
    int l = m0 + row - seg0; if (l >= 16 * jw) l = 0;
    ap[q] = P + ((long)(l / jw) * Wp + (l % jw)) * 800 + (long)zk * 800 + gslot * 8;
    int brow = row; if (e0 + brow > 119) brow = 119 - e0;
    bp[q] = Bp + ((long)fp * 120 + e0 + brow) * 2496 + zk * 832 + gslot * 8;
  }
  int lane = t & 63, wv = t >> 6, l15 = lane & 15, kg = lane >> 4;
  int sx = l15 & 7;
  f32x4 acc[3] = {};
  gload_lds(&As[0][t * 8], ap[0]); gload_lds(&As[0][2048 + t * 8], ap[1]);
  gload_lds(&Bs[0][t * 8], bp[0]); gload_lds(&Bs[0][2048 + t * 8], bp[1]);
  __syncthreads();
  int cur = 0;
  for (int kt = 0; kt < 13; kt++) {
    if (kt + 1 < 13) {
      int o = (kt + 1) * 64, nb = cur ^ 1;
      gload_lds(&As[nb][t * 8], ap[0] + o); gload_lds(&As[nb][2048 + t * 8], ap[1] + o);
      gload_lds(&Bs[nb][t * 8], bp[0] + o); gload_lds(&Bs[nb][2048 + t * 8], bp[1] + o);
    }
#pragma unroll
    for (int ks = 0; ks < 2; ks++) {
      int so = ((ks * 4 + kg) ^ sx) << 3;
      half8 av = *(const half8*)&As[cur][(wv * 16 + l15) * 64 + so];
#pragma unroll
      for (int j = 0; j < 3; j++) {
        half8 bv = *(const half8*)&Bs[cur][(j * 16 + l15) * 64 + so];
        acc[j] = __builtin_amdgcn_mfma_f32_16x16x32_f16(av, bv, acc[j], 0, 0, 0);
      }
    }
    __syncthreads();
    cur ^= 1;
  }
#pragma unroll
  for (int j = 0; j < 3; j++) {
    int n = j * 16 + l15;
    if (n >= 40) continue;
    f32x4 d = acc[j];
#pragma unroll
    for (int r = 0; r < 4; r++) {
      int m = m0 + wv * 16 + kg * 4 + r;
      if (m - seg0 >= 16 * jw) continue;
      Upart[((long)y * 1792 + m) * 40 + n] = d[r];
    }
  }
}

// Ufin[m][e] = sum_y Upart + cbblv[e0(m)+e]
__global__ void k_ured(const float* __restrict__ Upart, const float* __restrict__ cbblv,
                       float* __restrict__ Ufin) {
  int id = blockIdx.x * blockDim.x + threadIdx.x;
  if (id >= 1792 * 40) return;
  int m = id / 40, e = id % 40;
  int e0 = m < 640 ? 0 : (m < 1152 ? 40 : 80);
  float s = cbblv[e0 + e];
  for (int y = 0; y < 21; y++) s += Upart[(long)y * 71680 + id];
  Ufin[id] = s;
}

// cbblv[e] = sum_s bconv_o[s/5]*Vt[s,e] + b_local[s]*v[s,e]; svv[e]=sum_s v[s,e]
__global__ __launch_bounds__(256) void k_consts(
    const float* __restrict__ Vt, const float* __restrict__ vmat,
    const float* __restrict__ bconv, const float* __restrict__ blocal,
    float* __restrict__ cbblv, float* __restrict__ svv) {
  __shared__ float r1[256], r2[256];
  int e = blockIdx.x, t = threadIdx.x;
  float a = 0.f, b = 0.f;
  for (int s = t; s < 4000; s += 256) {
    a += bconv[s / 5] * Vt[(long)s * 120 + e] + blocal[s] * vmat[(long)s * 120 + e];
    b += vmat[(long)s * 120 + e];
  }
  r1[t] = a; r2[t] = b; __syncthreads();
  for (int o = 128; o > 0; o >>= 1) {
    if (t < o) { r1[t] += r1[t + o]; r2[t] += r2[t + o]; }
    __syncthreads();
  }
  if (t == 0) { cbblv[e] = r1[0]; svv[e] = r2[0]; }
}

// ---------------------------------------------------------------------------
__global__ __launch_bounds__(256) void k_kv_partial(
    const float* __restrict__ cl, const float* __restrict__ wlk, const float* __restrict__ blk,
    const float* __restrict__ wlv, const float* __restrict__ blv, float* __restrict__ kvp) {
  __shared__ float s_wk[1600], s_wv[1600];
  __shared__ float s_cl[8][40], s_k[8][40], s_v[8][40];
  int t = threadIdx.x, chunk = blockIdx.x, b = blockIdx.y;
  for (int p = t; p < 1600; p += 256) { s_wk[p] = wlk[p]; s_wv[p] = wlv[p]; }
  float acc[7] = {0.f, 0.f, 0.f, 0.f, 0.f, 0.f, 0.f};
  for (int c8 = 0; c8 < 20; c8++) {
    int sb = chunk * 160 + c8 * 8;
    __syncthreads();
    for (int p = t; p < 320; p += 256) {
      int sl = p / 40, e = p % 40;
      s_cl[sl][e] = cl[(long)(sb + sl) * 640 + b * 40 + e];
    }
    __syncthreads();
    for (int p = t; p < 640; p += 256) {
      int half = p / 320, q = p % 320, sl = q / 40, d = q % 40;
      const float* w = half ? s_wv : s_wk;
      float r = half ? blv[d] : blk[d];
      for (int e = 0; e < 40; e++) r += w[d * 40 + e] * s_cl[sl][e];
      if (half) s_v[sl][d] = r; else s_k[sl][d] = r;
    }
    __syncthreads();
    int ai = 0;
    for (int p = t; p < 1600; p += 256, ai++) {
      int d = p / 40, e = p % 40;
      float a = acc[ai];
      for (int sl = 0; sl < 8; sl++) a += s_k[sl][d] * s_v[sl][e];
      acc[ai] = a;
    }
  }
  int ai = 0;
  for (int p = t; p < 1600; p += 256, ai++)
    kvp[((long)(b * 25 + chunk)) * 1600 + p] = acc[ai];
}

__global__ void k_kv_reduce(const float* __restrict__ kvp, float* __restrict__ kv) {
  int i = blockIdx.x * blockDim.x + threadIdx.x;
  if (i >= 16 * 1600) return;
  int b = i / 1600, p = i % 1600;
  float s = 0.f;
  for (int c = 0; c < 25; c++) s += kvp[((long)(b * 25 + c)) * 1600 + p];
  kv[i] = s;
}

// ---------------------------------------------------------------------------
// lsp residual partials: rpart[b*25+chunk] = sum_{s in chunk} lsp[b,s,:]·vsum[s,:]
__global__ __launch_bounds__(256) void k_resid(
    const float* __restrict__ lsp32, const float* __restrict__ vmat,
    float* __restrict__ rpart) {
  __shared__ float red[256];
  int chunk = blockIdx.x, b = blockIdx.y, t = threadIdx.x;
  int s0 = chunk * 160;
  float y = 0.f;
  for (int idx = t; idx < 1600; idx += 256) {
    int sr = idx / 10, d4 = idx % 10;
    const float* lp = lsp32 + ((long)b * SEQN + s0 + sr) * 40 + d4 * 4;
    const float* vp = vmat + (long)(s0 + sr) * 120 + d4 * 4;
    f32x4 l = *(const f32x4*)lp;
    f32x4 vs = *(const f32x4*)vp + *(const f32x4*)(vp + 40) + *(const f32x4*)(vp + 80);
    y += l[0] * vs[0] + l[1] * vs[1] + l[2] * vs[2] + l[3] * vs[3];
  }
  red[t] = y; __syncthreads();
  for (int o = 128; o > 0; o >>= 1) { if (t < o) red[t] += red[t + o]; __syncthreads(); }
  if (t == 0) rpart[b * 25 + chunk] = red[0];
}

// final: per-batch tiny contraction + sums + sigmoid
__global__ __launch_bounds__(256) void k_final(
    const float* __restrict__ Ufin, const float* __restrict__ kvb,
    const float* __restrict__ rpart,
    const float* __restrict__ wgq, const float* __restrict__ wpq, const float* __restrict__ wcq,
    const float* __restrict__ bgq, const float* __restrict__ bpq, const float* __restrict__ bcq,
    const float* __restrict__ svv, const float* __restrict__ c1p,
    const float* __restrict__ bcls, const float* __restrict__ bnw,
    const float* __restrict__ bnb, float* __restrict__ out) {
  __shared__ float s_kv[1600], s_U[4800], s_w[4400], s_bq[120], s_sv[120], s_red[256];
  int b = blockIdx.x, t = threadIdx.x;
  for (int p = t; p < 1600; p += 256) {
    s_kv[p] = kvb[b * 1600 + p];
    s_w[p] = wgq[p];
    s_w[2800 + p] = wcq[p];
  }
  for (int p = t; p < 1200; p += 256) s_w[1600 + p] = wpq[p];
  for (int p = t; p < 4800; p += 256) {
    int tt = p / 1600, r = p % 1600, j = r / 40, e = r % 40;
    float uv = 0.f;
    if (tt == 0) uv = Ufin[(b * 40 + j) * 40 + e];
    else if (tt == 1) { if (j < 30) uv = Ufin[(640 + b * 30 + j) * 40 + e]; }
    else uv = Ufin[(1152 + b * 40 + j) * 40 + e];
    s_U[p] = uv;
  }
  if (t < 40) { s_bq[t] = bgq[t]; s_bq[40 + t] = bpq[t]; s_bq[80 + t] = bcq[t]; }
  for (int p = t; p < 120; p += 256) s_sv[p] = svv[p];
  __syncthreads();
  float y = 0.f;
  for (int p = t; p < 4800; p += 256) {
    int tt = p / 1600, q = p % 1600, d = q / 40, e = q % 40;
    float T = 0.f;
    if (tt == 0) {
      for (int j = 0; j < 40; j++) T += s_w[d * 40 + j] * s_U[j * 40 + e];
    } else if (tt == 1) {
      for (int j = 0; j < 30; j++) T += s_w[1600 + d * 30 + j] * s_U[1600 + j * 40 + e];
    } else {
      for (int j = 0; j < 40; j++) T += s_w[2800 + d * 40 + j] * s_U[3200 + j * 40 + e];
    }
    y += s_kv[d * 40 + e] * (T + s_bq[tt * 40 + d] * s_sv[tt * 40 + e]);
  }
  for (int p = t; p < 25; p += 256) y += rpart[b * 25 + p];
  s_red[t] = y; __syncthreads();
  for (int o = 128; o > 0; o >>= 1) { if (t < o) s_red[t] += s_red[t + o]; __syncthreads(); }
  if (t == 0) {
    float c1 = bcls[0];
    for (int i = 0; i < 120; i++) c1 += c1p[i];
    float yy = s_red[0] * (1.f / 1024.f) + c1;
    yy = yy * (bnw[0] * rsqrtf(1.f + 1e-5f)) + bnb[0];
    out[b] = 1.f / (1.f + expf(-yy));
  }
}

// ---------------------------------------------------------------------------
extern "C" void kernel_launch(void* const* d_in, const int* in_sizes, int n_in,
                              void* d_out, int out_size, void* d_ws, size_t ws_size,
                              hipStream_t stream) {
  const int*   X        = (const int*)d_in[0];
  const float* emb      = (const float*)d_in[1];
  const float* w_dwc_l  = (const float*)d_in[2];
  const float* b_dwc_l  = (const float*)d_in[3];
  const float* w_dwc_o  = (const float*)d_in[4];
  const float* b_dwc_o  = (const float*)d_in[5];
  const float* w_local  = (const float*)d_in[6];
  const float* b_local  = (const float*)d_in[7];
  const float* w_global = (const float*)d_in[8];
  const float* b_global = (const float*)d_in[9];
  const float* w_gq = (const float*)d_in[10];
  const float* b_gq = (const float*)d_in[11];
  const float* w_cq = (const float*)d_in[12];
  const float* b_cq = (const float*)d_in[13];
  const float* w_pq = (const float*)d_in[14];
  const float* b_pq = (const float*)d_in[15];
  const float* w_lk = (const float*)d_in[16];
  const float* b_lk = (const float*)d_in[17];
  const float* w_lv = (const float*)d_in[18];
  const float* b_lv = (const float*)d_in[19];
  const float* w_cls = (const float*)d_in[20];
  const float* b_cls = (const float*)d_in[21];
  const float* bn_w = (const float*)d_in[22];
  const float* bn_b = (const float*)d_in[23];
  float* out = (float*)d_out;

  char* ws = (char*)d_ws;
  size_t off = 0;
  auto alloc = [&](size_t bytes) -> void* {
    off = (off + 255) & ~(size_t)255;
    void* p = ws + off; off += bytes; return p;
  };

  const size_t sz_p40 = (size_t)7 * 16 * 42 * 800 * 2;
  const size_t sz_p30 = (size_t)7 * 16 * 32 * 800 * 2;
  f16* P_lsp = (f16*)alloc(sz_p40 + 256);
  f16* P_pit = (f16*)alloc(sz_p30 + 256);
  f16* P_cod = (f16*)alloc(sz_p40 + 256);
  f16* P_gai = (f16*)alloc(sz_p40 + 256);
  float* lsp32 = (float*)alloc((size_t)16 * 4000 * 40 * 4);
  f16* wp_lsp = (f16*)alloc((size_t)896 * 7296 * 2);
  f16* wlp    = (f16*)alloc((size_t)4000 * 4096 * 2 + 256);
  f16* wcT    = (f16*)alloc((size_t)128 * 4000 * 2);
  f16* vT     = (f16*)alloc((size_t)128 * 4000 * 2);
  f16* co     = (f16*)alloc((size_t)640 * 4000 * 2 + 256);
  float* cl   = (float*)alloc((size_t)4000 * 640 * 4);
  float* vmat  = (float*)alloc((size_t)480000 * 4);
  float* Vt    = (float*)alloc((size_t)480000 * 4);
  f16* vtT   = (f16*)alloc((size_t)640 * 832 * 2 + 256);
  f16* Bp    = (f16*)alloc((size_t)7 * 120 * 2496 * 2);
  float* Upart = (float*)alloc((size_t)21 * 1792 * 40 * 4);
  float* Ufin  = (float*)alloc((size_t)1792 * 40 * 4);
  float* cbblv = (float*)alloc(120 * 4);
  float* svv   = (float*)alloc(120 * 4);
  float* kvp  = (float*)alloc((size_t)400 * 1600 * 4);
  float* kvb  = (float*)alloc((size_t)16 * 1600 * 4);
  float* c1p  = (float*)alloc(120 * 4);
  float* rpart = (float*)alloc(400 * 4);
  // arena: A9(18.43MB)@0 | woT(11.68MB)@18.5MB | vpart(19.2MB)@30.2MB ; later Cp@0(30.7MB), Clp@0(41MB)
  char* arena = (char*)alloc((size_t)52 * 1024 * 1024);
  float* A9   = (float*)arena;
  f16*   woT  = (f16*)(arena + 18500000);
  float* vpart = (float*)(arena + 30200000);
  float* Cp   = (float*)arena;
  float* Clp  = (float*)arena;
  (void)ws_size; (void)in_sizes; (void)n_in; (void)out_size;

  // zero conv-pad borders + vtT (K-tail zeros for A9 GEMM)
  hipMemsetAsync(P_lsp, 0, sz_p40, stream);
  hipMemsetAsync(P_pit, 0, sz_p30, stream);
  hipMemsetAsync(P_cod, 0, sz_p40, stream);
  hipMemsetAsync(P_gai, 0, sz_p40, stream);
  hipMemsetAsync(vtT, 0, (size_t)640 * 832 * 2, stream);

  // prep
  k_prepA<<<5300, 256, 0, stream>>>(w_dwc_l, wp_lsp, w_local, wlp, w_cls, wcT);
  k_pack_woT<<<625, 256, 0, stream>>>(w_dwc_o, woT);
  k_gather<<<400, 256, 0, stream>>>(X, emb, P_lsp, P_pit, P_cod, P_gai, lsp32);
  k_c1<<<120, 256, 0, stream>>>(w_cls, b_global, c1p);

  // v = w_global^T @ (wc*1024): TN, splitK 10
  {
    dim3 g(32, 10);
    k_gemm_tn<<<g, 256, 0, stream>>>(wcT, 4000, w_global, 4000, vpart, 4000,
                                     13, 125, 480000, 120, 4000);
  }
  {
    dim3 g(32, 3);
    k_vredT2<0><<<g, 128, 0, stream>>>(vpart, vmat, vT);
  }

  // Vt = w_local^T @ v: TN, splitK 10
  {
    dim3 g(32, 10);
    k_gemm_tn<<<g, 256, 0, stream>>>(vT, 4000, w_local, 4000, vpart, 4000,
                                     13, 125, 480000, 120, 4000);
  }
  {
    dim3 g(32, 3);
    k_vredT2<1><<<g, 128, 0, stream>>>(vpart, Vt, vtT);
  }

  k_consts<<<120, 256, 0, stream>>>(Vt, vmat, b_dwc_o, b_local, cbblv, svv);

  // lsp residual partials (grid 400)
  {
    dim3 g(25, 16);
    k_resid<<<g, 256, 0, stream>>>(lsp32, vmat, rpart);
  }

  // A9[z][fe][gi] = sum_g vtT[fe][g]*woT[z][gi][g]  (128^2 BK=32 swz, K=832)
  {
    dim3 g(35, 1, 9);
    k_gemm128<<<g, 256, 0, stream>>>(vtT, 832, woT, 800, A9, 800,
                                     7, 35, 26, 26, 0, 0, 640000, 512000, 600, 800, 600);
  }
  k_fold_bp<<<8190, 256, 0, stream>>>(A9, Bp);

  // lsp conv GEMM (128^2 BK=32 swz, splitK 3 over df) + reduce w/ bias
  {
    dim3 g(175, 3);
    k_gemm_conv<<<g, 256, 0, stream>>>(P_lsp, wp_lsp, Cp);
  }
  k_co_reduce<<<2500, 256, 0, stream>>>(Cp, b_dwc_l, co);

  // cl = w_local(permuted) @ co^T + b_local : 128^2 BK=32 swz, splitK 4 -> Clp, reduce
  {
    dim3 g(160, 4);
    k_gemm128<<<g, 256, 0, stream>>>(wlp, 4096, co, 4000, Clp, 640,
                                     5, 160, 32, 128, 2560000L, 0, 0, 0, 4000, 640, 4000);
  }
  k_cl_reduce<<<2500, 256, 0, stream>>>(Clp, b_local, cl);

  // kv
  {
    dim3 g(25, 16);
    k_kv_partial<<<g, 256, 0, stream>>>(cl, w_lk, b_lk, w_lv, b_lv, kvp);
  }
  k_kv_reduce<<<100, 256, 0, stream>>>(kvp, kvb);

  // U path (BK=64 swz, splitK 3 over dw)
  {
    dim3 g(28, 21);
    k_gemm_u<<<g, 256, 0, stream>>>(P_gai, P_pit, P_cod, Bp, Upart);
  }
  k_ured<<<280, 256, 0, stream>>>(Upart, cbblv, Ufin);

  // final combine (tiny per-batch contraction + sums + sigmoid)
  k_final<<<16, 256, 0, stream>>>(Ufin, kvb, rpart,
                                  w_gq, w_pq, w_cq, b_gq, b_pq, b_cq,
                                  svv, c1p, b_cls, bn_w, bn_b, out);
}